// Round 5
// baseline (12524.236 us; speedup 1.0000x reference)
//
#include <hip/hip_runtime.h>
#include <hip/hip_bf16.h>
#include <stdint.h>

#define BATCH 4
#define SEQ 1024
#define DIMX 1024
#define VOCAB 32000
#define NLAYERS 4
#define NBLK 256   // blocks in persistent kernel (1/CU)

using bf16x8 = __attribute__((ext_vector_type(8))) short;
using f32x4v = __attribute__((ext_vector_type(4))) float;

__device__ __forceinline__ uint16_t f2b(float f) {
  __hip_bfloat16 h = __float2bfloat16(f);
  return *reinterpret_cast<uint16_t*>(&h);
}
__device__ __forceinline__ float b2f(uint16_t u) {
  __hip_bfloat16 h = *reinterpret_cast<__hip_bfloat16*>(&u);
  return __bfloat162float(h);
}
__device__ __forceinline__ void fsplit(float v, uint16_t& h, uint16_t& l) {
  h = f2b(v);
  l = f2b(v - b2f(h));
}

// ---------------- embedding gather -> split bf16: row (t*4+b)
__global__ __launch_bounds__(256) void k_embed_split(const int* __restrict__ ids,
                                                     const float* __restrict__ emb,
                                                     uint16_t* __restrict__ Hhi,
                                                     uint16_t* __restrict__ Hlo) {
  int idx = blockIdx.x * 256 + threadIdx.x;
  int d4 = idx & (DIMX / 4 - 1);
  int tb = idx >> 8;
  int t = tb >> 2, b = tb & 3;
  int id = ids[b * SEQ + t];
  float4 v = reinterpret_cast<const float4*>(emb + (size_t)id * DIMX)[d4];
  ushort4 h, l;
  fsplit(v.x, h.x, l.x); fsplit(v.y, h.y, l.y); fsplit(v.z, h.z, l.z); fsplit(v.w, h.w, l.w);
  reinterpret_cast<ushort4*>(Hhi)[idx] = h;
  reinterpret_cast<ushort4*>(Hlo)[idx] = l;
}

// ---------------- split all layers' weights: W1 (2048 rows), WS (1024), M1=Wss (1024)
__global__ __launch_bounds__(256) void k_split_w(const float* __restrict__ W,
                                                 uint16_t* __restrict__ W1h, uint16_t* __restrict__ W1l,
                                                 uint16_t* __restrict__ WSh, uint16_t* __restrict__ WSl,
                                                 uint16_t* __restrict__ M1h, uint16_t* __restrict__ M1l) {
  int idx = blockIdx.x * 256 + threadIdx.x;
  int c4 = idx & 255;
  int row = idx >> 8;
  int l = row >> 12, r = row & 4095;
  const float* Wl = W + (size_t)l * 4 * 1024 * 1024;
  const float* src;
  uint16_t *dh, *dl;
  size_t doff;
  if (r < 2048) { src = Wl + (size_t)r * 2048; dh = W1h; dl = W1l; doff = ((size_t)l * 2048 + r) * 1024; }
  else if (r < 3072) { int rr = r - 2048; src = Wl + (size_t)rr * 2048 + 1024; dh = WSh; dl = WSl; doff = ((size_t)l * 1024 + rr) * 1024; }
  else { int rr = r - 3072; src = Wl + (size_t)(1024 + rr) * 2048 + 1024; dh = M1h; dl = M1l; doff = ((size_t)l * 1024 + rr) * 1024; }
  float4 v = reinterpret_cast<const float4*>(src)[c4];
  ushort4 h, lo4;
  fsplit(v.x, h.x, lo4.x); fsplit(v.y, h.y, lo4.y); fsplit(v.z, h.z, lo4.z); fsplit(v.w, h.w, lo4.w);
  reinterpret_cast<ushort4*>(dh + doff)[c4] = h;
  reinterpret_cast<ushort4*>(dl + doff)[c4] = lo4;
}

// ---------------- T1 = Wss^T per layer (LDS-tiled transpose + split)
__global__ __launch_bounds__(256) void k_trans_w(const float* __restrict__ W,
                                                 uint16_t* __restrict__ T1h, uint16_t* __restrict__ T1l) {
  __shared__ float t[64][65];
  int l = blockIdx.z;
  const float* Wl = W + (size_t)l * 4 * 1024 * 1024;
  int i0 = blockIdx.y * 64, j0 = blockIdx.x * 64;
  int c4 = (threadIdx.x & 15) * 4, rr = threadIdx.x >> 4;
#pragma unroll
  for (int p = 0; p < 4; ++p) {
    int r = rr + p * 16;
    float4 v = *reinterpret_cast<const float4*>(Wl + (size_t)(1024 + i0 + r) * 2048 + 1024 + j0 + c4);
    t[r][c4] = v.x; t[r][c4 + 1] = v.y; t[r][c4 + 2] = v.z; t[r][c4 + 3] = v.w;
  }
  __syncthreads();
#pragma unroll
  for (int p = 0; p < 4; ++p) {
    int j = rr + p * 16;
    ushort4 h, l4;
    fsplit(t[c4 + 0][j], h.x, l4.x);
    fsplit(t[c4 + 1][j], h.y, l4.y);
    fsplit(t[c4 + 2][j], h.z, l4.z);
    fsplit(t[c4 + 3][j], h.w, l4.w);
    size_t o = (size_t)l * 1024 * 1024 + (size_t)(j0 + j) * 1024 + i0 + c4;
    *reinterpret_cast<ushort4*>(T1h + o) = h;
    *reinterpret_cast<ushort4*>(T1l + o) = l4;
  }
}

// ---------------- split-bf16 MFMA GEMM (NT), 128x128 tile, optional z-batch.
// O2: if o2_bs==0 -> transposed split(dot) at [n*o2_cs + m]; else strided split(dot).
template <int BM, int BN>
__global__ __launch_bounds__(256) void k_mfma(
    int K,
    const uint16_t* __restrict__ Ahi, const uint16_t* __restrict__ Alo, int a_cs, int a_bs, size_t a_z,
    const uint16_t* __restrict__ Bhi, const uint16_t* __restrict__ Blo, int ldb, size_t b_z,
    const float* __restrict__ ADD, int add_cs, int add_bs,
    float* __restrict__ O1f, int o1_cs, int o1_bs,
    uint16_t* __restrict__ O1hi, uint16_t* __restrict__ O1lo, int o1s_cs, int o1s_bs, int split_n0, size_t o1_z,
    uint16_t* __restrict__ O2hi, uint16_t* __restrict__ O2lo, int o2_cs, int o2_bs, size_t o2_z) {
  constexpr int FM = BM / 32;
  constexpr int FN = BN / 32;
  __shared__ uint16_t sAh[BM * 32], sAl[BM * 32], sBh[BN * 32], sBl[BN * 32];
  size_t zb = blockIdx.z;
  Ahi += zb * a_z; Alo += zb * a_z;
  Bhi += zb * b_z; Blo += zb * b_z;
  if (O1hi) { O1hi += zb * o1_z; O1lo += zb * o1_z; }
  if (O2hi) { O2hi += zb * o2_z; O2lo += zb * o2_z; }
  int tid = threadIdx.x;
  int lane = tid & 63;
  int wave = tid >> 6;
  int wm = wave >> 1, wn = wave & 1;
  int m0 = blockIdx.y * BM, n0 = blockIdx.x * BN;
  f32x4v acc[FM][FN] = {};
  for (int kt = 0; kt < K; kt += 32) {
    __syncthreads();
#pragma unroll
    for (int q = 0; q < BM / 64; ++q) {
      int off = q * 4096 + tid * 16;
      int r = off >> 6;
      int cu = (off & 63) >> 1;
      size_t goff = (size_t)(m0 / 4 + (r >> 2)) * a_cs + (size_t)(r & 3) * a_bs + kt + cu;
      __builtin_amdgcn_global_load_lds(
          (const __attribute__((address_space(1))) uint32_t*)(Ahi + goff),
          (__attribute__((address_space(3))) uint32_t*)((char*)sAh + off), 16, 0, 0);
      __builtin_amdgcn_global_load_lds(
          (const __attribute__((address_space(1))) uint32_t*)(Alo + goff),
          (__attribute__((address_space(3))) uint32_t*)((char*)sAl + off), 16, 0, 0);
    }
#pragma unroll
    for (int q = 0; q < BN / 64; ++q) {
      int off = q * 4096 + tid * 16;
      int r = off >> 6, cu = (off & 63) >> 1;
      size_t goff = (size_t)(n0 + r) * ldb + kt + cu;
      __builtin_amdgcn_global_load_lds(
          (const __attribute__((address_space(1))) uint32_t*)(Bhi + goff),
          (__attribute__((address_space(3))) uint32_t*)((char*)sBh + off), 16, 0, 0);
      __builtin_amdgcn_global_load_lds(
          (const __attribute__((address_space(1))) uint32_t*)(Blo + goff),
          (__attribute__((address_space(3))) uint32_t*)((char*)sBl + off), 16, 0, 0);
    }
    __syncthreads();
    int rsel = lane & 15, ko = (lane >> 4) * 8;
    bf16x8 ah[FM], al[FM], bh[FN], bl[FN];
#pragma unroll
    for (int mf = 0; mf < FM; ++mf) {
      int row = wm * (FM * 16) + mf * 16 + rsel;
      ah[mf] = *reinterpret_cast<const bf16x8*>(sAh + row * 32 + ko);
      al[mf] = *reinterpret_cast<const bf16x8*>(sAl + row * 32 + ko);
    }
#pragma unroll
    for (int nf = 0; nf < FN; ++nf) {
      int row = wn * (FN * 16) + nf * 16 + rsel;
      bh[nf] = *reinterpret_cast<const bf16x8*>(sBh + row * 32 + ko);
      bl[nf] = *reinterpret_cast<const bf16x8*>(sBl + row * 32 + ko);
    }
#pragma unroll
    for (int mf = 0; mf < FM; ++mf)
#pragma unroll
      for (int nf = 0; nf < FN; ++nf) {
        acc[mf][nf] = __builtin_amdgcn_mfma_f32_16x16x32_bf16(ah[mf], bh[nf], acc[mf][nf], 0, 0, 0);
        acc[mf][nf] = __builtin_amdgcn_mfma_f32_16x16x32_bf16(ah[mf], bl[nf], acc[mf][nf], 0, 0, 0);
        acc[mf][nf] = __builtin_amdgcn_mfma_f32_16x16x32_bf16(al[mf], bh[nf], acc[mf][nf], 0, 0, 0);
      }
  }
  int rowg = (lane >> 4) * 4, colg = lane & 15;
#pragma unroll
  for (int mf = 0; mf < FM; ++mf)
#pragma unroll
    for (int nf = 0; nf < FN; ++nf)
#pragma unroll
      for (int r = 0; r < 4; ++r) {
        int m = m0 + wm * (FM * 16) + mf * 16 + rowg + r;
        int n = n0 + wn * (FN * 16) + nf * 16 + colg;
        size_t ro = (size_t)(m >> 2);
        float dot = acc[mf][nf][r];
        float v = dot;
        if (ADD) v += ADD[ro * add_cs + (size_t)(m & 3) * add_bs + n];
        if (O1f) O1f[ro * o1_cs + (size_t)(m & 3) * o1_bs + n] = v;
        if (O1hi && n >= split_n0) {
          uint16_t h, l;
          fsplit(v, h, l);
          size_t o = ro * o1s_cs + (size_t)(m & 3) * o1s_bs + (n - split_n0);
          O1hi[o] = h; O1lo[o] = l;
        }
        if (O2hi) {
          uint16_t h, l;
          fsplit(dot, h, l);
          size_t o = (o2_bs == 0) ? ((size_t)n * o2_cs + m)
                                  : (ro * o2_cs + (size_t)(m & 3) * o2_bs + n);
          O2hi[o] = h; O2lo[o] = l;
        }
      }
}

// ---------------- slot barrier: NO atomic RMW anywhere (round-4 lesson: 128-way
// fetch_add to one address serializes ~40us). Each block release-stores its own
// 64B-strided slot; block 0's threads acquire-load all slots in parallel, then
// release-store a release word; others acquire-poll the release word.
__device__ __forceinline__ void gbar(uint32_t* slots, uint32_t* release, uint32_t& gen) {
  __syncthreads();
  gen++;
  if (threadIdx.x == 0)
    __hip_atomic_store(slots + (size_t)blockIdx.x * 16, gen, __ATOMIC_RELEASE, __HIP_MEMORY_SCOPE_AGENT);
  if (blockIdx.x == 0) {
    while (__hip_atomic_load(slots + (size_t)threadIdx.x * 16, __ATOMIC_ACQUIRE, __HIP_MEMORY_SCOPE_AGENT) < gen)
      __builtin_amdgcn_s_sleep(1);
    __syncthreads();
    if (threadIdx.x == 0)
      __hip_atomic_store(release, gen, __ATOMIC_RELEASE, __HIP_MEMORY_SCOPE_AGENT);
  } else {
    if (threadIdx.x == 0) {
      while (__hip_atomic_load(release, __ATOMIC_ACQUIRE, __HIP_MEMORY_SCOPE_AGENT) < gen)
        __builtin_amdgcn_s_sleep(1);
    }
    __syncthreads();
  }
}

// per-wave 16x16 NT tile, K=1024, B dense [n][1024], split operands, direct global loads
__device__ __forceinline__ f32x4v wtile16(
    const uint16_t* __restrict__ Ah, const uint16_t* __restrict__ Al,
    int a_cs, int a_bs, int m0,
    const uint16_t* __restrict__ Bh, const uint16_t* __restrict__ Bl,
    int n0, int lane) {
  int rsel = lane & 15, ko = (lane >> 4) * 8;
  int am = m0 + rsel;
  const uint16_t* pah = Ah + (size_t)(am >> 2) * a_cs + (size_t)(am & 3) * a_bs + ko;
  const uint16_t* pal = Al + (size_t)(am >> 2) * a_cs + (size_t)(am & 3) * a_bs + ko;
  const uint16_t* pbh = Bh + (size_t)(n0 + rsel) * 1024 + ko;
  const uint16_t* pbl = Bl + (size_t)(n0 + rsel) * 1024 + ko;
  f32x4v acc = {0.f, 0.f, 0.f, 0.f};
#pragma unroll 4
  for (int kt = 0; kt < 1024; kt += 32) {
    bf16x8 ah = *reinterpret_cast<const bf16x8*>(pah + kt);
    bf16x8 al = *reinterpret_cast<const bf16x8*>(pal + kt);
    bf16x8 bh = *reinterpret_cast<const bf16x8*>(pbh + kt);
    bf16x8 bl = *reinterpret_cast<const bf16x8*>(pbl + kt);
    acc = __builtin_amdgcn_mfma_f32_16x16x32_bf16(ah, bh, acc, 0, 0, 0);
    acc = __builtin_amdgcn_mfma_f32_16x16x32_bf16(ah, bl, acc, 0, 0, 0);
    acc = __builtin_amdgcn_mfma_f32_16x16x32_bf16(al, bh, acc, 0, 0, 0);
  }
  return acc;
}

// ---------------- persistent per-layer kernel: 3-phase chunked scan (powers precomputed)
// Wave->tile mapping is XCD-aware: blocks dispatch round-robin over 8 XCDs, so block
// (bid&7)==x lands on XCD x; all waves of an XCD share one 128-col B-slice -> the
// per-step working set (~1.5MB) stays L2-resident within a step.
__global__ __launch_bounds__(256) void k_layer(
    uint32_t* slots, uint32_t* release,
    float* __restrict__ P,
    uint16_t* __restrict__ PUh, uint16_t* __restrict__ PUl,
    uint16_t* __restrict__ Sh, uint16_t* __restrict__ Sl,
    const uint16_t* __restrict__ M1h, const uint16_t* __restrict__ M1l,
    const uint16_t* __restrict__ M16h, const uint16_t* __restrict__ M16l,
    const uint16_t* __restrict__ M128h, const uint16_t* __restrict__ M128l,
    uint16_t* G3h0, uint16_t* G3l0, uint16_t* G3h1, uint16_t* G3l1,
    uint16_t* BEh, uint16_t* BEl,
    float* LAMf, uint16_t* LAMh, uint16_t* LAMl,
    uint16_t* GSh0, uint16_t* GSl0, uint16_t* GSh1, uint16_t* GSl1,
    const float* __restrict__ starterL) {
  int tid = threadIdx.x, bid = blockIdx.x;
  int lane = tid & 63;
  int wv = tid >> 6;                  // 0..3
  int xcd = bid & 7;
  int gix = (bid >> 3) * 4 + wv;      // 0..127 within this XCD's wave group
  uint32_t gen = 0;
  int rowg = (lane >> 4) * 4, colg = lane & 15;

  // init: sigma_0 = starter broadcast -> beta[0], G3[0] rows (c=0), GS[0] rows (g=0), S t=0
  {
    int idx = bid * 256 + tid;
    if (idx < BATCH * DIMX) {
      int b = idx >> 10, d = idx & 1023;
      float v = starterL[d];
      uint16_t h, l;
      fsplit(v, h, l);
      size_t o = (size_t)b * 1024 + d;
      BEh[o] = h; BEl[o] = l;
      G3h0[o] = h; G3l0[o] = l;
      GSh0[o] = h; GSl0[o] = l;
      Sh[o] = h; Sl[o] = l;
    }
  }

  // ---- phase 1: local scans l_j = A l_{j-1} + u_j, j=1..15  (in place over P u-half)
  for (int j = 1; j < 16; ++j) {
    {
      int mt = gix >> 3, nt = xcd * 8 + (gix & 7);
      int m0 = mt * 16, n0 = nt * 16;
      f32x4v acc = wtile16(PUh + (size_t)(j - 1) * 4096, PUl + (size_t)(j - 1) * 4096,
                           65536, 1024, m0, M1h, M1l, n0, lane);
      int n = n0 + colg;
#pragma unroll
      for (int rr = 0; rr < 4; ++rr) {
        int m = m0 + rowg + rr;
        int c = m >> 2, b = m & 3;
        size_t t = (size_t)(c * 16 + j);
        float* pu = P + (t * 4 + b) * 2048 + 1024 + n;
        float v = acc[rr] + *pu;
        *pu = v;
        uint16_t h, l;
        fsplit(v, h, l);
        size_t o = (t * 4 + b) * 1024 + n;
        PUh[o] = h; PUl[o] = l;
      }
    }
    gbar(slots, release, gen);
  }

  // ---- phase 2a init: lambda_0 = e_{8g} (chunk-end values)
  {
    int idx = bid * 256 + tid;
    if (idx < 32 * 1024) {
      int r = idx >> 10, d = idx & 1023;
      int g = r >> 2, b = r & 3;
      float v = P[((size_t)(g * 128 + 15) * 4 + b) * 2048 + 1024 + d];
      LAMf[idx] = v;
      uint16_t h, l;
      fsplit(v, h, l);
      LAMh[idx] = h; LAMl[idx] = l;
    }
  }
  gbar(slots, release, gen);

  // ---- phase 2a: lambda_j = A16 lambda_{j-1} + e_{8g+j}, j=1..7
  for (int j = 1; j < 8; ++j) {
    if (gix < 16) {
      int mt = gix >> 3, nt = xcd * 8 + (gix & 7);
      int m0 = mt * 16, n0 = nt * 16;
      f32x4v acc = wtile16(LAMh + (size_t)(j - 1) * 32768, LAMl + (size_t)(j - 1) * 32768,
                           4096, 1024, m0, M16h, M16l, n0, lane);
      int n = n0 + colg;
#pragma unroll
      for (int rr = 0; rr < 4; ++rr) {
        int m = m0 + rowg + rr;
        int g = m >> 2, b = m & 3;
        int c = 8 * g + j;
        float e = P[((size_t)(c * 16 + 15) * 4 + b) * 2048 + 1024 + n];
        float v = acc[rr] + e;
        size_t o = (size_t)j * 32768 + (size_t)m * 1024 + n;
        LAMf[o] = v;
        uint16_t h, l;
        fsplit(v, h, l);
        LAMh[o] = h; LAMl[o] = l;
      }
    }
    gbar(slots, release, gen);
  }

  // ---- phase 2b: beta_{g+1} = A128 beta_g + lambda_7(g), g=0..6 (rows padded to 16)
  for (int g = 0; g < 7; ++g) {
    if (gix < 8) {
      int n0 = (xcd * 8 + gix) * 16;
      f32x4v acc = wtile16(BEh + (size_t)g * 16384, BEl + (size_t)g * 16384,
                           4096, 1024, 0, M128h, M128l, n0, lane);
      if ((lane >> 4) == 0) {
        int n = n0 + colg;
#pragma unroll
        for (int rr = 0; rr < 4; ++rr) {
          int b = rr;
          float v = acc[rr] + LAMf[(size_t)7 * 32768 + (size_t)(g * 4 + b) * 1024 + n];
          uint16_t h, l;
          fsplit(v, h, l);
          size_t ob = (size_t)(g + 1) * 16384 + (size_t)b * 1024 + n;
          BEh[ob] = h; BEl[ob] = l;
          int c = 8 * (g + 1);
          size_t o1 = (size_t)(c * 4 + b) * 1024 + n;
          G3h0[o1] = h; G3l0[o1] = l;
          size_t o2 = ((size_t)(c * 16) * 4 + b) * 1024 + n;
          Sh[o2] = h; Sl[o2] = l;
          size_t o3 = (size_t)((g + 1) * 4 + b) * 1024 + n;
          GSh0[o3] = h; GSl0[o3] = l;
        }
      }
    }
    gbar(slots, release, gen);
  }

  // ---- phase 2c: Gs_j = A16 Gs_{j-1}; sigma_{8g+j} = Gs_j + lambda_{j-1}, j=1..7
  int gsc = 0;
  for (int j = 1; j < 8; ++j) {
    uint16_t* gih = gsc ? GSh1 : GSh0;
    uint16_t* gil = gsc ? GSl1 : GSl0;
    uint16_t* goh = gsc ? GSh0 : GSh1;
    uint16_t* gol = gsc ? GSl0 : GSl1;
    if (gix < 16) {
      int mt = gix >> 3, nt = xcd * 8 + (gix & 7);
      int m0 = mt * 16, n0 = nt * 16;
      f32x4v acc = wtile16(gih, gil, 4096, 1024, m0, M16h, M16l, n0, lane);
      int n = n0 + colg;
#pragma unroll
      for (int rr = 0; rr < 4; ++rr) {
        int m = m0 + rowg + rr;
        int g = m >> 2, b = m & 3;
        int c = 8 * g + j;
        float lam = LAMf[(size_t)(j - 1) * 32768 + (size_t)m * 1024 + n];
        float v = acc[rr] + lam;
        uint16_t h, l;
        fsplit(v, h, l);
        size_t o1 = (size_t)(c * 4 + b) * 1024 + n;
        G3h0[o1] = h; G3l0[o1] = l;
        size_t o2 = ((size_t)(c * 16) * 4 + b) * 1024 + n;
        Sh[o2] = h; Sl[o2] = l;
        uint16_t h2, l2;
        fsplit(acc[rr], h2, l2);
        goh[(size_t)m * 1024 + n] = h2;
        gol[(size_t)m * 1024 + n] = l2;
      }
    }
    gbar(slots, release, gen);
    gsc ^= 1;
  }

  // ---- phase 3: G_j = A G_{j-1}; S[c*16+j] = G_j + l_{c*16+j-1}, j=1..15
  int g3 = 0;
  for (int j = 1; j < 16; ++j) {
    uint16_t* gih = g3 ? G3h1 : G3h0;
    uint16_t* gil = g3 ? G3l1 : G3l0;
    uint16_t* goh = g3 ? G3h0 : G3h1;
    uint16_t* gol = g3 ? G3l0 : G3l1;
    {
      int mt = gix >> 3, nt = xcd * 8 + (gix & 7);
      int m0 = mt * 16, n0 = nt * 16;
      f32x4v acc = wtile16(gih, gil, 4096, 1024, m0, M1h, M1l, n0, lane);
      int n = n0 + colg;
#pragma unroll
      for (int rr = 0; rr < 4; ++rr) {
        int m = m0 + rowg + rr;
        int c = m >> 2, b = m & 3;
        float u = P[((size_t)(c * 16 + j - 1) * 4 + b) * 2048 + 1024 + n];
        float v = acc[rr] + u;
        uint16_t h, l;
        fsplit(v, h, l);
        size_t o = ((size_t)(c * 16 + j) * 4 + b) * 1024 + n;
        Sh[o] = h; Sl[o] = l;
        uint16_t h2, l2;
        fsplit(acc[rr], h2, l2);
        goh[(size_t)m * 1024 + n] = h2;
        gol[(size_t)m * 1024 + n] = l2;
      }
    }
    if (j < 15) gbar(slots, release, gen);
    g3 ^= 1;
  }
}

// ---------------- reorder H_hi [t][b][d] -> Y [b][t][d]
__global__ __launch_bounds__(256) void k_reorder_hi(const uint16_t* __restrict__ Hhi, uint16_t* __restrict__ Y) {
  int idx = blockIdx.x * 256 + threadIdx.x;
  int d4 = idx & (DIMX / 4 - 1);
  int tb = idx >> 8;
  int t = tb >> 2, b = tb & 3;
  ushort4 v = reinterpret_cast<const ushort4*>(Hhi)[idx];
  reinterpret_cast<ushort4*>(Y + (size_t)(b * SEQ + t) * DIMX)[d4] = v;
}

__global__ __launch_bounds__(256) void k_cast_w(const float* __restrict__ src, uint16_t* __restrict__ dst, int n4) {
  int idx = blockIdx.x * 256 + threadIdx.x;
  if (idx >= n4) return;
  float4 v = reinterpret_cast<const float4*>(src)[idx];
  ushort4 o;
  o.x = f2b(v.x); o.y = f2b(v.y); o.z = f2b(v.z); o.w = f2b(v.w);
  reinterpret_cast<ushort4*>(dst)[idx] = o;
}

// ---------------- logits GEMM: bf16 MFMA 128x128
__global__ __launch_bounds__(256) void k_logits(const uint16_t* __restrict__ A,
                                                const uint16_t* __restrict__ Bt,
                                                float* __restrict__ C) {
  __shared__ uint16_t As[128 * 32];
  __shared__ uint16_t Bs[128 * 32];
  int tid = threadIdx.x;
  int bx = blockIdx.x, by = blockIdx.y;
  int lane = tid & 63, wave = tid >> 6;
  int wm = wave >> 1, wn = wave & 1;
  f32x4v acc[4][4] = {};
  const uint16_t* Ag = A + (size_t)by * 128 * 1024;
  const uint16_t* Bg = Bt + (size_t)bx * 128 * 1024;
  for (int kt = 0; kt < 1024; kt += 32) {
    __syncthreads();
#pragma unroll
    for (int q = 0; q < 2; ++q) {
      int off = q * 4096 + tid * 16;
      int r = off >> 6, cu = (off & 63) >> 1;
      __builtin_amdgcn_global_load_lds(
          (const __attribute__((address_space(1))) uint32_t*)(Ag + (size_t)r * 1024 + kt + cu),
          (__attribute__((address_space(3))) uint32_t*)((char*)As + off), 16, 0, 0);
      __builtin_amdgcn_global_load_lds(
          (const __attribute__((address_space(1))) uint32_t*)(Bg + (size_t)r * 1024 + kt + cu),
          (__attribute__((address_space(3))) uint32_t*)((char*)Bs + off), 16, 0, 0);
    }
    __syncthreads();
    int rsel = lane & 15, ko = (lane >> 4) * 8;
    bf16x8 af[4], bfr[4];
#pragma unroll
    for (int mf = 0; mf < 4; ++mf)
      af[mf] = *reinterpret_cast<const bf16x8*>(As + (wm * 64 + mf * 16 + rsel) * 32 + ko);
#pragma unroll
    for (int nf = 0; nf < 4; ++nf)
      bfr[nf] = *reinterpret_cast<const bf16x8*>(Bs + (wn * 64 + nf * 16 + rsel) * 32 + ko);
#pragma unroll
    for (int mf = 0; mf < 4; ++mf)
#pragma unroll
      for (int nf = 0; nf < 4; ++nf)
        acc[mf][nf] = __builtin_amdgcn_mfma_f32_16x16x32_bf16(af[mf], bfr[nf], acc[mf][nf], 0, 0, 0);
  }
  int rowg = (lane >> 4) * 4;
  int colg = lane & 15;
#pragma unroll
  for (int mf = 0; mf < 4; ++mf)
#pragma unroll
    for (int nf = 0; nf < 4; ++nf)
#pragma unroll
      for (int r = 0; r < 4; ++r) {
        int m = by * 128 + wm * 64 + mf * 16 + rowg + r;
        int n = bx * 128 + wn * 64 + nf * 16 + colg;
        C[(size_t)m * VOCAB + n] = acc[mf][nf][r];
      }
}

// =========================================================================
extern "C" void kernel_launch(void* const* d_in, const int* in_sizes, int n_in,
                              void* d_out, int out_size, void* d_ws, size_t ws_size,
                              hipStream_t stream) {
  const int* ids = (const int*)d_in[0];
  const float* emb = (const float*)d_in[1];
  const float* W = (const float*)d_in[2];
  const float* outw = (const float*)d_in[3];
  const float* starter = (const float*)d_in[4];
  float* out = (float*)d_out;

  char* wsb = (char*)d_ws;
  size_t off = 0;
  auto alloc = [&](size_t bytes) {
    void* p = wsb + off;
    off = (off + bytes + 255) & ~(size_t)255;
    return p;
  };
  const size_t TB = SEQ * BATCH;
  const size_t MB1 = (size_t)1024 * 1024;

  // per-layer sync region: 256 slots * 16 words + release word at word 4096
  uint32_t* SYNC = (uint32_t*)alloc((size_t)NLAYERS * 8192 * 4);
  uint16_t* Hh[2] = {(uint16_t*)alloc(TB * DIMX * 2), (uint16_t*)alloc(TB * DIMX * 2)};
  uint16_t* Hl[2] = {(uint16_t*)alloc(TB * DIMX * 2), (uint16_t*)alloc(TB * DIMX * 2)};
  float* P = (float*)alloc(TB * 2 * DIMX * 4);
  uint16_t* PUh = (uint16_t*)alloc(TB * DIMX * 2);
  uint16_t* PUl = (uint16_t*)alloc(TB * DIMX * 2);
  uint16_t* Sh = (uint16_t*)alloc(TB * DIMX * 2);
  uint16_t* Sl = (uint16_t*)alloc(TB * DIMX * 2);
  uint16_t* W1h = (uint16_t*)alloc((size_t)NLAYERS * 2048 * 1024 * 2);
  uint16_t* W1l = (uint16_t*)alloc((size_t)NLAYERS * 2048 * 1024 * 2);
  uint16_t* WSh = (uint16_t*)alloc((size_t)NLAYERS * MB1 * 2);
  uint16_t* WSl = (uint16_t*)alloc((size_t)NLAYERS * MB1 * 2);
  uint16_t* M1h = (uint16_t*)alloc((size_t)NLAYERS * MB1 * 2);
  uint16_t* M1l = (uint16_t*)alloc((size_t)NLAYERS * MB1 * 2);
  uint16_t* T1h = (uint16_t*)alloc((size_t)NLAYERS * MB1 * 2);
  uint16_t* T1l = (uint16_t*)alloc((size_t)NLAYERS * MB1 * 2);
  uint16_t* M16Ah = (uint16_t*)alloc((size_t)NLAYERS * MB1 * 2);
  uint16_t* M16Al = (uint16_t*)alloc((size_t)NLAYERS * MB1 * 2);
  uint16_t* M128Ah = (uint16_t*)alloc((size_t)NLAYERS * MB1 * 2);
  uint16_t* M128Al = (uint16_t*)alloc((size_t)NLAYERS * MB1 * 2);
  uint16_t* G3h0 = (uint16_t*)alloc((size_t)256 * 1024 * 2);
  uint16_t* G3l0 = (uint16_t*)alloc((size_t)256 * 1024 * 2);
  uint16_t* G3h1 = (uint16_t*)alloc((size_t)256 * 1024 * 2);
  uint16_t* G3l1 = (uint16_t*)alloc((size_t)256 * 1024 * 2);
  uint16_t* BEh = (uint16_t*)alloc((size_t)8 * 16 * 1024 * 2);
  uint16_t* BEl = (uint16_t*)alloc((size_t)8 * 16 * 1024 * 2);
  float* LAMf = (float*)alloc((size_t)8 * 32 * 1024 * 4);
  uint16_t* LAMh = (uint16_t*)alloc((size_t)8 * 32 * 1024 * 2);
  uint16_t* LAMl = (uint16_t*)alloc((size_t)8 * 32 * 1024 * 2);
  uint16_t* GSh0 = (uint16_t*)alloc((size_t)32 * 1024 * 2);
  uint16_t* GSl0 = (uint16_t*)alloc((size_t)32 * 1024 * 2);
  uint16_t* GSh1 = (uint16_t*)alloc((size_t)32 * 1024 * 2);
  uint16_t* GSl1 = (uint16_t*)alloc((size_t)32 * 1024 * 2);
  uint16_t* YSB = (uint16_t*)alloc(TB * DIMX * 2);
  uint16_t* OWB = (uint16_t*)alloc((size_t)VOCAB * DIMX * 2);

  // power-chain ping-pong buffers overlaid on P / S / H[1] (all rewritten after powers)
  uint16_t* CMh[2] = {(uint16_t*)P, Sh};
  uint16_t* CMl[2] = {(uint16_t*)P + 4 * MB1, Sl};
  uint16_t* CTh[2] = {(uint16_t*)P + 8 * MB1, Hh[1]};
  uint16_t* CTl[2] = {(uint16_t*)P + 12 * MB1, Hl[1]};

  hipMemsetAsync(SYNC, 0, (size_t)NLAYERS * 8192 * 4, stream);
  k_split_w<<<NLAYERS * 4096, 256, 0, stream>>>(W, W1h, W1l, WSh, WSl, M1h, M1l);
  k_trans_w<<<dim3(16, 16, NLAYERS), 256, 0, stream>>>(W, T1h, T1l);
  k_cast_w<<<(int)((size_t)VOCAB * DIMX / 4 / 256), 256, 0, stream>>>(outw, OWB, VOCAB * DIMX / 4);
  k_embed_split<<<(int)(TB * DIMX / 4 / 256), 256, 0, stream>>>(ids, emb, Hh[0], Hl[0]);

  // power chain: level k -> A^(2^k); M_k = NT(M_{k-1}, T_{k-1}); T_k via transposed O2 write.
  {
    const uint16_t *inMh = M1h, *inMl = M1l, *inTh = T1h, *inTl = T1l;
    for (int k = 1; k <= 7; ++k) {
      uint16_t *oMh, *oMl;
      if (k == 4) { oMh = M16Ah; oMl = M16Al; }
      else if (k == 7) { oMh = M128Ah; oMl = M128Al; }
      else { oMh = CMh[k & 1]; oMl = CMl[k & 1]; }
      uint16_t* oTh = (k < 7) ? CTh[k & 1] : nullptr;
      uint16_t* oTl = (k < 7) ? CTl[k & 1] : nullptr;
      k_mfma<128, 128><<<dim3(8, 8, NLAYERS), 256, 0, stream>>>(
          1024,
          inMh, inMl, 4096, 1024, MB1,
          inTh, inTl, 1024, MB1,
          nullptr, 0, 0,
          nullptr, 0, 0,
          oMh, oMl, 4096, 1024, 0, MB1,
          oTh, oTl, 1024, 0, MB1);
      inMh = oMh; inMl = oMl; inTh = oTh; inTl = oTl;
    }
  }

  int cur = 0;
  for (int l = 0; l < NLAYERS; ++l) {
    // [a|u] = H @ W[:,0:1024]^T ; f32 -> P, split(u) -> PU
    k_mfma<128, 128><<<dim3(16, 32, 1), 256, 0, stream>>>(
        1024,
        Hh[cur], Hl[cur], 4096, 1024, 0,
        W1h + (size_t)l * 2048 * 1024, W1l + (size_t)l * 2048 * 1024, 1024, 0,
        nullptr, 0, 0,
        P, 8192, 2048,
        PUh, PUl, 4096, 1024, 1024, 0,
        nullptr, nullptr, 0, 1, 0);

    // persistent: phase1 + phase2 + phase3
    k_layer<<<NBLK, 256, 0, stream>>>(
        SYNC + (size_t)l * 8192, SYNC + (size_t)l * 8192 + 4096,
        P, PUh, PUl, Sh, Sl,
        M1h + (size_t)l * MB1, M1l + (size_t)l * MB1,
        M16Ah + (size_t)l * MB1, M16Al + (size_t)l * MB1,
        M128Ah + (size_t)l * MB1, M128Al + (size_t)l * MB1,
        G3h0, G3l0, G3h1, G3l1,
        BEh, BEl, LAMf, LAMh, LAMl,
        GSh0, GSl0, GSh1, GSl1,
        starter + (size_t)l * DIMX);

    // H_next = a + S @ W_hs^T (split out)
    k_mfma<128, 128><<<dim3(8, 32, 1), 256, 0, stream>>>(
        1024,
        Sh, Sl, 4096, 1024, 0,
        WSh + (size_t)l * MB1, WSl + (size_t)l * MB1, 1024, 0,
        P, 8192, 2048,
        nullptr, 0, 0,
        Hh[cur ^ 1], Hl[cur ^ 1], 4096, 1024, 0, 0,
        nullptr, nullptr, 0, 1, 0);
    cur ^= 1;
  }

  k_reorder_hi<<<(int)(TB * DIMX / 4 / 256), 256, 0, stream>>>(Hh[cur], YSB);
  k_logits<<<dim3(VOCAB / 128, TB / 128), 256, 0, stream>>>(YSB, OWB, out);
}

// Round 6
// 6676.796 us; speedup vs baseline: 1.8758x; 1.8758x over previous
//
#include <hip/hip_runtime.h>
#include <hip/hip_bf16.h>
#include <stdint.h>

#define BATCH 4
#define SEQ 1024
#define DIMX 1024
#define VOCAB 32000
#define NLAYERS 4
#define NBLK 256   // blocks in persistent kernel (1/CU)

using bf16x8 = __attribute__((ext_vector_type(8))) short;
using f32x4v = __attribute__((ext_vector_type(4))) float;

__device__ __forceinline__ uint16_t f2b(float f) {
  __hip_bfloat16 h = __float2bfloat16(f);
  return *reinterpret_cast<uint16_t*>(&h);
}
__device__ __forceinline__ float b2f(uint16_t u) {
  __hip_bfloat16 h = *reinterpret_cast<__hip_bfloat16*>(&u);
  return __bfloat162float(h);
}
__device__ __forceinline__ void fsplit(float v, uint16_t& h, uint16_t& l) {
  h = f2b(v);
  l = f2b(v - b2f(h));
}

// ---------------- embedding gather -> split bf16: row (t*4+b)
__global__ __launch_bounds__(256) void k_embed_split(const int* __restrict__ ids,
                                                     const float* __restrict__ emb,
                                                     uint16_t* __restrict__ Hhi,
                                                     uint16_t* __restrict__ Hlo) {
  int idx = blockIdx.x * 256 + threadIdx.x;
  int d4 = idx & (DIMX / 4 - 1);
  int tb = idx >> 8;
  int t = tb >> 2, b = tb & 3;
  int id = ids[b * SEQ + t];
  float4 v = reinterpret_cast<const float4*>(emb + (size_t)id * DIMX)[d4];
  ushort4 h, l;
  fsplit(v.x, h.x, l.x); fsplit(v.y, h.y, l.y); fsplit(v.z, h.z, l.z); fsplit(v.w, h.w, l.w);
  reinterpret_cast<ushort4*>(Hhi)[idx] = h;
  reinterpret_cast<ushort4*>(Hlo)[idx] = l;
}

// ---------------- split all layers' weights: W1 (2048 rows), WS (1024), M1=Wss (1024)
__global__ __launch_bounds__(256) void k_split_w(const float* __restrict__ W,
                                                 uint16_t* __restrict__ W1h, uint16_t* __restrict__ W1l,
                                                 uint16_t* __restrict__ WSh, uint16_t* __restrict__ WSl,
                                                 uint16_t* __restrict__ M1h, uint16_t* __restrict__ M1l) {
  int idx = blockIdx.x * 256 + threadIdx.x;
  int c4 = idx & 255;
  int row = idx >> 8;
  int l = row >> 12, r = row & 4095;
  const float* Wl = W + (size_t)l * 4 * 1024 * 1024;
  const float* src;
  uint16_t *dh, *dl;
  size_t doff;
  if (r < 2048) { src = Wl + (size_t)r * 2048; dh = W1h; dl = W1l; doff = ((size_t)l * 2048 + r) * 1024; }
  else if (r < 3072) { int rr = r - 2048; src = Wl + (size_t)rr * 2048 + 1024; dh = WSh; dl = WSl; doff = ((size_t)l * 1024 + rr) * 1024; }
  else { int rr = r - 3072; src = Wl + (size_t)(1024 + rr) * 2048 + 1024; dh = M1h; dl = M1l; doff = ((size_t)l * 1024 + rr) * 1024; }
  float4 v = reinterpret_cast<const float4*>(src)[c4];
  ushort4 h, lo4;
  fsplit(v.x, h.x, lo4.x); fsplit(v.y, h.y, lo4.y); fsplit(v.z, h.z, lo4.z); fsplit(v.w, h.w, lo4.w);
  reinterpret_cast<ushort4*>(dh + doff)[c4] = h;
  reinterpret_cast<ushort4*>(dl + doff)[c4] = lo4;
}

// ---------------- T1 = Wss^T per layer (LDS-tiled transpose + split)
__global__ __launch_bounds__(256) void k_trans_w(const float* __restrict__ W,
                                                 uint16_t* __restrict__ T1h, uint16_t* __restrict__ T1l) {
  __shared__ float t[64][65];
  int l = blockIdx.z;
  const float* Wl = W + (size_t)l * 4 * 1024 * 1024;
  int i0 = blockIdx.y * 64, j0 = blockIdx.x * 64;
  int c4 = (threadIdx.x & 15) * 4, rr = threadIdx.x >> 4;
#pragma unroll
  for (int p = 0; p < 4; ++p) {
    int r = rr + p * 16;
    float4 v = *reinterpret_cast<const float4*>(Wl + (size_t)(1024 + i0 + r) * 2048 + 1024 + j0 + c4);
    t[r][c4] = v.x; t[r][c4 + 1] = v.y; t[r][c4 + 2] = v.z; t[r][c4 + 3] = v.w;
  }
  __syncthreads();
#pragma unroll
  for (int p = 0; p < 4; ++p) {
    int j = rr + p * 16;
    ushort4 h, l4;
    fsplit(t[c4 + 0][j], h.x, l4.x);
    fsplit(t[c4 + 1][j], h.y, l4.y);
    fsplit(t[c4 + 2][j], h.z, l4.z);
    fsplit(t[c4 + 3][j], h.w, l4.w);
    size_t o = (size_t)l * 1024 * 1024 + (size_t)(j0 + j) * 1024 + i0 + c4;
    *reinterpret_cast<ushort4*>(T1h + o) = h;
    *reinterpret_cast<ushort4*>(T1l + o) = l4;
  }
}

// ---------------- split-bf16 MFMA GEMM (NT), 128x128 tile, optional z-batch.
// O2: if o2_bs==0 -> transposed split(dot) at [n*o2_cs + m]; else strided split(dot).
template <int BM, int BN>
__global__ __launch_bounds__(256) void k_mfma(
    int K,
    const uint16_t* __restrict__ Ahi, const uint16_t* __restrict__ Alo, int a_cs, int a_bs, size_t a_z,
    const uint16_t* __restrict__ Bhi, const uint16_t* __restrict__ Blo, int ldb, size_t b_z,
    const float* __restrict__ ADD, int add_cs, int add_bs,
    float* __restrict__ O1f, int o1_cs, int o1_bs,
    uint16_t* __restrict__ O1hi, uint16_t* __restrict__ O1lo, int o1s_cs, int o1s_bs, int split_n0, size_t o1_z,
    uint16_t* __restrict__ O2hi, uint16_t* __restrict__ O2lo, int o2_cs, int o2_bs, size_t o2_z) {
  constexpr int FM = BM / 32;
  constexpr int FN = BN / 32;
  __shared__ uint16_t sAh[BM * 32], sAl[BM * 32], sBh[BN * 32], sBl[BN * 32];
  size_t zb = blockIdx.z;
  Ahi += zb * a_z; Alo += zb * a_z;
  Bhi += zb * b_z; Blo += zb * b_z;
  if (O1hi) { O1hi += zb * o1_z; O1lo += zb * o1_z; }
  if (O2hi) { O2hi += zb * o2_z; O2lo += zb * o2_z; }
  int tid = threadIdx.x;
  int lane = tid & 63;
  int wave = tid >> 6;
  int wm = wave >> 1, wn = wave & 1;
  int m0 = blockIdx.y * BM, n0 = blockIdx.x * BN;
  f32x4v acc[FM][FN] = {};
  for (int kt = 0; kt < K; kt += 32) {
    __syncthreads();
#pragma unroll
    for (int q = 0; q < BM / 64; ++q) {
      int off = q * 4096 + tid * 16;
      int r = off >> 6;
      int cu = (off & 63) >> 1;
      size_t goff = (size_t)(m0 / 4 + (r >> 2)) * a_cs + (size_t)(r & 3) * a_bs + kt + cu;
      __builtin_amdgcn_global_load_lds(
          (const __attribute__((address_space(1))) uint32_t*)(Ahi + goff),
          (__attribute__((address_space(3))) uint32_t*)((char*)sAh + off), 16, 0, 0);
      __builtin_amdgcn_global_load_lds(
          (const __attribute__((address_space(1))) uint32_t*)(Alo + goff),
          (__attribute__((address_space(3))) uint32_t*)((char*)sAl + off), 16, 0, 0);
    }
#pragma unroll
    for (int q = 0; q < BN / 64; ++q) {
      int off = q * 4096 + tid * 16;
      int r = off >> 6, cu = (off & 63) >> 1;
      size_t goff = (size_t)(n0 + r) * ldb + kt + cu;
      __builtin_amdgcn_global_load_lds(
          (const __attribute__((address_space(1))) uint32_t*)(Bhi + goff),
          (__attribute__((address_space(3))) uint32_t*)((char*)sBh + off), 16, 0, 0);
      __builtin_amdgcn_global_load_lds(
          (const __attribute__((address_space(1))) uint32_t*)(Blo + goff),
          (__attribute__((address_space(3))) uint32_t*)((char*)sBl + off), 16, 0, 0);
    }
    __syncthreads();
    int rsel = lane & 15, ko = (lane >> 4) * 8;
    bf16x8 ah[FM], al[FM], bh[FN], bl[FN];
#pragma unroll
    for (int mf = 0; mf < FM; ++mf) {
      int row = wm * (FM * 16) + mf * 16 + rsel;
      ah[mf] = *reinterpret_cast<const bf16x8*>(sAh + row * 32 + ko);
      al[mf] = *reinterpret_cast<const bf16x8*>(sAl + row * 32 + ko);
    }
#pragma unroll
    for (int nf = 0; nf < FN; ++nf) {
      int row = wn * (FN * 16) + nf * 16 + rsel;
      bh[nf] = *reinterpret_cast<const bf16x8*>(sBh + row * 32 + ko);
      bl[nf] = *reinterpret_cast<const bf16x8*>(sBl + row * 32 + ko);
    }
#pragma unroll
    for (int mf = 0; mf < FM; ++mf)
#pragma unroll
      for (int nf = 0; nf < FN; ++nf) {
        acc[mf][nf] = __builtin_amdgcn_mfma_f32_16x16x32_bf16(ah[mf], bh[nf], acc[mf][nf], 0, 0, 0);
        acc[mf][nf] = __builtin_amdgcn_mfma_f32_16x16x32_bf16(ah[mf], bl[nf], acc[mf][nf], 0, 0, 0);
        acc[mf][nf] = __builtin_amdgcn_mfma_f32_16x16x32_bf16(al[mf], bh[nf], acc[mf][nf], 0, 0, 0);
      }
  }
  int rowg = (lane >> 4) * 4, colg = lane & 15;
#pragma unroll
  for (int mf = 0; mf < FM; ++mf)
#pragma unroll
    for (int nf = 0; nf < FN; ++nf)
#pragma unroll
      for (int r = 0; r < 4; ++r) {
        int m = m0 + wm * (FM * 16) + mf * 16 + rowg + r;
        int n = n0 + wn * (FN * 16) + nf * 16 + colg;
        size_t ro = (size_t)(m >> 2);
        float dot = acc[mf][nf][r];
        float v = dot;
        if (ADD) v += ADD[ro * add_cs + (size_t)(m & 3) * add_bs + n];
        if (O1f) O1f[ro * o1_cs + (size_t)(m & 3) * o1_bs + n] = v;
        if (O1hi && n >= split_n0) {
          uint16_t h, l;
          fsplit(v, h, l);
          size_t o = ro * o1s_cs + (size_t)(m & 3) * o1s_bs + (n - split_n0);
          O1hi[o] = h; O1lo[o] = l;
        }
        if (O2hi) {
          uint16_t h, l;
          fsplit(dot, h, l);
          size_t o = (o2_bs == 0) ? ((size_t)n * o2_cs + m)
                                  : (ro * o2_cs + (size_t)(m & 3) * o2_bs + n);
          O2hi[o] = h; O2lo[o] = l;
        }
      }
}

// ---------------- slot barrier with RELAXED polling.
// Round-5 lesson: ACQUIRE-polling emits an L2-invalidate per poll iteration (agent scope
// on non-coherent per-XCD L2) -> continuous cache-op storm + loss of all L2 residency
// (~50us/step). Fix: poll with RELAXED atomic loads (coherent, no cache ops), then issue
// exactly ONE acquire fence per block after the poll exits. One release store + one
// acquire fence per block per step total.
__device__ __forceinline__ void gbar(uint32_t* slots, uint32_t* release, uint32_t& gen) {
  __syncthreads();
  gen++;
  if (threadIdx.x == 0)
    __hip_atomic_store(slots + (size_t)blockIdx.x * 16, gen, __ATOMIC_RELEASE, __HIP_MEMORY_SCOPE_AGENT);
  if (blockIdx.x == 0) {
    while (__hip_atomic_load(slots + (size_t)threadIdx.x * 16, __ATOMIC_RELAXED, __HIP_MEMORY_SCOPE_AGENT) < gen)
      __builtin_amdgcn_s_sleep(2);
    __syncthreads();
    if (threadIdx.x == 0) {
      __builtin_amdgcn_fence(__ATOMIC_ACQUIRE, "agent");   // single L2 inv for this block
      __hip_atomic_store(release, gen, __ATOMIC_RELEASE, __HIP_MEMORY_SCOPE_AGENT);
    }
    __syncthreads();
  } else {
    if (threadIdx.x == 0) {
      while (__hip_atomic_load(release, __ATOMIC_RELAXED, __HIP_MEMORY_SCOPE_AGENT) < gen)
        __builtin_amdgcn_s_sleep(2);
      __builtin_amdgcn_fence(__ATOMIC_ACQUIRE, "agent");   // single L2 inv for this block
    }
    __syncthreads();
  }
}

// per-wave 16x16 NT tile, K=1024, B dense [n][1024], split operands, direct global loads
__device__ __forceinline__ f32x4v wtile16(
    const uint16_t* __restrict__ Ah, const uint16_t* __restrict__ Al,
    int a_cs, int a_bs, int m0,
    const uint16_t* __restrict__ Bh, const uint16_t* __restrict__ Bl,
    int n0, int lane) {
  int rsel = lane & 15, ko = (lane >> 4) * 8;
  int am = m0 + rsel;
  const uint16_t* pah = Ah + (size_t)(am >> 2) * a_cs + (size_t)(am & 3) * a_bs + ko;
  const uint16_t* pal = Al + (size_t)(am >> 2) * a_cs + (size_t)(am & 3) * a_bs + ko;
  const uint16_t* pbh = Bh + (size_t)(n0 + rsel) * 1024 + ko;
  const uint16_t* pbl = Bl + (size_t)(n0 + rsel) * 1024 + ko;
  f32x4v acc = {0.f, 0.f, 0.f, 0.f};
#pragma unroll 4
  for (int kt = 0; kt < 1024; kt += 32) {
    bf16x8 ah = *reinterpret_cast<const bf16x8*>(pah + kt);
    bf16x8 al = *reinterpret_cast<const bf16x8*>(pal + kt);
    bf16x8 bh = *reinterpret_cast<const bf16x8*>(pbh + kt);
    bf16x8 bl = *reinterpret_cast<const bf16x8*>(pbl + kt);
    acc = __builtin_amdgcn_mfma_f32_16x16x32_bf16(ah, bh, acc, 0, 0, 0);
    acc = __builtin_amdgcn_mfma_f32_16x16x32_bf16(ah, bl, acc, 0, 0, 0);
    acc = __builtin_amdgcn_mfma_f32_16x16x32_bf16(al, bh, acc, 0, 0, 0);
  }
  return acc;
}

// ---------------- persistent per-layer kernel: 3-phase chunked scan (powers precomputed)
__global__ __launch_bounds__(256) void k_layer(
    uint32_t* slots, uint32_t* release,
    float* __restrict__ P,
    uint16_t* __restrict__ PUh, uint16_t* __restrict__ PUl,
    uint16_t* __restrict__ Sh, uint16_t* __restrict__ Sl,
    const uint16_t* __restrict__ M1h, const uint16_t* __restrict__ M1l,
    const uint16_t* __restrict__ M16h, const uint16_t* __restrict__ M16l,
    const uint16_t* __restrict__ M128h, const uint16_t* __restrict__ M128l,
    uint16_t* G3h0, uint16_t* G3l0, uint16_t* G3h1, uint16_t* G3l1,
    uint16_t* BEh, uint16_t* BEl,
    float* LAMf, uint16_t* LAMh, uint16_t* LAMl,
    uint16_t* GSh0, uint16_t* GSl0, uint16_t* GSh1, uint16_t* GSl1,
    const float* __restrict__ starterL) {
  int tid = threadIdx.x, bid = blockIdx.x;
  int lane = tid & 63;
  int wv = tid >> 6;                  // 0..3
  int xcd = bid & 7;
  int gix = (bid >> 3) * 4 + wv;      // 0..127 within this XCD's wave group
  uint32_t gen = 0;
  int rowg = (lane >> 4) * 4, colg = lane & 15;

  // init: sigma_0 = starter broadcast -> beta[0], G3[0] rows (c=0), GS[0] rows (g=0), S t=0
  {
    int idx = bid * 256 + tid;
    if (idx < BATCH * DIMX) {
      int b = idx >> 10, d = idx & 1023;
      float v = starterL[d];
      uint16_t h, l;
      fsplit(v, h, l);
      size_t o = (size_t)b * 1024 + d;
      BEh[o] = h; BEl[o] = l;
      G3h0[o] = h; G3l0[o] = l;
      GSh0[o] = h; GSl0[o] = l;
      Sh[o] = h; Sl[o] = l;
    }
  }

  // ---- phase 1: local scans l_j = A l_{j-1} + u_j, j=1..15  (in place over P u-half)
  for (int j = 1; j < 16; ++j) {
    {
      int mt = gix >> 3, nt = xcd * 8 + (gix & 7);
      int m0 = mt * 16, n0 = nt * 16;
      f32x4v acc = wtile16(PUh + (size_t)(j - 1) * 4096, PUl + (size_t)(j - 1) * 4096,
                           65536, 1024, m0, M1h, M1l, n0, lane);
      int n = n0 + colg;
#pragma unroll
      for (int rr = 0; rr < 4; ++rr) {
        int m = m0 + rowg + rr;
        int c = m >> 2, b = m & 3;
        size_t t = (size_t)(c * 16 + j);
        float* pu = P + (t * 4 + b) * 2048 + 1024 + n;
        float v = acc[rr] + *pu;
        *pu = v;
        uint16_t h, l;
        fsplit(v, h, l);
        size_t o = (t * 4 + b) * 1024 + n;
        PUh[o] = h; PUl[o] = l;
      }
    }
    gbar(slots, release, gen);
  }

  // ---- phase 2a init: lambda_0 = e_{8g} (chunk-end values)
  {
    int idx = bid * 256 + tid;
    if (idx < 32 * 1024) {
      int r = idx >> 10, d = idx & 1023;
      int g = r >> 2, b = r & 3;
      float v = P[((size_t)(g * 128 + 15) * 4 + b) * 2048 + 1024 + d];
      LAMf[idx] = v;
      uint16_t h, l;
      fsplit(v, h, l);
      LAMh[idx] = h; LAMl[idx] = l;
    }
  }
  gbar(slots, release, gen);

  // ---- phase 2a: lambda_j = A16 lambda_{j-1} + e_{8g+j}, j=1..7
  for (int j = 1; j < 8; ++j) {
    if (gix < 16) {
      int mt = gix >> 3, nt = xcd * 8 + (gix & 7);
      int m0 = mt * 16, n0 = nt * 16;
      f32x4v acc = wtile16(LAMh + (size_t)(j - 1) * 32768, LAMl + (size_t)(j - 1) * 32768,
                           4096, 1024, m0, M16h, M16l, n0, lane);
      int n = n0 + colg;
#pragma unroll
      for (int rr = 0; rr < 4; ++rr) {
        int m = m0 + rowg + rr;
        int g = m >> 2, b = m & 3;
        int c = 8 * g + j;
        float e = P[((size_t)(c * 16 + 15) * 4 + b) * 2048 + 1024 + n];
        float v = acc[rr] + e;
        size_t o = (size_t)j * 32768 + (size_t)m * 1024 + n;
        LAMf[o] = v;
        uint16_t h, l;
        fsplit(v, h, l);
        LAMh[o] = h; LAMl[o] = l;
      }
    }
    gbar(slots, release, gen);
  }

  // ---- phase 2b: beta_{g+1} = A128 beta_g + lambda_7(g), g=0..6 (rows padded to 16)
  for (int g = 0; g < 7; ++g) {
    if (gix < 8) {
      int n0 = (xcd * 8 + gix) * 16;
      f32x4v acc = wtile16(BEh + (size_t)g * 16384, BEl + (size_t)g * 16384,
                           4096, 1024, 0, M128h, M128l, n0, lane);
      if ((lane >> 4) == 0) {
        int n = n0 + colg;
#pragma unroll
        for (int rr = 0; rr < 4; ++rr) {
          int b = rr;
          float v = acc[rr] + LAMf[(size_t)7 * 32768 + (size_t)(g * 4 + b) * 1024 + n];
          uint16_t h, l;
          fsplit(v, h, l);
          size_t ob = (size_t)(g + 1) * 16384 + (size_t)b * 1024 + n;
          BEh[ob] = h; BEl[ob] = l;
          int c = 8 * (g + 1);
          size_t o1 = (size_t)(c * 4 + b) * 1024 + n;
          G3h0[o1] = h; G3l0[o1] = l;
          size_t o2 = ((size_t)(c * 16) * 4 + b) * 1024 + n;
          Sh[o2] = h; Sl[o2] = l;
          size_t o3 = (size_t)((g + 1) * 4 + b) * 1024 + n;
          GSh0[o3] = h; GSl0[o3] = l;
        }
      }
    }
    gbar(slots, release, gen);
  }

  // ---- phase 2c: Gs_j = A16 Gs_{j-1}; sigma_{8g+j} = Gs_j + lambda_{j-1}, j=1..7
  int gsc = 0;
  for (int j = 1; j < 8; ++j) {
    uint16_t* gih = gsc ? GSh1 : GSh0;
    uint16_t* gil = gsc ? GSl1 : GSl0;
    uint16_t* goh = gsc ? GSh0 : GSh1;
    uint16_t* gol = gsc ? GSl0 : GSl1;
    if (gix < 16) {
      int mt = gix >> 3, nt = xcd * 8 + (gix & 7);
      int m0 = mt * 16, n0 = nt * 16;
      f32x4v acc = wtile16(gih, gil, 4096, 1024, m0, M16h, M16l, n0, lane);
      int n = n0 + colg;
#pragma unroll
      for (int rr = 0; rr < 4; ++rr) {
        int m = m0 + rowg + rr;
        int g = m >> 2, b = m & 3;
        int c = 8 * g + j;
        float lam = LAMf[(size_t)(j - 1) * 32768 + (size_t)m * 1024 + n];
        float v = acc[rr] + lam;
        uint16_t h, l;
        fsplit(v, h, l);
        size_t o1 = (size_t)(c * 4 + b) * 1024 + n;
        G3h0[o1] = h; G3l0[o1] = l;
        size_t o2 = ((size_t)(c * 16) * 4 + b) * 1024 + n;
        Sh[o2] = h; Sl[o2] = l;
        uint16_t h2, l2;
        fsplit(acc[rr], h2, l2);
        goh[(size_t)m * 1024 + n] = h2;
        gol[(size_t)m * 1024 + n] = l2;
      }
    }
    gbar(slots, release, gen);
    gsc ^= 1;
  }

  // ---- phase 3: G_j = A G_{j-1}; S[c*16+j] = G_j + l_{c*16+j-1}, j=1..15
  int g3 = 0;
  for (int j = 1; j < 16; ++j) {
    uint16_t* gih = g3 ? G3h1 : G3h0;
    uint16_t* gil = g3 ? G3l1 : G3l0;
    uint16_t* goh = g3 ? G3h0 : G3h1;
    uint16_t* gol = g3 ? G3l0 : G3l1;
    {
      int mt = gix >> 3, nt = xcd * 8 + (gix & 7);
      int m0 = mt * 16, n0 = nt * 16;
      f32x4v acc = wtile16(gih, gil, 4096, 1024, m0, M1h, M1l, n0, lane);
      int n = n0 + colg;
#pragma unroll
      for (int rr = 0; rr < 4; ++rr) {
        int m = m0 + rowg + rr;
        int c = m >> 2, b = m & 3;
        float u = P[((size_t)(c * 16 + j - 1) * 4 + b) * 2048 + 1024 + n];
        float v = acc[rr] + u;
        uint16_t h, l;
        fsplit(v, h, l);
        size_t o = ((size_t)(c * 16 + j) * 4 + b) * 1024 + n;
        Sh[o] = h; Sl[o] = l;
        uint16_t h2, l2;
        fsplit(acc[rr], h2, l2);
        goh[(size_t)m * 1024 + n] = h2;
        gol[(size_t)m * 1024 + n] = l2;
      }
    }
    if (j < 15) gbar(slots, release, gen);
    g3 ^= 1;
  }
}

// ---------------- reorder H_hi [t][b][d] -> Y [b][t][d]
__global__ __launch_bounds__(256) void k_reorder_hi(const uint16_t* __restrict__ Hhi, uint16_t* __restrict__ Y) {
  int idx = blockIdx.x * 256 + threadIdx.x;
  int d4 = idx & (DIMX / 4 - 1);
  int tb = idx >> 8;
  int t = tb >> 2, b = tb & 3;
  ushort4 v = reinterpret_cast<const ushort4*>(Hhi)[idx];
  reinterpret_cast<ushort4*>(Y + (size_t)(b * SEQ + t) * DIMX)[d4] = v;
}

__global__ __launch_bounds__(256) void k_cast_w(const float* __restrict__ src, uint16_t* __restrict__ dst, int n4) {
  int idx = blockIdx.x * 256 + threadIdx.x;
  if (idx >= n4) return;
  float4 v = reinterpret_cast<const float4*>(src)[idx];
  ushort4 o;
  o.x = f2b(v.x); o.y = f2b(v.y); o.z = f2b(v.z); o.w = f2b(v.w);
  reinterpret_cast<ushort4*>(dst)[idx] = o;
}

// ---------------- logits GEMM: bf16 MFMA 128x128
__global__ __launch_bounds__(256) void k_logits(const uint16_t* __restrict__ A,
                                                const uint16_t* __restrict__ Bt,
                                                float* __restrict__ C) {
  __shared__ uint16_t As[128 * 32];
  __shared__ uint16_t Bs[128 * 32];
  int tid = threadIdx.x;
  int bx = blockIdx.x, by = blockIdx.y;
  int lane = tid & 63, wave = tid >> 6;
  int wm = wave >> 1, wn = wave & 1;
  f32x4v acc[4][4] = {};
  const uint16_t* Ag = A + (size_t)by * 128 * 1024;
  const uint16_t* Bg = Bt + (size_t)bx * 128 * 1024;
  for (int kt = 0; kt < 1024; kt += 32) {
    __syncthreads();
#pragma unroll
    for (int q = 0; q < 2; ++q) {
      int off = q * 4096 + tid * 16;
      int r = off >> 6, cu = (off & 63) >> 1;
      __builtin_amdgcn_global_load_lds(
          (const __attribute__((address_space(1))) uint32_t*)(Ag + (size_t)r * 1024 + kt + cu),
          (__attribute__((address_space(3))) uint32_t*)((char*)As + off), 16, 0, 0);
      __builtin_amdgcn_global_load_lds(
          (const __attribute__((address_space(1))) uint32_t*)(Bg + (size_t)r * 1024 + kt + cu),
          (__attribute__((address_space(3))) uint32_t*)((char*)Bs + off), 16, 0, 0);
    }
    __syncthreads();
    int rsel = lane & 15, ko = (lane >> 4) * 8;
    bf16x8 af[4], bfr[4];
#pragma unroll
    for (int mf = 0; mf < 4; ++mf)
      af[mf] = *reinterpret_cast<const bf16x8*>(As + (wm * 64 + mf * 16 + rsel) * 32 + ko);
#pragma unroll
    for (int nf = 0; nf < 4; ++nf)
      bfr[nf] = *reinterpret_cast<const bf16x8*>(Bs + (wn * 64 + nf * 16 + rsel) * 32 + ko);
#pragma unroll
    for (int mf = 0; mf < 4; ++mf)
#pragma unroll
      for (int nf = 0; nf < 4; ++nf)
        acc[mf][nf] = __builtin_amdgcn_mfma_f32_16x16x32_bf16(af[mf], bfr[nf], acc[mf][nf], 0, 0, 0);
  }
  int rowg = (lane >> 4) * 4;
  int colg = lane & 15;
#pragma unroll
  for (int mf = 0; mf < 4; ++mf)
#pragma unroll
    for (int nf = 0; nf < 4; ++nf)
#pragma unroll
      for (int r = 0; r < 4; ++r) {
        int m = by * 128 + wm * 64 + mf * 16 + rowg + r;
        int n = bx * 128 + wn * 64 + nf * 16 + colg;
        C[(size_t)m * VOCAB + n] = acc[mf][nf][r];
      }
}

// =========================================================================
extern "C" void kernel_launch(void* const* d_in, const int* in_sizes, int n_in,
                              void* d_out, int out_size, void* d_ws, size_t ws_size,
                              hipStream_t stream) {
  const int* ids = (const int*)d_in[0];
  const float* emb = (const float*)d_in[1];
  const float* W = (const float*)d_in[2];
  const float* outw = (const float*)d_in[3];
  const float* starter = (const float*)d_in[4];
  float* out = (float*)d_out;

  char* wsb = (char*)d_ws;
  size_t off = 0;
  auto alloc = [&](size_t bytes) {
    void* p = wsb + off;
    off = (off + bytes + 255) & ~(size_t)255;
    return p;
  };
  const size_t TB = SEQ * BATCH;
  const size_t MB1 = (size_t)1024 * 1024;

  // per-layer sync region: 256 slots * 16 words + release word at word 4096
  uint32_t* SYNC = (uint32_t*)alloc((size_t)NLAYERS * 8192 * 4);
  uint16_t* Hh[2] = {(uint16_t*)alloc(TB * DIMX * 2), (uint16_t*)alloc(TB * DIMX * 2)};
  uint16_t* Hl[2] = {(uint16_t*)alloc(TB * DIMX * 2), (uint16_t*)alloc(TB * DIMX * 2)};
  float* P = (float*)alloc(TB * 2 * DIMX * 4);
  uint16_t* PUh = (uint16_t*)alloc(TB * DIMX * 2);
  uint16_t* PUl = (uint16_t*)alloc(TB * DIMX * 2);
  uint16_t* Sh = (uint16_t*)alloc(TB * DIMX * 2);
  uint16_t* Sl = (uint16_t*)alloc(TB * DIMX * 2);
  uint16_t* W1h = (uint16_t*)alloc((size_t)NLAYERS * 2048 * 1024 * 2);
  uint16_t* W1l = (uint16_t*)alloc((size_t)NLAYERS * 2048 * 1024 * 2);
  uint16_t* WSh = (uint16_t*)alloc((size_t)NLAYERS * MB1 * 2);
  uint16_t* WSl = (uint16_t*)alloc((size_t)NLAYERS * MB1 * 2);
  uint16_t* M1h = (uint16_t*)alloc((size_t)NLAYERS * MB1 * 2);
  uint16_t* M1l = (uint16_t*)alloc((size_t)NLAYERS * MB1 * 2);
  uint16_t* T1h = (uint16_t*)alloc((size_t)NLAYERS * MB1 * 2);
  uint16_t* T1l = (uint16_t*)alloc((size_t)NLAYERS * MB1 * 2);
  uint16_t* M16Ah = (uint16_t*)alloc((size_t)NLAYERS * MB1 * 2);
  uint16_t* M16Al = (uint16_t*)alloc((size_t)NLAYERS * MB1 * 2);
  uint16_t* M128Ah = (uint16_t*)alloc((size_t)NLAYERS * MB1 * 2);
  uint16_t* M128Al = (uint16_t*)alloc((size_t)NLAYERS * MB1 * 2);
  uint16_t* G3h0 = (uint16_t*)alloc((size_t)256 * 1024 * 2);
  uint16_t* G3l0 = (uint16_t*)alloc((size_t)256 * 1024 * 2);
  uint16_t* G3h1 = (uint16_t*)alloc((size_t)256 * 1024 * 2);
  uint16_t* G3l1 = (uint16_t*)alloc((size_t)256 * 1024 * 2);
  uint16_t* BEh = (uint16_t*)alloc((size_t)8 * 16 * 1024 * 2);
  uint16_t* BEl = (uint16_t*)alloc((size_t)8 * 16 * 1024 * 2);
  float* LAMf = (float*)alloc((size_t)8 * 32 * 1024 * 4);
  uint16_t* LAMh = (uint16_t*)alloc((size_t)8 * 32 * 1024 * 2);
  uint16_t* LAMl = (uint16_t*)alloc((size_t)8 * 32 * 1024 * 2);
  uint16_t* GSh0 = (uint16_t*)alloc((size_t)32 * 1024 * 2);
  uint16_t* GSl0 = (uint16_t*)alloc((size_t)32 * 1024 * 2);
  uint16_t* GSh1 = (uint16_t*)alloc((size_t)32 * 1024 * 2);
  uint16_t* GSl1 = (uint16_t*)alloc((size_t)32 * 1024 * 2);
  uint16_t* YSB = (uint16_t*)alloc(TB * DIMX * 2);
  uint16_t* OWB = (uint16_t*)alloc((size_t)VOCAB * DIMX * 2);

  // power-chain ping-pong buffers overlaid on P / S / H[1] (all rewritten after powers)
  uint16_t* CMh[2] = {(uint16_t*)P, Sh};
  uint16_t* CMl[2] = {(uint16_t*)P + 4 * MB1, Sl};
  uint16_t* CTh[2] = {(uint16_t*)P + 8 * MB1, Hh[1]};
  uint16_t* CTl[2] = {(uint16_t*)P + 12 * MB1, Hl[1]};

  hipMemsetAsync(SYNC, 0, (size_t)NLAYERS * 8192 * 4, stream);
  k_split_w<<<NLAYERS * 4096, 256, 0, stream>>>(W, W1h, W1l, WSh, WSl, M1h, M1l);
  k_trans_w<<<dim3(16, 16, NLAYERS), 256, 0, stream>>>(W, T1h, T1l);
  k_cast_w<<<(int)((size_t)VOCAB * DIMX / 4 / 256), 256, 0, stream>>>(outw, OWB, VOCAB * DIMX / 4);
  k_embed_split<<<(int)(TB * DIMX / 4 / 256), 256, 0, stream>>>(ids, emb, Hh[0], Hl[0]);

  // power chain: level k -> A^(2^k); M_k = NT(M_{k-1}, T_{k-1}); T_k via transposed O2 write.
  {
    const uint16_t *inMh = M1h, *inMl = M1l, *inTh = T1h, *inTl = T1l;
    for (int k = 1; k <= 7; ++k) {
      uint16_t *oMh, *oMl;
      if (k == 4) { oMh = M16Ah; oMl = M16Al; }
      else if (k == 7) { oMh = M128Ah; oMl = M128Al; }
      else { oMh = CMh[k & 1]; oMl = CMl[k & 1]; }
      uint16_t* oTh = (k < 7) ? CTh[k & 1] : nullptr;
      uint16_t* oTl = (k < 7) ? CTl[k & 1] : nullptr;
      k_mfma<128, 128><<<dim3(8, 8, NLAYERS), 256, 0, stream>>>(
          1024,
          inMh, inMl, 4096, 1024, MB1,
          inTh, inTl, 1024, MB1,
          nullptr, 0, 0,
          nullptr, 0, 0,
          oMh, oMl, 4096, 1024, 0, MB1,
          oTh, oTl, 1024, 0, MB1);
      inMh = oMh; inMl = oMl; inTh = oTh; inTl = oTl;
    }
  }

  int cur = 0;
  for (int l = 0; l < NLAYERS; ++l) {
    // [a|u] = H @ W[:,0:1024]^T ; f32 -> P, split(u) -> PU
    k_mfma<128, 128><<<dim3(16, 32, 1), 256, 0, stream>>>(
        1024,
        Hh[cur], Hl[cur], 4096, 1024, 0,
        W1h + (size_t)l * 2048 * 1024, W1l + (size_t)l * 2048 * 1024, 1024, 0,
        nullptr, 0, 0,
        P, 8192, 2048,
        PUh, PUl, 4096, 1024, 1024, 0,
        nullptr, nullptr, 0, 1, 0);

    // persistent: phase1 + phase2 + phase3
    k_layer<<<NBLK, 256, 0, stream>>>(
        SYNC + (size_t)l * 8192, SYNC + (size_t)l * 8192 + 4096,
        P, PUh, PUl, Sh, Sl,
        M1h + (size_t)l * MB1, M1l + (size_t)l * MB1,
        M16Ah + (size_t)l * MB1, M16Al + (size_t)l * MB1,
        M128Ah + (size_t)l * MB1, M128Al + (size_t)l * MB1,
        G3h0, G3l0, G3h1, G3l1,
        BEh, BEl, LAMf, LAMh, LAMl,
        GSh0, GSl0, GSh1, GSl1,
        starter + (size_t)l * DIMX);

    // H_next = a + S @ W_hs^T (split out)
    k_mfma<128, 128><<<dim3(8, 32, 1), 256, 0, stream>>>(
        1024,
        Sh, Sl, 4096, 1024, 0,
        WSh + (size_t)l * MB1, WSl + (size_t)l * MB1, 1024, 0,
        P, 8192, 2048,
        nullptr, 0, 0,
        Hh[cur ^ 1], Hl[cur ^ 1], 4096, 1024, 0, 0,
        nullptr, nullptr, 0, 1, 0);
    cur ^= 1;
  }

  k_reorder_hi<<<(int)(TB * DIMX / 4 / 256), 256, 0, stream>>>(Hh[cur], YSB);
  k_logits<<<dim3(VOCAB / 128, TB / 128), 256, 0, stream>>>(YSB, OWB, out);
}

// Round 7
// 5269.867 us; speedup vs baseline: 2.3766x; 1.2670x over previous
//
#include <hip/hip_runtime.h>
#include <hip/hip_bf16.h>
#include <stdint.h>

#define BATCH 4
#define SEQ 1024
#define DIMX 1024
#define VOCAB 32000
#define NLAYERS 4
#define NBLK 256   // blocks in persistent kernel (1/CU)

using bf16x8 = __attribute__((ext_vector_type(8))) short;
using f32x4v = __attribute__((ext_vector_type(4))) float;

__device__ __forceinline__ uint16_t f2b(float f) {
  __hip_bfloat16 h = __float2bfloat16(f);
  return *reinterpret_cast<uint16_t*>(&h);
}
__device__ __forceinline__ float b2f(uint16_t u) {
  __hip_bfloat16 h = *reinterpret_cast<__hip_bfloat16*>(&u);
  return __bfloat162float(h);
}
__device__ __forceinline__ void fsplit(float v, uint16_t& h, uint16_t& l) {
  h = f2b(v);
  l = f2b(v - b2f(h));
}

// ---------------- embedding gather -> split bf16: row (t*4+b)
__global__ __launch_bounds__(256) void k_embed_split(const int* __restrict__ ids,
                                                     const float* __restrict__ emb,
                                                     uint16_t* __restrict__ Hhi,
                                                     uint16_t* __restrict__ Hlo) {
  int idx = blockIdx.x * 256 + threadIdx.x;
  int d4 = idx & (DIMX / 4 - 1);
  int tb = idx >> 8;
  int t = tb >> 2, b = tb & 3;
  int id = ids[b * SEQ + t];
  float4 v = reinterpret_cast<const float4*>(emb + (size_t)id * DIMX)[d4];
  ushort4 h, l;
  fsplit(v.x, h.x, l.x); fsplit(v.y, h.y, l.y); fsplit(v.z, h.z, l.z); fsplit(v.w, h.w, l.w);
  reinterpret_cast<ushort4*>(Hhi)[idx] = h;
  reinterpret_cast<ushort4*>(Hlo)[idx] = l;
}

// ---------------- split all layers' weights: W1 (2048 rows), WS (1024), M1=Wss (1024)
__global__ __launch_bounds__(256) void k_split_w(const float* __restrict__ W,
                                                 uint16_t* __restrict__ W1h, uint16_t* __restrict__ W1l,
                                                 uint16_t* __restrict__ WSh, uint16_t* __restrict__ WSl,
                                                 uint16_t* __restrict__ M1h, uint16_t* __restrict__ M1l) {
  int idx = blockIdx.x * 256 + threadIdx.x;
  int c4 = idx & 255;
  int row = idx >> 8;
  int l = row >> 12, r = row & 4095;
  const float* Wl = W + (size_t)l * 4 * 1024 * 1024;
  const float* src;
  uint16_t *dh, *dl;
  size_t doff;
  if (r < 2048) { src = Wl + (size_t)r * 2048; dh = W1h; dl = W1l; doff = ((size_t)l * 2048 + r) * 1024; }
  else if (r < 3072) { int rr = r - 2048; src = Wl + (size_t)rr * 2048 + 1024; dh = WSh; dl = WSl; doff = ((size_t)l * 1024 + rr) * 1024; }
  else { int rr = r - 3072; src = Wl + (size_t)(1024 + rr) * 2048 + 1024; dh = M1h; dl = M1l; doff = ((size_t)l * 1024 + rr) * 1024; }
  float4 v = reinterpret_cast<const float4*>(src)[c4];
  ushort4 h, lo4;
  fsplit(v.x, h.x, lo4.x); fsplit(v.y, h.y, lo4.y); fsplit(v.z, h.z, lo4.z); fsplit(v.w, h.w, lo4.w);
  reinterpret_cast<ushort4*>(dh + doff)[c4] = h;
  reinterpret_cast<ushort4*>(dl + doff)[c4] = lo4;
}

// ---------------- T1 = Wss^T per layer (LDS-tiled transpose + split)
__global__ __launch_bounds__(256) void k_trans_w(const float* __restrict__ W,
                                                 uint16_t* __restrict__ T1h, uint16_t* __restrict__ T1l) {
  __shared__ float t[64][65];
  int l = blockIdx.z;
  const float* Wl = W + (size_t)l * 4 * 1024 * 1024;
  int i0 = blockIdx.y * 64, j0 = blockIdx.x * 64;
  int c4 = (threadIdx.x & 15) * 4, rr = threadIdx.x >> 4;
#pragma unroll
  for (int p = 0; p < 4; ++p) {
    int r = rr + p * 16;
    float4 v = *reinterpret_cast<const float4*>(Wl + (size_t)(1024 + i0 + r) * 2048 + 1024 + j0 + c4);
    t[r][c4] = v.x; t[r][c4 + 1] = v.y; t[r][c4 + 2] = v.z; t[r][c4 + 3] = v.w;
  }
  __syncthreads();
#pragma unroll
  for (int p = 0; p < 4; ++p) {
    int j = rr + p * 16;
    ushort4 h, l4;
    fsplit(t[c4 + 0][j], h.x, l4.x);
    fsplit(t[c4 + 1][j], h.y, l4.y);
    fsplit(t[c4 + 2][j], h.z, l4.z);
    fsplit(t[c4 + 3][j], h.w, l4.w);
    size_t o = (size_t)l * 1024 * 1024 + (size_t)(j0 + j) * 1024 + i0 + c4;
    *reinterpret_cast<ushort4*>(T1h + o) = h;
    *reinterpret_cast<ushort4*>(T1l + o) = l4;
  }
}

// ---------------- split-bf16 MFMA GEMM (NT), 128x128 tile, optional z-batch.
template <int BM, int BN>
__global__ __launch_bounds__(256) void k_mfma(
    int K,
    const uint16_t* __restrict__ Ahi, const uint16_t* __restrict__ Alo, int a_cs, int a_bs, size_t a_z,
    const uint16_t* __restrict__ Bhi, const uint16_t* __restrict__ Blo, int ldb, size_t b_z,
    const float* __restrict__ ADD, int add_cs, int add_bs,
    float* __restrict__ O1f, int o1_cs, int o1_bs,
    uint16_t* __restrict__ O1hi, uint16_t* __restrict__ O1lo, int o1s_cs, int o1s_bs, int split_n0, size_t o1_z,
    uint16_t* __restrict__ O2hi, uint16_t* __restrict__ O2lo, int o2_cs, int o2_bs, size_t o2_z) {
  constexpr int FM = BM / 32;
  constexpr int FN = BN / 32;
  __shared__ uint16_t sAh[BM * 32], sAl[BM * 32], sBh[BN * 32], sBl[BN * 32];
  size_t zb = blockIdx.z;
  Ahi += zb * a_z; Alo += zb * a_z;
  Bhi += zb * b_z; Blo += zb * b_z;
  if (O1hi) { O1hi += zb * o1_z; O1lo += zb * o1_z; }
  if (O2hi) { O2hi += zb * o2_z; O2lo += zb * o2_z; }
  int tid = threadIdx.x;
  int lane = tid & 63;
  int wave = tid >> 6;
  int wm = wave >> 1, wn = wave & 1;
  int m0 = blockIdx.y * BM, n0 = blockIdx.x * BN;
  f32x4v acc[FM][FN] = {};
  for (int kt = 0; kt < K; kt += 32) {
    __syncthreads();
#pragma unroll
    for (int q = 0; q < BM / 64; ++q) {
      int off = q * 4096 + tid * 16;
      int r = off >> 6;
      int cu = (off & 63) >> 1;
      size_t goff = (size_t)(m0 / 4 + (r >> 2)) * a_cs + (size_t)(r & 3) * a_bs + kt + cu;
      __builtin_amdgcn_global_load_lds(
          (const __attribute__((address_space(1))) uint32_t*)(Ahi + goff),
          (__attribute__((address_space(3))) uint32_t*)((char*)sAh + off), 16, 0, 0);
      __builtin_amdgcn_global_load_lds(
          (const __attribute__((address_space(1))) uint32_t*)(Alo + goff),
          (__attribute__((address_space(3))) uint32_t*)((char*)sAl + off), 16, 0, 0);
    }
#pragma unroll
    for (int q = 0; q < BN / 64; ++q) {
      int off = q * 4096 + tid * 16;
      int r = off >> 6, cu = (off & 63) >> 1;
      size_t goff = (size_t)(n0 + r) * ldb + kt + cu;
      __builtin_amdgcn_global_load_lds(
          (const __attribute__((address_space(1))) uint32_t*)(Bhi + goff),
          (__attribute__((address_space(3))) uint32_t*)((char*)sBh + off), 16, 0, 0);
      __builtin_amdgcn_global_load_lds(
          (const __attribute__((address_space(1))) uint32_t*)(Blo + goff),
          (__attribute__((address_space(3))) uint32_t*)((char*)sBl + off), 16, 0, 0);
    }
    __syncthreads();
    int rsel = lane & 15, ko = (lane >> 4) * 8;
    bf16x8 ah[FM], al[FM], bh[FN], bl[FN];
#pragma unroll
    for (int mf = 0; mf < FM; ++mf) {
      int row = wm * (FM * 16) + mf * 16 + rsel;
      ah[mf] = *reinterpret_cast<const bf16x8*>(sAh + row * 32 + ko);
      al[mf] = *reinterpret_cast<const bf16x8*>(sAl + row * 32 + ko);
    }
#pragma unroll
    for (int nf = 0; nf < FN; ++nf) {
      int row = wn * (FN * 16) + nf * 16 + rsel;
      bh[nf] = *reinterpret_cast<const bf16x8*>(sBh + row * 32 + ko);
      bl[nf] = *reinterpret_cast<const bf16x8*>(sBl + row * 32 + ko);
    }
#pragma unroll
    for (int mf = 0; mf < FM; ++mf)
#pragma unroll
      for (int nf = 0; nf < FN; ++nf) {
        acc[mf][nf] = __builtin_amdgcn_mfma_f32_16x16x32_bf16(ah[mf], bh[nf], acc[mf][nf], 0, 0, 0);
        acc[mf][nf] = __builtin_amdgcn_mfma_f32_16x16x32_bf16(ah[mf], bl[nf], acc[mf][nf], 0, 0, 0);
        acc[mf][nf] = __builtin_amdgcn_mfma_f32_16x16x32_bf16(al[mf], bh[nf], acc[mf][nf], 0, 0, 0);
      }
  }
  int rowg = (lane >> 4) * 4, colg = lane & 15;
#pragma unroll
  for (int mf = 0; mf < FM; ++mf)
#pragma unroll
    for (int nf = 0; nf < FN; ++nf)
#pragma unroll
      for (int r = 0; r < 4; ++r) {
        int m = m0 + wm * (FM * 16) + mf * 16 + rowg + r;
        int n = n0 + wn * (FN * 16) + nf * 16 + colg;
        size_t ro = (size_t)(m >> 2);
        float dot = acc[mf][nf][r];
        float v = dot;
        if (ADD) v += ADD[ro * add_cs + (size_t)(m & 3) * add_bs + n];
        if (O1f) O1f[ro * o1_cs + (size_t)(m & 3) * o1_bs + n] = v;
        if (O1hi && n >= split_n0) {
          uint16_t h, l;
          fsplit(v, h, l);
          size_t o = ro * o1s_cs + (size_t)(m & 3) * o1s_bs + (n - split_n0);
          O1hi[o] = h; O1lo[o] = l;
        }
        if (O2hi) {
          uint16_t h, l;
          fsplit(dot, h, l);
          size_t o = (o2_bs == 0) ? ((size_t)n * o2_cs + m)
                                  : (ro * o2_cs + (size_t)(m & 3) * o2_bs + n);
          O2hi[o] = h; O2lo[o] = l;
        }
      }
}

// ---------------- slot barrier, RELAXED polling + one acquire fence per block per step
// (round-6 verified: 2.1x over acquire-polling). Release store per block, relaxed polls.
__device__ __forceinline__ void gbar(uint32_t* slots, uint32_t* release, uint32_t& gen) {
  __syncthreads();
  gen++;
  if (threadIdx.x == 0)
    __hip_atomic_store(slots + (size_t)blockIdx.x * 16, gen, __ATOMIC_RELEASE, __HIP_MEMORY_SCOPE_AGENT);
  if (blockIdx.x == 0) {
    while (__hip_atomic_load(slots + (size_t)threadIdx.x * 16, __ATOMIC_RELAXED, __HIP_MEMORY_SCOPE_AGENT) < gen)
      __builtin_amdgcn_s_sleep(2);
    __syncthreads();
    if (threadIdx.x == 0) {
      __builtin_amdgcn_fence(__ATOMIC_ACQUIRE, "agent");
      __hip_atomic_store(release, gen, __ATOMIC_RELEASE, __HIP_MEMORY_SCOPE_AGENT);
    }
    __syncthreads();
  } else {
    if (threadIdx.x == 0) {
      while (__hip_atomic_load(release, __ATOMIC_RELAXED, __HIP_MEMORY_SCOPE_AGENT) < gen)
        __builtin_amdgcn_s_sleep(2);
      __builtin_amdgcn_fence(__ATOMIC_ACQUIRE, "agent");
    }
    __syncthreads();
  }
}

// per-wave 16x16 NT tile, K=1024, B from GLOBAL (phase-2b only)
__device__ __forceinline__ f32x4v wtile16(
    const uint16_t* __restrict__ Ah, const uint16_t* __restrict__ Al,
    int a_cs, int a_bs, int m0,
    const uint16_t* __restrict__ Bh, const uint16_t* __restrict__ Bl,
    int n0, int lane) {
  int rsel = lane & 15, ko = (lane >> 4) * 8;
  int am = m0 + rsel;
  const uint16_t* pah = Ah + (size_t)(am >> 2) * a_cs + (size_t)(am & 3) * a_bs + ko;
  const uint16_t* pal = Al + (size_t)(am >> 2) * a_cs + (size_t)(am & 3) * a_bs + ko;
  const uint16_t* pbh = Bh + (size_t)(n0 + rsel) * 1024 + ko;
  const uint16_t* pbl = Bl + (size_t)(n0 + rsel) * 1024 + ko;
  f32x4v acc = {0.f, 0.f, 0.f, 0.f};
#pragma unroll 4
  for (int kt = 0; kt < 1024; kt += 32) {
    bf16x8 ah = *reinterpret_cast<const bf16x8*>(pah + kt);
    bf16x8 al = *reinterpret_cast<const bf16x8*>(pal + kt);
    bf16x8 bh = *reinterpret_cast<const bf16x8*>(pbh + kt);
    bf16x8 bl = *reinterpret_cast<const bf16x8*>(pbl + kt);
    acc = __builtin_amdgcn_mfma_f32_16x16x32_bf16(ah, bh, acc, 0, 0, 0);
    acc = __builtin_amdgcn_mfma_f32_16x16x32_bf16(ah, bl, acc, 0, 0, 0);
    acc = __builtin_amdgcn_mfma_f32_16x16x32_bf16(al, bh, acc, 0, 0, 0);
  }
  return acc;
}

// per-wave 16x16 NT tile, K=1024, B from LDS (XOR-swizzled 16B chunks), dual accumulator.
// sBh/sBl point at local row 0 of the wave's 16-row staged slice.
__device__ __forceinline__ f32x4v wtile16_lds(
    const uint16_t* __restrict__ Ah, const uint16_t* __restrict__ Al,
    int a_cs, int a_bs, int m0,
    const uint16_t* sBh, const uint16_t* sBl,
    int lane) {
  int rsel = lane & 15, ko = (lane >> 4) * 8;
  int am = m0 + rsel;
  const uint16_t* pah = Ah + (size_t)(am >> 2) * a_cs + (size_t)(am & 3) * a_bs + ko;
  const uint16_t* pal = Al + (size_t)(am >> 2) * a_cs + (size_t)(am & 3) * a_bs + ko;
  int rb = rsel * 1024;
  int s7 = rsel & 7;
  f32x4v acc0 = {0.f, 0.f, 0.f, 0.f}, acc1 = {0.f, 0.f, 0.f, 0.f};
#pragma unroll 4
  for (int kt = 0; kt < 1024; kt += 64) {
    int e0 = kt + ko, e1 = kt + 32 + ko;
    int o0 = rb + ((((e0) >> 3) ^ s7) << 3);
    int o1 = rb + ((((e1) >> 3) ^ s7) << 3);
    bf16x8 ah0 = *reinterpret_cast<const bf16x8*>(pah + kt);
    bf16x8 al0 = *reinterpret_cast<const bf16x8*>(pal + kt);
    bf16x8 ah1 = *reinterpret_cast<const bf16x8*>(pah + kt + 32);
    bf16x8 al1 = *reinterpret_cast<const bf16x8*>(pal + kt + 32);
    bf16x8 bh0 = *reinterpret_cast<const bf16x8*>(sBh + o0);
    bf16x8 bl0 = *reinterpret_cast<const bf16x8*>(sBl + o0);
    bf16x8 bh1 = *reinterpret_cast<const bf16x8*>(sBh + o1);
    bf16x8 bl1 = *reinterpret_cast<const bf16x8*>(sBl + o1);
    acc0 = __builtin_amdgcn_mfma_f32_16x16x32_bf16(ah0, bh0, acc0, 0, 0, 0);
    acc1 = __builtin_amdgcn_mfma_f32_16x16x32_bf16(ah1, bh1, acc1, 0, 0, 0);
    acc0 = __builtin_amdgcn_mfma_f32_16x16x32_bf16(ah0, bl0, acc0, 0, 0, 0);
    acc1 = __builtin_amdgcn_mfma_f32_16x16x32_bf16(ah1, bl1, acc1, 0, 0, 0);
    acc0 = __builtin_amdgcn_mfma_f32_16x16x32_bf16(al0, bh0, acc0, 0, 0, 0);
    acc1 = __builtin_amdgcn_mfma_f32_16x16x32_bf16(al1, bh1, acc1, 0, 0, 0);
  }
  return acc0 + acc1;
}

// ---------------- persistent per-layer kernel: 3-phase chunked scan (powers precomputed)
// Block = 4 waves = 4 m-tiles x 1 n-tile; B-slice (16 or 32 rows) staged in LDS per phase
// (XOR-swizzled, 128KB) so the per-step acquire fences can't evict the read-only B panel.
__global__ __launch_bounds__(256) void k_layer(
    uint32_t* slots, uint32_t* release,
    float* __restrict__ P,
    uint16_t* __restrict__ PUh, uint16_t* __restrict__ PUl,
    uint16_t* __restrict__ Sh, uint16_t* __restrict__ Sl,
    const uint16_t* __restrict__ M1h, const uint16_t* __restrict__ M1l,
    const uint16_t* __restrict__ M16h, const uint16_t* __restrict__ M16l,
    const uint16_t* __restrict__ M128h, const uint16_t* __restrict__ M128l,
    uint16_t* G3h0, uint16_t* G3l0, uint16_t* G3h1, uint16_t* G3l1,
    uint16_t* BEh, uint16_t* BEl,
    float* LAMf, uint16_t* LAMh, uint16_t* LAMl,
    uint16_t* GSh0, uint16_t* GSl0, uint16_t* GSh1, uint16_t* GSl1,
    const float* __restrict__ starterL) {
  __shared__ uint16_t sB[2][32 * 1024];   // 128 KB: [hi/lo][local row][swizzled col]
  int tid = threadIdx.x, bid = blockIdx.x;
  int lane = tid & 63;
  int wv = tid >> 6;                 // 0..3
  int xcd = bid & 7;
  int q = bid >> 3;                  // 0..31 within XCD group
  uint32_t gen = 0;
  int rowg = (lane >> 4) * 4, colg = lane & 15;

  // phase-1/3 mapping: all 1024 waves; block covers 4 m-tiles x 1 n-tile
  int nt13 = xcd * 8 + (q & 7);          // 0..63
  int m0_13 = ((q >> 3) * 4 + wv) * 16;  // 0..255 step 16
  int n0_13 = nt13 * 16;
  // phase-2a/2c mapping (active q<4): M=32 -> 2 m-tiles; block stages 2 n-slices (32 rows)
  int m0_2 = (wv & 1) * 16;
  int nt2 = xcd * 8 + q * 2 + (wv >> 1);
  int n0_2 = nt2 * 16;
  int lrb2 = (wv >> 1) * 16 * 1024;      // LDS row offset of this wave's slice
  // phase-2b mapping (active q<2): M=4(pad16) x 64 n-tiles
  int n0_b = (xcd * 8 + q * 4 + wv) * 16;

  // init: sigma_0 = starter broadcast
  {
    int idx = bid * 256 + tid;
    if (idx < BATCH * DIMX) {
      int b = idx >> 10, d = idx & 1023;
      float v = starterL[d];
      uint16_t h, l;
      fsplit(v, h, l);
      size_t o = (size_t)b * 1024 + d;
      BEh[o] = h; BEl[o] = l;
      G3h0[o] = h; G3l0[o] = l;
      GSh0[o] = h; GSl0[o] = l;
      Sh[o] = h; Sl[o] = l;
    }
  }

  // stage M1 B-slice (16 rows at n0_13) into LDS, swizzled
  {
    const uint16_t* gh = M1h + (size_t)n0_13 * 1024;
    const uint16_t* gl = M1l + (size_t)n0_13 * 1024;
    for (int i = tid; i < 16 * 128; i += 256) {
      int r = i >> 7, c8 = i & 127;
      int dst = r * 1024 + ((c8 ^ (r & 7)) << 3);
      *reinterpret_cast<bf16x8*>(&sB[0][dst]) = *reinterpret_cast<const bf16x8*>(gh + (size_t)r * 1024 + c8 * 8);
      *reinterpret_cast<bf16x8*>(&sB[1][dst]) = *reinterpret_cast<const bf16x8*>(gl + (size_t)r * 1024 + c8 * 8);
    }
  }
  __syncthreads();

  // ---- phase 1: l_j = A l_{j-1} + u_j, j=1..15 (in place over P u-half)
  for (int j = 1; j < 16; ++j) {
    {
      f32x4v acc = wtile16_lds(PUh + (size_t)(j - 1) * 4096, PUl + (size_t)(j - 1) * 4096,
                               65536, 1024, m0_13, &sB[0][0], &sB[1][0], lane);
      int n = n0_13 + colg;
#pragma unroll
      for (int rr = 0; rr < 4; ++rr) {
        int m = m0_13 + rowg + rr;
        int c = m >> 2, b = m & 3;
        size_t t = (size_t)(c * 16 + j);
        float* pu = P + (t * 4 + b) * 2048 + 1024 + n;
        float v = acc[rr] + *pu;
        *pu = v;
        uint16_t h, l;
        fsplit(v, h, l);
        size_t o = (t * 4 + b) * 1024 + n;
        PUh[o] = h; PUl[o] = l;
      }
    }
    gbar(slots, release, gen);
  }

  // ---- phase 2a init: lambda_0 = e_{8g}
  {
    int idx = bid * 256 + tid;
    if (idx < 32 * 1024) {
      int r = idx >> 10, d = idx & 1023;
      int g = r >> 2, b = r & 3;
      float v = P[((size_t)(g * 128 + 15) * 4 + b) * 2048 + 1024 + d];
      LAMf[idx] = v;
      uint16_t h, l;
      fsplit(v, h, l);
      LAMh[idx] = h; LAMl[idx] = l;
    }
  }
  gbar(slots, release, gen);

  // stage M16 (32 rows: slices q*2, q*2+1) for active blocks
  if (q < 4) {
    int nb = (xcd * 8 + q * 2) * 16;
    const uint16_t* gh = M16h + (size_t)nb * 1024;
    const uint16_t* gl = M16l + (size_t)nb * 1024;
    for (int i = tid; i < 32 * 128; i += 256) {
      int r = i >> 7, c8 = i & 127;
      int dst = r * 1024 + ((c8 ^ (r & 7)) << 3);
      *reinterpret_cast<bf16x8*>(&sB[0][dst]) = *reinterpret_cast<const bf16x8*>(gh + (size_t)r * 1024 + c8 * 8);
      *reinterpret_cast<bf16x8*>(&sB[1][dst]) = *reinterpret_cast<const bf16x8*>(gl + (size_t)r * 1024 + c8 * 8);
    }
  }
  __syncthreads();

  // ---- phase 2a: lambda_j = A16 lambda_{j-1} + e_{8g+j}, j=1..7
  for (int j = 1; j < 8; ++j) {
    if (q < 4) {
      f32x4v acc = wtile16_lds(LAMh + (size_t)(j - 1) * 32768, LAMl + (size_t)(j - 1) * 32768,
                               4096, 1024, m0_2, &sB[0][lrb2], &sB[1][lrb2], lane);
      int n = n0_2 + colg;
#pragma unroll
      for (int rr = 0; rr < 4; ++rr) {
        int m = m0_2 + rowg + rr;
        int g = m >> 2, b = m & 3;
        int c = 8 * g + j;
        float e = P[((size_t)(c * 16 + 15) * 4 + b) * 2048 + 1024 + n];
        float v = acc[rr] + e;
        size_t o = (size_t)j * 32768 + (size_t)m * 1024 + n;
        LAMf[o] = v;
        uint16_t h, l;
        fsplit(v, h, l);
        LAMh[o] = h; LAMl[o] = l;
      }
    }
    gbar(slots, release, gen);
  }

  // ---- phase 2b: beta_{g+1} = A128 beta_g + lambda_7(g), g=0..6 (global B)
  for (int g = 0; g < 7; ++g) {
    if (q < 2) {
      f32x4v acc = wtile16(BEh + (size_t)g * 16384, BEl + (size_t)g * 16384,
                           4096, 1024, 0, M128h, M128l, n0_b, lane);
      if ((lane >> 4) == 0) {
        int n = n0_b + colg;
#pragma unroll
        for (int rr = 0; rr < 4; ++rr) {
          int b = rr;
          float v = acc[rr] + LAMf[(size_t)7 * 32768 + (size_t)(g * 4 + b) * 1024 + n];
          uint16_t h, l;
          fsplit(v, h, l);
          size_t ob = (size_t)(g + 1) * 16384 + (size_t)b * 1024 + n;
          BEh[ob] = h; BEl[ob] = l;
          int c = 8 * (g + 1);
          size_t o1 = (size_t)(c * 4 + b) * 1024 + n;
          G3h0[o1] = h; G3l0[o1] = l;
          size_t o2 = ((size_t)(c * 16) * 4 + b) * 1024 + n;
          Sh[o2] = h; Sl[o2] = l;
          size_t o3 = (size_t)((g + 1) * 4 + b) * 1024 + n;
          GSh0[o3] = h; GSl0[o3] = l;
        }
      }
    }
    gbar(slots, release, gen);
  }

  // ---- phase 2c: Gs_j = A16 Gs_{j-1}; sigma_{8g+j} = Gs_j + lambda_{j-1}, j=1..7
  int gsc = 0;
  for (int j = 1; j < 8; ++j) {
    uint16_t* gih = gsc ? GSh1 : GSh0;
    uint16_t* gil = gsc ? GSl1 : GSl0;
    uint16_t* goh = gsc ? GSh0 : GSh1;
    uint16_t* gol = gsc ? GSl0 : GSl1;
    if (q < 4) {
      f32x4v acc = wtile16_lds(gih, gil, 4096, 1024, m0_2, &sB[0][lrb2], &sB[1][lrb2], lane);
      int n = n0_2 + colg;
#pragma unroll
      for (int rr = 0; rr < 4; ++rr) {
        int m = m0_2 + rowg + rr;
        int g = m >> 2, b = m & 3;
        int c = 8 * g + j;
        float lam = LAMf[(size_t)(j - 1) * 32768 + (size_t)m * 1024 + n];
        float v = acc[rr] + lam;
        uint16_t h, l;
        fsplit(v, h, l);
        size_t o1 = (size_t)(c * 4 + b) * 1024 + n;
        G3h0[o1] = h; G3l0[o1] = l;
        size_t o2 = ((size_t)(c * 16) * 4 + b) * 1024 + n;
        Sh[o2] = h; Sl[o2] = l;
        uint16_t h2, l2;
        fsplit(acc[rr], h2, l2);
        goh[(size_t)m * 1024 + n] = h2;
        gol[(size_t)m * 1024 + n] = l2;
      }
    }
    gbar(slots, release, gen);
    gsc ^= 1;
  }

  // re-stage M1 B-slice for phase 3 (LDS was overwritten with M16 by q<4 blocks)
  {
    const uint16_t* gh = M1h + (size_t)n0_13 * 1024;
    const uint16_t* gl = M1l + (size_t)n0_13 * 1024;
    for (int i = tid; i < 16 * 128; i += 256) {
      int r = i >> 7, c8 = i & 127;
      int dst = r * 1024 + ((c8 ^ (r & 7)) << 3);
      *reinterpret_cast<bf16x8*>(&sB[0][dst]) = *reinterpret_cast<const bf16x8*>(gh + (size_t)r * 1024 + c8 * 8);
      *reinterpret_cast<bf16x8*>(&sB[1][dst]) = *reinterpret_cast<const bf16x8*>(gl + (size_t)r * 1024 + c8 * 8);
    }
  }
  __syncthreads();

  // ---- phase 3: G_j = A G_{j-1}; S[c*16+j] = G_j + l_{c*16+j-1}, j=1..15
  int g3 = 0;
  for (int j = 1; j < 16; ++j) {
    uint16_t* gih = g3 ? G3h1 : G3h0;
    uint16_t* gil = g3 ? G3l1 : G3l0;
    uint16_t* goh = g3 ? G3h0 : G3h1;
    uint16_t* gol = g3 ? G3l0 : G3l1;
    {
      f32x4v acc = wtile16_lds(gih, gil, 4096, 1024, m0_13, &sB[0][0], &sB[1][0], lane);
      int n = n0_13 + colg;
#pragma unroll
      for (int rr = 0; rr < 4; ++rr) {
        int m = m0_13 + rowg + rr;
        int c = m >> 2, b = m & 3;
        float u = P[((size_t)(c * 16 + j - 1) * 4 + b) * 2048 + 1024 + n];
        float v = acc[rr] + u;
        uint16_t h, l;
        fsplit(v, h, l);
        size_t o = ((size_t)(c * 16 + j) * 4 + b) * 1024 + n;
        Sh[o] = h; Sl[o] = l;
        uint16_t h2, l2;
        fsplit(acc[rr], h2, l2);
        goh[(size_t)m * 1024 + n] = h2;
        gol[(size_t)m * 1024 + n] = l2;
      }
    }
    if (j < 15) gbar(slots, release, gen);
    g3 ^= 1;
  }
}

// ---------------- reorder H_hi [t][b][d] -> Y [b][t][d]
__global__ __launch_bounds__(256) void k_reorder_hi(const uint16_t* __restrict__ Hhi, uint16_t* __restrict__ Y) {
  int idx = blockIdx.x * 256 + threadIdx.x;
  int d4 = idx & (DIMX / 4 - 1);
  int tb = idx >> 8;
  int t = tb >> 2, b = tb & 3;
  ushort4 v = reinterpret_cast<const ushort4*>(Hhi)[idx];
  reinterpret_cast<ushort4*>(Y + (size_t)(b * SEQ + t) * DIMX)[d4] = v;
}

__global__ __launch_bounds__(256) void k_cast_w(const float* __restrict__ src, uint16_t* __restrict__ dst, int n4) {
  int idx = blockIdx.x * 256 + threadIdx.x;
  if (idx >= n4) return;
  float4 v = reinterpret_cast<const float4*>(src)[idx];
  ushort4 o;
  o.x = f2b(v.x); o.y = f2b(v.y); o.z = f2b(v.z); o.w = f2b(v.w);
  reinterpret_cast<ushort4*>(dst)[idx] = o;
}

// ---------------- logits GEMM: bf16 MFMA 128x128
__global__ __launch_bounds__(256) void k_logits(const uint16_t* __restrict__ A,
                                                const uint16_t* __restrict__ Bt,
                                                float* __restrict__ C) {
  __shared__ uint16_t As[128 * 32];
  __shared__ uint16_t Bs[128 * 32];
  int tid = threadIdx.x;
  int bx = blockIdx.x, by = blockIdx.y;
  int lane = tid & 63, wave = tid >> 6;
  int wm = wave >> 1, wn = wave & 1;
  f32x4v acc[4][4] = {};
  const uint16_t* Ag = A + (size_t)by * 128 * 1024;
  const uint16_t* Bg = Bt + (size_t)bx * 128 * 1024;
  for (int kt = 0; kt < 1024; kt += 32) {
    __syncthreads();
#pragma unroll
    for (int q = 0; q < 2; ++q) {
      int off = q * 4096 + tid * 16;
      int r = off >> 6, cu = (off & 63) >> 1;
      __builtin_amdgcn_global_load_lds(
          (const __attribute__((address_space(1))) uint32_t*)(Ag + (size_t)r * 1024 + kt + cu),
          (__attribute__((address_space(3))) uint32_t*)((char*)As + off), 16, 0, 0);
      __builtin_amdgcn_global_load_lds(
          (const __attribute__((address_space(1))) uint32_t*)(Bg + (size_t)r * 1024 + kt + cu),
          (__attribute__((address_space(3))) uint32_t*)((char*)Bs + off), 16, 0, 0);
    }
    __syncthreads();
    int rsel = lane & 15, ko = (lane >> 4) * 8;
    bf16x8 af[4], bfr[4];
#pragma unroll
    for (int mf = 0; mf < 4; ++mf)
      af[mf] = *reinterpret_cast<const bf16x8*>(As + (wm * 64 + mf * 16 + rsel) * 32 + ko);
#pragma unroll
    for (int nf = 0; nf < 4; ++nf)
      bfr[nf] = *reinterpret_cast<const bf16x8*>(Bs + (wn * 64 + nf * 16 + rsel) * 32 + ko);
#pragma unroll
    for (int mf = 0; mf < 4; ++mf)
#pragma unroll
      for (int nf = 0; nf < 4; ++nf)
        acc[mf][nf] = __builtin_amdgcn_mfma_f32_16x16x32_bf16(af[mf], bfr[nf], acc[mf][nf], 0, 0, 0);
  }
  int rowg = (lane >> 4) * 4;
  int colg = lane & 15;
#pragma unroll
  for (int mf = 0; mf < 4; ++mf)
#pragma unroll
    for (int nf = 0; nf < 4; ++nf)
#pragma unroll
      for (int r = 0; r < 4; ++r) {
        int m = by * 128 + wm * 64 + mf * 16 + rowg + r;
        int n = bx * 128 + wn * 64 + nf * 16 + colg;
        C[(size_t)m * VOCAB + n] = acc[mf][nf][r];
      }
}

// =========================================================================
extern "C" void kernel_launch(void* const* d_in, const int* in_sizes, int n_in,
                              void* d_out, int out_size, void* d_ws, size_t ws_size,
                              hipStream_t stream) {
  const int* ids = (const int*)d_in[0];
  const float* emb = (const float*)d_in[1];
  const float* W = (const float*)d_in[2];
  const float* outw = (const float*)d_in[3];
  const float* starter = (const float*)d_in[4];
  float* out = (float*)d_out;

  char* wsb = (char*)d_ws;
  size_t off = 0;
  auto alloc = [&](size_t bytes) {
    void* p = wsb + off;
    off = (off + bytes + 255) & ~(size_t)255;
    return p;
  };
  const size_t TB = SEQ * BATCH;
  const size_t MB1 = (size_t)1024 * 1024;

  uint32_t* SYNC = (uint32_t*)alloc((size_t)NLAYERS * 8192 * 4);
  uint16_t* Hh[2] = {(uint16_t*)alloc(TB * DIMX * 2), (uint16_t*)alloc(TB * DIMX * 2)};
  uint16_t* Hl[2] = {(uint16_t*)alloc(TB * DIMX * 2), (uint16_t*)alloc(TB * DIMX * 2)};
  float* P = (float*)alloc(TB * 2 * DIMX * 4);
  uint16_t* PUh = (uint16_t*)alloc(TB * DIMX * 2);
  uint16_t* PUl = (uint16_t*)alloc(TB * DIMX * 2);
  uint16_t* Sh = (uint16_t*)alloc(TB * DIMX * 2);
  uint16_t* Sl = (uint16_t*)alloc(TB * DIMX * 2);
  uint16_t* W1h = (uint16_t*)alloc((size_t)NLAYERS * 2048 * 1024 * 2);
  uint16_t* W1l = (uint16_t*)alloc((size_t)NLAYERS * 2048 * 1024 * 2);
  uint16_t* WSh = (uint16_t*)alloc((size_t)NLAYERS * MB1 * 2);
  uint16_t* WSl = (uint16_t*)alloc((size_t)NLAYERS * MB1 * 2);
  uint16_t* M1h = (uint16_t*)alloc((size_t)NLAYERS * MB1 * 2);
  uint16_t* M1l = (uint16_t*)alloc((size_t)NLAYERS * MB1 * 2);
  uint16_t* T1h = (uint16_t*)alloc((size_t)NLAYERS * MB1 * 2);
  uint16_t* T1l = (uint16_t*)alloc((size_t)NLAYERS * MB1 * 2);
  uint16_t* M16Ah = (uint16_t*)alloc((size_t)NLAYERS * MB1 * 2);
  uint16_t* M16Al = (uint16_t*)alloc((size_t)NLAYERS * MB1 * 2);
  uint16_t* M128Ah = (uint16_t*)alloc((size_t)NLAYERS * MB1 * 2);
  uint16_t* M128Al = (uint16_t*)alloc((size_t)NLAYERS * MB1 * 2);
  uint16_t* G3h0 = (uint16_t*)alloc((size_t)256 * 1024 * 2);
  uint16_t* G3l0 = (uint16_t*)alloc((size_t)256 * 1024 * 2);
  uint16_t* G3h1 = (uint16_t*)alloc((size_t)256 * 1024 * 2);
  uint16_t* G3l1 = (uint16_t*)alloc((size_t)256 * 1024 * 2);
  uint16_t* BEh = (uint16_t*)alloc((size_t)8 * 16 * 1024 * 2);
  uint16_t* BEl = (uint16_t*)alloc((size_t)8 * 16 * 1024 * 2);
  float* LAMf = (float*)alloc((size_t)8 * 32 * 1024 * 4);
  uint16_t* LAMh = (uint16_t*)alloc((size_t)8 * 32 * 1024 * 2);
  uint16_t* LAMl = (uint16_t*)alloc((size_t)8 * 32 * 1024 * 2);
  uint16_t* GSh0 = (uint16_t*)alloc((size_t)32 * 1024 * 2);
  uint16_t* GSl0 = (uint16_t*)alloc((size_t)32 * 1024 * 2);
  uint16_t* GSh1 = (uint16_t*)alloc((size_t)32 * 1024 * 2);
  uint16_t* GSl1 = (uint16_t*)alloc((size_t)32 * 1024 * 2);
  uint16_t* YSB = (uint16_t*)alloc(TB * DIMX * 2);
  uint16_t* OWB = (uint16_t*)alloc((size_t)VOCAB * DIMX * 2);

  // power-chain ping-pong buffers overlaid on P / S / H[1]
  uint16_t* CMh[2] = {(uint16_t*)P, Sh};
  uint16_t* CMl[2] = {(uint16_t*)P + 4 * MB1, Sl};
  uint16_t* CTh[2] = {(uint16_t*)P + 8 * MB1, Hh[1]};
  uint16_t* CTl[2] = {(uint16_t*)P + 12 * MB1, Hl[1]};

  hipMemsetAsync(SYNC, 0, (size_t)NLAYERS * 8192 * 4, stream);
  k_split_w<<<NLAYERS * 4096, 256, 0, stream>>>(W, W1h, W1l, WSh, WSl, M1h, M1l);
  k_trans_w<<<dim3(16, 16, NLAYERS), 256, 0, stream>>>(W, T1h, T1l);
  k_cast_w<<<(int)((size_t)VOCAB * DIMX / 4 / 256), 256, 0, stream>>>(outw, OWB, VOCAB * DIMX / 4);
  k_embed_split<<<(int)(TB * DIMX / 4 / 256), 256, 0, stream>>>(ids, emb, Hh[0], Hl[0]);

  // power chain: level k -> A^(2^k)
  {
    const uint16_t *inMh = M1h, *inMl = M1l, *inTh = T1h, *inTl = T1l;
    for (int k = 1; k <= 7; ++k) {
      uint16_t *oMh, *oMl;
      if (k == 4) { oMh = M16Ah; oMl = M16Al; }
      else if (k == 7) { oMh = M128Ah; oMl = M128Al; }
      else { oMh = CMh[k & 1]; oMl = CMl[k & 1]; }
      uint16_t* oTh = (k < 7) ? CTh[k & 1] : nullptr;
      uint16_t* oTl = (k < 7) ? CTl[k & 1] : nullptr;
      k_mfma<128, 128><<<dim3(8, 8, NLAYERS), 256, 0, stream>>>(
          1024,
          inMh, inMl, 4096, 1024, MB1,
          inTh, inTl, 1024, MB1,
          nullptr, 0, 0,
          nullptr, 0, 0,
          oMh, oMl, 4096, 1024, 0, MB1,
          oTh, oTl, 1024, 0, MB1);
      inMh = oMh; inMl = oMl; inTh = oTh; inTl = oTl;
    }
  }

  int cur = 0;
  for (int l = 0; l < NLAYERS; ++l) {
    // [a|u] = H @ W[:,0:1024]^T ; f32 -> P, split(u) -> PU
    k_mfma<128, 128><<<dim3(16, 32, 1), 256, 0, stream>>>(
        1024,
        Hh[cur], Hl[cur], 4096, 1024, 0,
        W1h + (size_t)l * 2048 * 1024, W1l + (size_t)l * 2048 * 1024, 1024, 0,
        nullptr, 0, 0,
        P, 8192, 2048,
        PUh, PUl, 4096, 1024, 1024, 0,
        nullptr, nullptr, 0, 1, 0);

    // persistent: phase1 + phase2 + phase3
    k_layer<<<NBLK, 256, 0, stream>>>(
        SYNC + (size_t)l * 8192, SYNC + (size_t)l * 8192 + 4096,
        P, PUh, PUl, Sh, Sl,
        M1h + (size_t)l * MB1, M1l + (size_t)l * MB1,
        M16Ah + (size_t)l * MB1, M16Al + (size_t)l * MB1,
        M128Ah + (size_t)l * MB1, M128Al + (size_t)l * MB1,
        G3h0, G3l0, G3h1, G3l1,
        BEh, BEl, LAMf, LAMh, LAMl,
        GSh0, GSl0, GSh1, GSl1,
        starter + (size_t)l * DIMX);

    // H_next = a + S @ W_hs^T (split out)
    k_mfma<128, 128><<<dim3(8, 32, 1), 256, 0, stream>>>(
        1024,
        Sh, Sl, 4096, 1024, 0,
        WSh + (size_t)l * MB1, WSl + (size_t)l * MB1, 1024, 0,
        P, 8192, 2048,
        nullptr, 0, 0,
        Hh[cur ^ 1], Hl[cur ^ 1], 4096, 1024, 0, 0,
        nullptr, nullptr, 0, 1, 0);
    cur ^= 1;
  }

  k_reorder_hi<<<(int)(TB * DIMX / 4 / 256), 256, 0, stream>>>(Hh[cur], YSB);
  k_logits<<<dim3(VOCAB / 128, TB / 128), 256, 0, stream>>>(YSB, OWB, out);
}

// Round 8
// 4229.453 us; speedup vs baseline: 2.9612x; 1.2460x over previous
//
#include <hip/hip_runtime.h>
#include <hip/hip_bf16.h>
#include <stdint.h>

#define BATCH 4
#define SEQ 1024
#define DIMX 1024
#define VOCAB 32000
#define NLAYERS 4
#define NBLK 256   // blocks in persistent kernel (1/CU)

// SYNC word layout per layer (stride-16 words = 64B slots):
//   [ (idx)*16 ]      : arrive slots (flat: idx=bid; hier: idx=xcd*32+q)
//   [ 4096+xcd*16 ]   : per-XCD global arrive
//   [ 4608 ]          : global release
//   [ 4864+xcd*16 ]   : per-XCD local release
//   [ 5120 ]          : mapping-mismatch flag
#define W_GARR 4096
#define W_GREL 4608
#define W_LREL 4864
#define W_FLAG 5120

using bf16x8 = __attribute__((ext_vector_type(8))) short;
using f32x4v = __attribute__((ext_vector_type(4))) float;

__device__ __forceinline__ uint16_t f2b(float f) {
  __hip_bfloat16 h = __float2bfloat16(f);
  return *reinterpret_cast<uint16_t*>(&h);
}
__device__ __forceinline__ float b2f(uint16_t u) {
  __hip_bfloat16 h = *reinterpret_cast<__hip_bfloat16*>(&u);
  return __bfloat162float(h);
}
__device__ __forceinline__ void fsplit(float v, uint16_t& h, uint16_t& l) {
  h = f2b(v);
  l = f2b(v - b2f(h));
}

__device__ __forceinline__ uint32_t get_xcc() {
  uint32_t x;
  asm volatile("s_getreg_b32 %0, hwreg(HW_REG_XCC_ID)" : "=s"(x));
  return x & 7u;
}

// ---------------- embedding gather -> split bf16: row (t*4+b)
__global__ __launch_bounds__(256) void k_embed_split(const int* __restrict__ ids,
                                                     const float* __restrict__ emb,
                                                     uint16_t* __restrict__ Hhi,
                                                     uint16_t* __restrict__ Hlo) {
  int idx = blockIdx.x * 256 + threadIdx.x;
  int d4 = idx & (DIMX / 4 - 1);
  int tb = idx >> 8;
  int t = tb >> 2, b = tb & 3;
  int id = ids[b * SEQ + t];
  float4 v = reinterpret_cast<const float4*>(emb + (size_t)id * DIMX)[d4];
  ushort4 h, l;
  fsplit(v.x, h.x, l.x); fsplit(v.y, h.y, l.y); fsplit(v.z, h.z, l.z); fsplit(v.w, h.w, l.w);
  reinterpret_cast<ushort4*>(Hhi)[idx] = h;
  reinterpret_cast<ushort4*>(Hlo)[idx] = l;
}

// ---------------- split all layers' weights: W1 (2048 rows), WS (1024), M1=Wss (1024)
__global__ __launch_bounds__(256) void k_split_w(const float* __restrict__ W,
                                                 uint16_t* __restrict__ W1h, uint16_t* __restrict__ W1l,
                                                 uint16_t* __restrict__ WSh, uint16_t* __restrict__ WSl,
                                                 uint16_t* __restrict__ M1h, uint16_t* __restrict__ M1l) {
  int idx = blockIdx.x * 256 + threadIdx.x;
  int c4 = idx & 255;
  int row = idx >> 8;
  int l = row >> 12, r = row & 4095;
  const float* Wl = W + (size_t)l * 4 * 1024 * 1024;
  const float* src;
  uint16_t *dh, *dl;
  size_t doff;
  if (r < 2048) { src = Wl + (size_t)r * 2048; dh = W1h; dl = W1l; doff = ((size_t)l * 2048 + r) * 1024; }
  else if (r < 3072) { int rr = r - 2048; src = Wl + (size_t)rr * 2048 + 1024; dh = WSh; dl = WSl; doff = ((size_t)l * 1024 + rr) * 1024; }
  else { int rr = r - 3072; src = Wl + (size_t)(1024 + rr) * 2048 + 1024; dh = M1h; dl = M1l; doff = ((size_t)l * 1024 + rr) * 1024; }
  float4 v = reinterpret_cast<const float4*>(src)[c4];
  ushort4 h, lo4;
  fsplit(v.x, h.x, lo4.x); fsplit(v.y, h.y, lo4.y); fsplit(v.z, h.z, lo4.z); fsplit(v.w, h.w, lo4.w);
  reinterpret_cast<ushort4*>(dh + doff)[c4] = h;
  reinterpret_cast<ushort4*>(dl + doff)[c4] = lo4;
}

// ---------------- T1 = Wss^T per layer (LDS-tiled transpose + split)
__global__ __launch_bounds__(256) void k_trans_w(const float* __restrict__ W,
                                                 uint16_t* __restrict__ T1h, uint16_t* __restrict__ T1l) {
  __shared__ float t[64][65];
  int l = blockIdx.z;
  const float* Wl = W + (size_t)l * 4 * 1024 * 1024;
  int i0 = blockIdx.y * 64, j0 = blockIdx.x * 64;
  int c4 = (threadIdx.x & 15) * 4, rr = threadIdx.x >> 4;
#pragma unroll
  for (int p = 0; p < 4; ++p) {
    int r = rr + p * 16;
    float4 v = *reinterpret_cast<const float4*>(Wl + (size_t)(1024 + i0 + r) * 2048 + 1024 + j0 + c4);
    t[r][c4] = v.x; t[r][c4 + 1] = v.y; t[r][c4 + 2] = v.z; t[r][c4 + 3] = v.w;
  }
  __syncthreads();
#pragma unroll
  for (int p = 0; p < 4; ++p) {
    int j = rr + p * 16;
    ushort4 h, l4;
    fsplit(t[c4 + 0][j], h.x, l4.x);
    fsplit(t[c4 + 1][j], h.y, l4.y);
    fsplit(t[c4 + 2][j], h.z, l4.z);
    fsplit(t[c4 + 3][j], h.w, l4.w);
    size_t o = (size_t)l * 1024 * 1024 + (size_t)(j0 + j) * 1024 + i0 + c4;
    *reinterpret_cast<ushort4*>(T1h + o) = h;
    *reinterpret_cast<ushort4*>(T1l + o) = l4;
  }
}

// ---------------- split-bf16 MFMA GEMM (NT), 128x128 tile, optional z-batch.
template <int BM, int BN>
__global__ __launch_bounds__(256) void k_mfma(
    int K,
    const uint16_t* __restrict__ Ahi, const uint16_t* __restrict__ Alo, int a_cs, int a_bs, size_t a_z,
    const uint16_t* __restrict__ Bhi, const uint16_t* __restrict__ Blo, int ldb, size_t b_z,
    const float* __restrict__ ADD, int add_cs, int add_bs,
    float* __restrict__ O1f, int o1_cs, int o1_bs,
    uint16_t* __restrict__ O1hi, uint16_t* __restrict__ O1lo, int o1s_cs, int o1s_bs, int split_n0, size_t o1_z,
    uint16_t* __restrict__ O2hi, uint16_t* __restrict__ O2lo, int o2_cs, int o2_bs, size_t o2_z) {
  constexpr int FM = BM / 32;
  constexpr int FN = BN / 32;
  __shared__ uint16_t sAh[BM * 32], sAl[BM * 32], sBh[BN * 32], sBl[BN * 32];
  size_t zb = blockIdx.z;
  Ahi += zb * a_z; Alo += zb * a_z;
  Bhi += zb * b_z; Blo += zb * b_z;
  if (O1hi) { O1hi += zb * o1_z; O1lo += zb * o1_z; }
  if (O2hi) { O2hi += zb * o2_z; O2lo += zb * o2_z; }
  int tid = threadIdx.x;
  int lane = tid & 63;
  int wave = tid >> 6;
  int wm = wave >> 1, wn = wave & 1;
  int m0 = blockIdx.y * BM, n0 = blockIdx.x * BN;
  f32x4v acc[FM][FN] = {};
  for (int kt = 0; kt < K; kt += 32) {
    __syncthreads();
#pragma unroll
    for (int q = 0; q < BM / 64; ++q) {
      int off = q * 4096 + tid * 16;
      int r = off >> 6;
      int cu = (off & 63) >> 1;
      size_t goff = (size_t)(m0 / 4 + (r >> 2)) * a_cs + (size_t)(r & 3) * a_bs + kt + cu;
      __builtin_amdgcn_global_load_lds(
          (const __attribute__((address_space(1))) uint32_t*)(Ahi + goff),
          (__attribute__((address_space(3))) uint32_t*)((char*)sAh + off), 16, 0, 0);
      __builtin_amdgcn_global_load_lds(
          (const __attribute__((address_space(1))) uint32_t*)(Alo + goff),
          (__attribute__((address_space(3))) uint32_t*)((char*)sAl + off), 16, 0, 0);
    }
#pragma unroll
    for (int q = 0; q < BN / 64; ++q) {
      int off = q * 4096 + tid * 16;
      int r = off >> 6, cu = (off & 63) >> 1;
      size_t goff = (size_t)(n0 + r) * ldb + kt + cu;
      __builtin_amdgcn_global_load_lds(
          (const __attribute__((address_space(1))) uint32_t*)(Bhi + goff),
          (__attribute__((address_space(3))) uint32_t*)((char*)sBh + off), 16, 0, 0);
      __builtin_amdgcn_global_load_lds(
          (const __attribute__((address_space(1))) uint32_t*)(Blo + goff),
          (__attribute__((address_space(3))) uint32_t*)((char*)sBl + off), 16, 0, 0);
    }
    __syncthreads();
    int rsel = lane & 15, ko = (lane >> 4) * 8;
    bf16x8 ah[FM], al[FM], bh[FN], bl[FN];
#pragma unroll
    for (int mf = 0; mf < FM; ++mf) {
      int row = wm * (FM * 16) + mf * 16 + rsel;
      ah[mf] = *reinterpret_cast<const bf16x8*>(sAh + row * 32 + ko);
      al[mf] = *reinterpret_cast<const bf16x8*>(sAl + row * 32 + ko);
    }
#pragma unroll
    for (int nf = 0; nf < FN; ++nf) {
      int row = wn * (FN * 16) + nf * 16 + rsel;
      bh[nf] = *reinterpret_cast<const bf16x8*>(sBh + row * 32 + ko);
      bl[nf] = *reinterpret_cast<const bf16x8*>(sBl + row * 32 + ko);
    }
#pragma unroll
    for (int mf = 0; mf < FM; ++mf)
#pragma unroll
      for (int nf = 0; nf < FN; ++nf) {
        acc[mf][nf] = __builtin_amdgcn_mfma_f32_16x16x32_bf16(ah[mf], bh[nf], acc[mf][nf], 0, 0, 0);
        acc[mf][nf] = __builtin_amdgcn_mfma_f32_16x16x32_bf16(ah[mf], bl[nf], acc[mf][nf], 0, 0, 0);
        acc[mf][nf] = __builtin_amdgcn_mfma_f32_16x16x32_bf16(al[mf], bh[nf], acc[mf][nf], 0, 0, 0);
      }
  }
  int rowg = (lane >> 4) * 4, colg = lane & 15;
#pragma unroll
  for (int mf = 0; mf < FM; ++mf)
#pragma unroll
    for (int nf = 0; nf < FN; ++nf)
#pragma unroll
      for (int r = 0; r < 4; ++r) {
        int m = m0 + wm * (FM * 16) + mf * 16 + rowg + r;
        int n = n0 + wn * (FN * 16) + nf * 16 + colg;
        size_t ro = (size_t)(m >> 2);
        float dot = acc[mf][nf][r];
        float v = dot;
        if (ADD) v += ADD[ro * add_cs + (size_t)(m & 3) * add_bs + n];
        if (O1f) O1f[ro * o1_cs + (size_t)(m & 3) * o1_bs + n] = v;
        if (O1hi && n >= split_n0) {
          uint16_t h, l;
          fsplit(v, h, l);
          size_t o = ro * o1s_cs + (size_t)(m & 3) * o1s_bs + (n - split_n0);
          O1hi[o] = h; O1lo[o] = l;
        }
        if (O2hi) {
          uint16_t h, l;
          fsplit(dot, h, l);
          size_t o = (o2_bs == 0) ? ((size_t)n * o2_cs + m)
                                  : (ro * o2_cs + (size_t)(m & 3) * o2_bs + n);
          O2hi[o] = h; O2lo[o] = l;
        }
      }
}

// ---------------- grid barrier.
// flat mode (round-6/7 verified): every block release-stores (wbl2 walk) + acquire-fences
// (inv walk) -> 64 walks per XCD per step, ~16us/step. hier mode: arrive via RELAXED sc1
// stores (no wbl2); ONE leader per XCD does the release (1 wbl2 flushes all 32 blocks'
// dirty L2 data) and ONE acquire fence (1 L2 inv); non-leaders only invalidate their
// private L1 (buffer_inv sc0). Requires bid&7 == physical XCD (verified at start; flat
// fallback otherwise).
__device__ __forceinline__ void gbar(uint32_t* S, int flat, uint32_t& gen) {
  __syncthreads();
  gen++;
  int bid = blockIdx.x;
  if (flat) {
    if (threadIdx.x == 0)
      __hip_atomic_store(S + (size_t)bid * 16, gen, __ATOMIC_RELEASE, __HIP_MEMORY_SCOPE_AGENT);
    if (bid == 0) {
      while (__hip_atomic_load(S + (size_t)threadIdx.x * 16, __ATOMIC_RELAXED, __HIP_MEMORY_SCOPE_AGENT) < gen)
        __builtin_amdgcn_s_sleep(2);
      __syncthreads();
      if (threadIdx.x == 0) {
        __builtin_amdgcn_fence(__ATOMIC_ACQUIRE, "agent");
        __hip_atomic_store(S + W_GREL, gen, __ATOMIC_RELEASE, __HIP_MEMORY_SCOPE_AGENT);
      }
      __syncthreads();
    } else {
      if (threadIdx.x == 0) {
        while (__hip_atomic_load(S + W_GREL, __ATOMIC_RELAXED, __HIP_MEMORY_SCOPE_AGENT) < gen)
          __builtin_amdgcn_s_sleep(2);
        __builtin_amdgcn_fence(__ATOMIC_ACQUIRE, "agent");
      }
      __syncthreads();
    }
  } else {
    int xcd = bid & 7, q = bid >> 3;
    if (q != 0) {
      if (threadIdx.x == 0) {
        asm volatile("s_waitcnt vmcnt(0)" ::: "memory");      // data in L2 before arriving
        __hip_atomic_store(S + (size_t)(xcd * 32 + q) * 16, gen, __ATOMIC_RELAXED, __HIP_MEMORY_SCOPE_AGENT);
        while (__hip_atomic_load(S + W_LREL + xcd * 16, __ATOMIC_RELAXED, __HIP_MEMORY_SCOPE_AGENT) < gen)
          __builtin_amdgcn_s_sleep(1);
        asm volatile("buffer_inv sc0" ::: "memory");          // L1-only invalidate
      }
      __builtin_amdgcn_sched_barrier(0);
      __syncthreads();
    } else {
      // XCD leader
      if (threadIdx.x < 31) {
        uint32_t* s = S + (size_t)(xcd * 32 + 1 + threadIdx.x) * 16;
        while (__hip_atomic_load(s, __ATOMIC_RELAXED, __HIP_MEMORY_SCOPE_AGENT) < gen)
          __builtin_amdgcn_s_sleep(1);
      }
      __syncthreads();
      if (threadIdx.x == 0)
        __hip_atomic_store(S + W_GARR + xcd * 16, gen, __ATOMIC_RELEASE, __HIP_MEMORY_SCOPE_AGENT);  // wbl2 flushes XCD
      if (xcd == 0) {
        if (threadIdx.x < 8) {
          while (__hip_atomic_load(S + W_GARR + threadIdx.x * 16, __ATOMIC_RELAXED, __HIP_MEMORY_SCOPE_AGENT) < gen)
            __builtin_amdgcn_s_sleep(1);
        }
        __syncthreads();
        if (threadIdx.x == 0)
          __hip_atomic_store(S + W_GREL, gen, __ATOMIC_RELEASE, __HIP_MEMORY_SCOPE_AGENT);
      }
      if (threadIdx.x == 0) {
        while (__hip_atomic_load(S + W_GREL, __ATOMIC_RELAXED, __HIP_MEMORY_SCOPE_AGENT) < gen)
          __builtin_amdgcn_s_sleep(1);
        __builtin_amdgcn_fence(__ATOMIC_ACQUIRE, "agent");    // 1 L2+L1 inv for this XCD
        // release (not relaxed): its waitcnt orders the inv before lrel becomes visible
        __hip_atomic_store(S + W_LREL + xcd * 16, gen, __ATOMIC_RELEASE, __HIP_MEMORY_SCOPE_AGENT);
      }
      __builtin_amdgcn_sched_barrier(0);
      __syncthreads();
    }
  }
}

// per-wave 16x16 NT tile, K=1024, B from GLOBAL (phase-2b only)
__device__ __forceinline__ f32x4v wtile16(
    const uint16_t* __restrict__ Ah, const uint16_t* __restrict__ Al,
    int a_cs, int a_bs, int m0,
    const uint16_t* __restrict__ Bh, const uint16_t* __restrict__ Bl,
    int n0, int lane) {
  int rsel = lane & 15, ko = (lane >> 4) * 8;
  int am = m0 + rsel;
  const uint16_t* pah = Ah + (size_t)(am >> 2) * a_cs + (size_t)(am & 3) * a_bs + ko;
  const uint16_t* pal = Al + (size_t)(am >> 2) * a_cs + (size_t)(am & 3) * a_bs + ko;
  const uint16_t* pbh = Bh + (size_t)(n0 + rsel) * 1024 + ko;
  const uint16_t* pbl = Bl + (size_t)(n0 + rsel) * 1024 + ko;
  f32x4v acc = {0.f, 0.f, 0.f, 0.f};
#pragma unroll 4
  for (int kt = 0; kt < 1024; kt += 32) {
    bf16x8 ah = *reinterpret_cast<const bf16x8*>(pah + kt);
    bf16x8 al = *reinterpret_cast<const bf16x8*>(pal + kt);
    bf16x8 bh = *reinterpret_cast<const bf16x8*>(pbh + kt);
    bf16x8 bl = *reinterpret_cast<const bf16x8*>(pbl + kt);
    acc = __builtin_amdgcn_mfma_f32_16x16x32_bf16(ah, bh, acc, 0, 0, 0);
    acc = __builtin_amdgcn_mfma_f32_16x16x32_bf16(ah, bl, acc, 0, 0, 0);
    acc = __builtin_amdgcn_mfma_f32_16x16x32_bf16(al, bh, acc, 0, 0, 0);
  }
  return acc;
}

// per-wave 16x16 NT tile, K=1024, B from LDS (XOR-swizzled 16B chunks), dual accumulator.
__device__ __forceinline__ f32x4v wtile16_lds(
    const uint16_t* __restrict__ Ah, const uint16_t* __restrict__ Al,
    int a_cs, int a_bs, int m0,
    const uint16_t* sBh, const uint16_t* sBl,
    int lane) {
  int rsel = lane & 15, ko = (lane >> 4) * 8;
  int am = m0 + rsel;
  const uint16_t* pah = Ah + (size_t)(am >> 2) * a_cs + (size_t)(am & 3) * a_bs + ko;
  const uint16_t* pal = Al + (size_t)(am >> 2) * a_cs + (size_t)(am & 3) * a_bs + ko;
  int rb = rsel * 1024;
  int s7 = rsel & 7;
  f32x4v acc0 = {0.f, 0.f, 0.f, 0.f}, acc1 = {0.f, 0.f, 0.f, 0.f};
#pragma unroll 4
  for (int kt = 0; kt < 1024; kt += 64) {
    int e0 = kt + ko, e1 = kt + 32 + ko;
    int o0 = rb + ((((e0) >> 3) ^ s7) << 3);
    int o1 = rb + ((((e1) >> 3) ^ s7) << 3);
    bf16x8 ah0 = *reinterpret_cast<const bf16x8*>(pah + kt);
    bf16x8 al0 = *reinterpret_cast<const bf16x8*>(pal + kt);
    bf16x8 ah1 = *reinterpret_cast<const bf16x8*>(pah + kt + 32);
    bf16x8 al1 = *reinterpret_cast<const bf16x8*>(pal + kt + 32);
    bf16x8 bh0 = *reinterpret_cast<const bf16x8*>(sBh + o0);
    bf16x8 bl0 = *reinterpret_cast<const bf16x8*>(sBl + o0);
    bf16x8 bh1 = *reinterpret_cast<const bf16x8*>(sBh + o1);
    bf16x8 bl1 = *reinterpret_cast<const bf16x8*>(sBl + o1);
    acc0 = __builtin_amdgcn_mfma_f32_16x16x32_bf16(ah0, bh0, acc0, 0, 0, 0);
    acc1 = __builtin_amdgcn_mfma_f32_16x16x32_bf16(ah1, bh1, acc1, 0, 0, 0);
    acc0 = __builtin_amdgcn_mfma_f32_16x16x32_bf16(ah0, bl0, acc0, 0, 0, 0);
    acc1 = __builtin_amdgcn_mfma_f32_16x16x32_bf16(ah1, bl1, acc1, 0, 0, 0);
    acc0 = __builtin_amdgcn_mfma_f32_16x16x32_bf16(al0, bh0, acc0, 0, 0, 0);
    acc1 = __builtin_amdgcn_mfma_f32_16x16x32_bf16(al1, bh1, acc1, 0, 0, 0);
  }
  return acc0 + acc1;
}

// ---------------- persistent per-layer kernel: 3-phase chunked scan (powers precomputed)
__global__ __launch_bounds__(256) void k_layer(
    uint32_t* S,
    float* __restrict__ P,
    uint16_t* __restrict__ PUh, uint16_t* __restrict__ PUl,
    uint16_t* __restrict__ Sh, uint16_t* __restrict__ Sl,
    const uint16_t* __restrict__ M1h, const uint16_t* __restrict__ M1l,
    const uint16_t* __restrict__ M16h, const uint16_t* __restrict__ M16l,
    const uint16_t* __restrict__ M128h, const uint16_t* __restrict__ M128l,
    uint16_t* G3h0, uint16_t* G3l0, uint16_t* G3h1, uint16_t* G3l1,
    uint16_t* BEh, uint16_t* BEl,
    float* LAMf, uint16_t* LAMh, uint16_t* LAMl,
    uint16_t* GSh0, uint16_t* GSl0, uint16_t* GSh1, uint16_t* GSl1,
    const float* __restrict__ starterL) {
  __shared__ uint16_t sB[2][32 * 1024];   // 128 KB
  int tid = threadIdx.x, bid = blockIdx.x;
  int lane = tid & 63;
  int wv = tid >> 6;
  int xcd = bid & 7;
  int q = bid >> 3;
  uint32_t gen = 0;
  int rowg = (lane >> 4) * 4, colg = lane & 15;

  int nt13 = xcd * 8 + (q & 7);
  int m0_13 = ((q >> 3) * 4 + wv) * 16;
  int n0_13 = nt13 * 16;
  int m0_2 = (wv & 1) * 16;
  int nt2 = xcd * 8 + q * 2 + (wv >> 1);
  int n0_2 = nt2 * 16;
  int lrb2 = (wv >> 1) * 16 * 1024;
  int n0_b = (xcd * 8 + q * 4 + wv) * 16;

  // init: sigma_0 = starter broadcast
  {
    int idx = bid * 256 + tid;
    if (idx < BATCH * DIMX) {
      int b = idx >> 10, d = idx & 1023;
      float v = starterL[d];
      uint16_t h, l;
      fsplit(v, h, l);
      size_t o = (size_t)b * 1024 + d;
      BEh[o] = h; BEl[o] = l;
      G3h0[o] = h; G3l0[o] = l;
      GSh0[o] = h; GSl0[o] = l;
      Sh[o] = h; Sl[o] = l;
    }
  }

  // ---- verify bid&7 == physical XCD; any mismatch -> flat barriers for whole kernel
  if (threadIdx.x == 0 && get_xcc() != (uint32_t)xcd)
    __hip_atomic_store(S + W_FLAG, 1u, __ATOMIC_RELAXED, __HIP_MEMORY_SCOPE_AGENT);
  gbar(S, 1, gen);   // flat verification barrier (also publishes init + flag)
  int flat = (int)__hip_atomic_load(S + W_FLAG, __ATOMIC_RELAXED, __HIP_MEMORY_SCOPE_AGENT);

  // stage M1 B-slice (16 rows at n0_13) into LDS, swizzled
  {
    const uint16_t* gh = M1h + (size_t)n0_13 * 1024;
    const uint16_t* gl = M1l + (size_t)n0_13 * 1024;
    for (int i = tid; i < 16 * 128; i += 256) {
      int r = i >> 7, c8 = i & 127;
      int dst = r * 1024 + ((c8 ^ (r & 7)) << 3);
      *reinterpret_cast<bf16x8*>(&sB[0][dst]) = *reinterpret_cast<const bf16x8*>(gh + (size_t)r * 1024 + c8 * 8);
      *reinterpret_cast<bf16x8*>(&sB[1][dst]) = *reinterpret_cast<const bf16x8*>(gl + (size_t)r * 1024 + c8 * 8);
    }
  }
  __syncthreads();

  // ---- phase 1: l_j = A l_{j-1} + u_j, j=1..15
  for (int j = 1; j < 16; ++j) {
    {
      f32x4v acc = wtile16_lds(PUh + (size_t)(j - 1) * 4096, PUl + (size_t)(j - 1) * 4096,
                               65536, 1024, m0_13, &sB[0][0], &sB[1][0], lane);
      int n = n0_13 + colg;
#pragma unroll
      for (int rr = 0; rr < 4; ++rr) {
        int m = m0_13 + rowg + rr;
        int c = m >> 2, b = m & 3;
        size_t t = (size_t)(c * 16 + j);
        float* pu = P + (t * 4 + b) * 2048 + 1024 + n;
        float v = acc[rr] + *pu;
        *pu = v;
        uint16_t h, l;
        fsplit(v, h, l);
        size_t o = (t * 4 + b) * 1024 + n;
        PUh[o] = h; PUl[o] = l;
      }
    }
    gbar(S, flat, gen);
  }

  // ---- phase 2a init: lambda_0 = e_{8g}
  {
    int idx = bid * 256 + tid;
    if (idx < 32 * 1024) {
      int r = idx >> 10, d = idx & 1023;
      int g = r >> 2, b = r & 3;
      float v = P[((size_t)(g * 128 + 15) * 4 + b) * 2048 + 1024 + d];
      LAMf[idx] = v;
      uint16_t h, l;
      fsplit(v, h, l);
      LAMh[idx] = h; LAMl[idx] = l;
    }
  }
  gbar(S, flat, gen);

  // stage M16 (32 rows) for active blocks
  if (q < 4) {
    int nb = (xcd * 8 + q * 2) * 16;
    const uint16_t* gh = M16h + (size_t)nb * 1024;
    const uint16_t* gl = M16l + (size_t)nb * 1024;
    for (int i = tid; i < 32 * 128; i += 256) {
      int r = i >> 7, c8 = i & 127;
      int dst = r * 1024 + ((c8 ^ (r & 7)) << 3);
      *reinterpret_cast<bf16x8*>(&sB[0][dst]) = *reinterpret_cast<const bf16x8*>(gh + (size_t)r * 1024 + c8 * 8);
      *reinterpret_cast<bf16x8*>(&sB[1][dst]) = *reinterpret_cast<const bf16x8*>(gl + (size_t)r * 1024 + c8 * 8);
    }
  }
  __syncthreads();

  // ---- phase 2a: lambda_j = A16 lambda_{j-1} + e_{8g+j}, j=1..7
  for (int j = 1; j < 8; ++j) {
    if (q < 4) {
      f32x4v acc = wtile16_lds(LAMh + (size_t)(j - 1) * 32768, LAMl + (size_t)(j - 1) * 32768,
                               4096, 1024, m0_2, &sB[0][lrb2], &sB[1][lrb2], lane);
      int n = n0_2 + colg;
#pragma unroll
      for (int rr = 0; rr < 4; ++rr) {
        int m = m0_2 + rowg + rr;
        int g = m >> 2, b = m & 3;
        int c = 8 * g + j;
        float e = P[((size_t)(c * 16 + 15) * 4 + b) * 2048 + 1024 + n];
        float v = acc[rr] + e;
        size_t o = (size_t)j * 32768 + (size_t)m * 1024 + n;
        LAMf[o] = v;
        uint16_t h, l;
        fsplit(v, h, l);
        LAMh[o] = h; LAMl[o] = l;
      }
    }
    gbar(S, flat, gen);
  }

  // ---- phase 2b: beta_{g+1} = A128 beta_g + lambda_7(g), g=0..6
  for (int g = 0; g < 7; ++g) {
    if (q < 2) {
      f32x4v acc = wtile16(BEh + (size_t)g * 16384, BEl + (size_t)g * 16384,
                           4096, 1024, 0, M128h, M128l, n0_b, lane);
      if ((lane >> 4) == 0) {
        int n = n0_b + colg;
#pragma unroll
        for (int rr = 0; rr < 4; ++rr) {
          int b = rr;
          float v = acc[rr] + LAMf[(size_t)7 * 32768 + (size_t)(g * 4 + b) * 1024 + n];
          uint16_t h, l;
          fsplit(v, h, l);
          size_t ob = (size_t)(g + 1) * 16384 + (size_t)b * 1024 + n;
          BEh[ob] = h; BEl[ob] = l;
          int c = 8 * (g + 1);
          size_t o1 = (size_t)(c * 4 + b) * 1024 + n;
          G3h0[o1] = h; G3l0[o1] = l;
          size_t o2 = ((size_t)(c * 16) * 4 + b) * 1024 + n;
          Sh[o2] = h; Sl[o2] = l;
          size_t o3 = (size_t)((g + 1) * 4 + b) * 1024 + n;
          GSh0[o3] = h; GSl0[o3] = l;
        }
      }
    }
    gbar(S, flat, gen);
  }

  // ---- phase 2c: Gs_j = A16 Gs_{j-1}; sigma_{8g+j} = Gs_j + lambda_{j-1}, j=1..7
  int gsc = 0;
  for (int j = 1; j < 8; ++j) {
    uint16_t* gih = gsc ? GSh1 : GSh0;
    uint16_t* gil = gsc ? GSl1 : GSl0;
    uint16_t* goh = gsc ? GSh0 : GSh1;
    uint16_t* gol = gsc ? GSl0 : GSl1;
    if (q < 4) {
      f32x4v acc = wtile16_lds(gih, gil, 4096, 1024, m0_2, &sB[0][lrb2], &sB[1][lrb2], lane);
      int n = n0_2 + colg;
#pragma unroll
      for (int rr = 0; rr < 4; ++rr) {
        int m = m0_2 + rowg + rr;
        int g = m >> 2, b = m & 3;
        int c = 8 * g + j;
        float lam = LAMf[(size_t)(j - 1) * 32768 + (size_t)m * 1024 + n];
        float v = acc[rr] + lam;
        uint16_t h, l;
        fsplit(v, h, l);
        size_t o1 = (size_t)(c * 4 + b) * 1024 + n;
        G3h0[o1] = h; G3l0[o1] = l;
        size_t o2 = ((size_t)(c * 16) * 4 + b) * 1024 + n;
        Sh[o2] = h; Sl[o2] = l;
        uint16_t h2, l2;
        fsplit(acc[rr], h2, l2);
        goh[(size_t)m * 1024 + n] = h2;
        gol[(size_t)m * 1024 + n] = l2;
      }
    }
    gbar(S, flat, gen);
    gsc ^= 1;
  }

  // re-stage M1 B-slice for phase 3
  {
    const uint16_t* gh = M1h + (size_t)n0_13 * 1024;
    const uint16_t* gl = M1l + (size_t)n0_13 * 1024;
    for (int i = tid; i < 16 * 128; i += 256) {
      int r = i >> 7, c8 = i & 127;
      int dst = r * 1024 + ((c8 ^ (r & 7)) << 3);
      *reinterpret_cast<bf16x8*>(&sB[0][dst]) = *reinterpret_cast<const bf16x8*>(gh + (size_t)r * 1024 + c8 * 8);
      *reinterpret_cast<bf16x8*>(&sB[1][dst]) = *reinterpret_cast<const bf16x8*>(gl + (size_t)r * 1024 + c8 * 8);
    }
  }
  __syncthreads();

  // ---- phase 3: G_j = A G_{j-1}; S[c*16+j] = G_j + l_{c*16+j-1}, j=1..15
  int g3 = 0;
  for (int j = 1; j < 16; ++j) {
    uint16_t* gih = g3 ? G3h1 : G3h0;
    uint16_t* gil = g3 ? G3l1 : G3l0;
    uint16_t* goh = g3 ? G3h0 : G3h1;
    uint16_t* gol = g3 ? G3l0 : G3l1;
    {
      f32x4v acc = wtile16_lds(gih, gil, 4096, 1024, m0_13, &sB[0][0], &sB[1][0], lane);
      int n = n0_13 + colg;
#pragma unroll
      for (int rr = 0; rr < 4; ++rr) {
        int m = m0_13 + rowg + rr;
        int c = m >> 2, b = m & 3;
        float u = P[((size_t)(c * 16 + j - 1) * 4 + b) * 2048 + 1024 + n];
        float v = acc[rr] + u;
        uint16_t h, l;
        fsplit(v, h, l);
        size_t o = ((size_t)(c * 16 + j) * 4 + b) * 1024 + n;
        Sh[o] = h; Sl[o] = l;
        uint16_t h2, l2;
        fsplit(acc[rr], h2, l2);
        goh[(size_t)m * 1024 + n] = h2;
        gol[(size_t)m * 1024 + n] = l2;
      }
    }
    if (j < 15) gbar(S, flat, gen);
    g3 ^= 1;
  }
}

// ---------------- reorder H_hi [t][b][d] -> Y [b][t][d]
__global__ __launch_bounds__(256) void k_reorder_hi(const uint16_t* __restrict__ Hhi, uint16_t* __restrict__ Y) {
  int idx = blockIdx.x * 256 + threadIdx.x;
  int d4 = idx & (DIMX / 4 - 1);
  int tb = idx >> 8;
  int t = tb >> 2, b = tb & 3;
  ushort4 v = reinterpret_cast<const ushort4*>(Hhi)[idx];
  reinterpret_cast<ushort4*>(Y + (size_t)(b * SEQ + t) * DIMX)[d4] = v;
}

__global__ __launch_bounds__(256) void k_cast_w(const float* __restrict__ src, uint16_t* __restrict__ dst, int n4) {
  int idx = blockIdx.x * 256 + threadIdx.x;
  if (idx >= n4) return;
  float4 v = reinterpret_cast<const float4*>(src)[idx];
  ushort4 o;
  o.x = f2b(v.x); o.y = f2b(v.y); o.z = f2b(v.z); o.w = f2b(v.w);
  reinterpret_cast<ushort4*>(dst)[idx] = o;
}

// ---------------- logits GEMM: bf16 MFMA 128x128
__global__ __launch_bounds__(256) void k_logits(const uint16_t* __restrict__ A,
                                                const uint16_t* __restrict__ Bt,
                                                float* __restrict__ C) {
  __shared__ uint16_t As[128 * 32];
  __shared__ uint16_t Bs[128 * 32];
  int tid = threadIdx.x;
  int bx = blockIdx.x, by = blockIdx.y;
  int lane = tid & 63, wave = tid >> 6;
  int wm = wave >> 1, wn = wave & 1;
  f32x4v acc[4][4] = {};
  const uint16_t* Ag = A + (size_t)by * 128 * 1024;
  const uint16_t* Bg = Bt + (size_t)bx * 128 * 1024;
  for (int kt = 0; kt < 1024; kt += 32) {
    __syncthreads();
#pragma unroll
    for (int q = 0; q < 2; ++q) {
      int off = q * 4096 + tid * 16;
      int r = off >> 6, cu = (off & 63) >> 1;
      __builtin_amdgcn_global_load_lds(
          (const __attribute__((address_space(1))) uint32_t*)(Ag + (size_t)r * 1024 + kt + cu),
          (__attribute__((address_space(3))) uint32_t*)((char*)As + off), 16, 0, 0);
      __builtin_amdgcn_global_load_lds(
          (const __attribute__((address_space(1))) uint32_t*)(Bg + (size_t)r * 1024 + kt + cu),
          (__attribute__((address_space(3))) uint32_t*)((char*)Bs + off), 16, 0, 0);
    }
    __syncthreads();
    int rsel = lane & 15, ko = (lane >> 4) * 8;
    bf16x8 af[4], bfr[4];
#pragma unroll
    for (int mf = 0; mf < 4; ++mf)
      af[mf] = *reinterpret_cast<const bf16x8*>(As + (wm * 64 + mf * 16 + rsel) * 32 + ko);
#pragma unroll
    for (int nf = 0; nf < 4; ++nf)
      bfr[nf] = *reinterpret_cast<const bf16x8*>(Bs + (wn * 64 + nf * 16 + rsel) * 32 + ko);
#pragma unroll
    for (int mf = 0; mf < 4; ++mf)
#pragma unroll
      for (int nf = 0; nf < 4; ++nf)
        acc[mf][nf] = __builtin_amdgcn_mfma_f32_16x16x32_bf16(af[mf], bfr[nf], acc[mf][nf], 0, 0, 0);
  }
  int rowg = (lane >> 4) * 4;
  int colg = lane & 15;
#pragma unroll
  for (int mf = 0; mf < 4; ++mf)
#pragma unroll
    for (int nf = 0; nf < 4; ++nf)
#pragma unroll
      for (int r = 0; r < 4; ++r) {
        int m = by * 128 + wm * 64 + mf * 16 + rowg + r;
        int n = bx * 128 + wn * 64 + nf * 16 + colg;
        C[(size_t)m * VOCAB + n] = acc[mf][nf][r];
      }
}

// =========================================================================
extern "C" void kernel_launch(void* const* d_in, const int* in_sizes, int n_in,
                              void* d_out, int out_size, void* d_ws, size_t ws_size,
                              hipStream_t stream) {
  const int* ids = (const int*)d_in[0];
  const float* emb = (const float*)d_in[1];
  const float* W = (const float*)d_in[2];
  const float* outw = (const float*)d_in[3];
  const float* starter = (const float*)d_in[4];
  float* out = (float*)d_out;

  char* wsb = (char*)d_ws;
  size_t off = 0;
  auto alloc = [&](size_t bytes) {
    void* p = wsb + off;
    off = (off + bytes + 255) & ~(size_t)255;
    return p;
  };
  const size_t TB = SEQ * BATCH;
  const size_t MB1 = (size_t)1024 * 1024;

  uint32_t* SYNC = (uint32_t*)alloc((size_t)NLAYERS * 8192 * 4);
  uint16_t* Hh[2] = {(uint16_t*)alloc(TB * DIMX * 2), (uint16_t*)alloc(TB * DIMX * 2)};
  uint16_t* Hl[2] = {(uint16_t*)alloc(TB * DIMX * 2), (uint16_t*)alloc(TB * DIMX * 2)};
  float* P = (float*)alloc(TB * 2 * DIMX * 4);
  uint16_t* PUh = (uint16_t*)alloc(TB * DIMX * 2);
  uint16_t* PUl = (uint16_t*)alloc(TB * DIMX * 2);
  uint16_t* Sh = (uint16_t*)alloc(TB * DIMX * 2);
  uint16_t* Sl = (uint16_t*)alloc(TB * DIMX * 2);
  uint16_t* W1h = (uint16_t*)alloc((size_t)NLAYERS * 2048 * 1024 * 2);
  uint16_t* W1l = (uint16_t*)alloc((size_t)NLAYERS * 2048 * 1024 * 2);
  uint16_t* WSh = (uint16_t*)alloc((size_t)NLAYERS * MB1 * 2);
  uint16_t* WSl = (uint16_t*)alloc((size_t)NLAYERS * MB1 * 2);
  uint16_t* M1h = (uint16_t*)alloc((size_t)NLAYERS * MB1 * 2);
  uint16_t* M1l = (uint16_t*)alloc((size_t)NLAYERS * MB1 * 2);
  uint16_t* T1h = (uint16_t*)alloc((size_t)NLAYERS * MB1 * 2);
  uint16_t* T1l = (uint16_t*)alloc((size_t)NLAYERS * MB1 * 2);
  uint16_t* M16Ah = (uint16_t*)alloc((size_t)NLAYERS * MB1 * 2);
  uint16_t* M16Al = (uint16_t*)alloc((size_t)NLAYERS * MB1 * 2);
  uint16_t* M128Ah = (uint16_t*)alloc((size_t)NLAYERS * MB1 * 2);
  uint16_t* M128Al = (uint16_t*)alloc((size_t)NLAYERS * MB1 * 2);
  uint16_t* G3h0 = (uint16_t*)alloc((size_t)256 * 1024 * 2);
  uint16_t* G3l0 = (uint16_t*)alloc((size_t)256 * 1024 * 2);
  uint16_t* G3h1 = (uint16_t*)alloc((size_t)256 * 1024 * 2);
  uint16_t* G3l1 = (uint16_t*)alloc((size_t)256 * 1024 * 2);
  uint16_t* BEh = (uint16_t*)alloc((size_t)8 * 16 * 1024 * 2);
  uint16_t* BEl = (uint16_t*)alloc((size_t)8 * 16 * 1024 * 2);
  float* LAMf = (float*)alloc((size_t)8 * 32 * 1024 * 4);
  uint16_t* LAMh = (uint16_t*)alloc((size_t)8 * 32 * 1024 * 2);
  uint16_t* LAMl = (uint16_t*)alloc((size_t)8 * 32 * 1024 * 2);
  uint16_t* GSh0 = (uint16_t*)alloc((size_t)32 * 1024 * 2);
  uint16_t* GSl0 = (uint16_t*)alloc((size_t)32 * 1024 * 2);
  uint16_t* GSh1 = (uint16_t*)alloc((size_t)32 * 1024 * 2);
  uint16_t* GSl1 = (uint16_t*)alloc((size_t)32 * 1024 * 2);
  uint16_t* YSB = (uint16_t*)alloc(TB * DIMX * 2);
  uint16_t* OWB = (uint16_t*)alloc((size_t)VOCAB * DIMX * 2);

  // power-chain ping-pong buffers overlaid on P / S / H[1]
  uint16_t* CMh[2] = {(uint16_t*)P, Sh};
  uint16_t* CMl[2] = {(uint16_t*)P + 4 * MB1, Sl};
  uint16_t* CTh[2] = {(uint16_t*)P + 8 * MB1, Hh[1]};
  uint16_t* CTl[2] = {(uint16_t*)P + 12 * MB1, Hl[1]};

  hipMemsetAsync(SYNC, 0, (size_t)NLAYERS * 8192 * 4, stream);
  k_split_w<<<NLAYERS * 4096, 256, 0, stream>>>(W, W1h, W1l, WSh, WSl, M1h, M1l);
  k_trans_w<<<dim3(16, 16, NLAYERS), 256, 0, stream>>>(W, T1h, T1l);
  k_cast_w<<<(int)((size_t)VOCAB * DIMX / 4 / 256), 256, 0, stream>>>(outw, OWB, VOCAB * DIMX / 4);
  k_embed_split<<<(int)(TB * DIMX / 4 / 256), 256, 0, stream>>>(ids, emb, Hh[0], Hl[0]);

  // power chain: level k -> A^(2^k)
  {
    const uint16_t *inMh = M1h, *inMl = M1l, *inTh = T1h, *inTl = T1l;
    for (int k = 1; k <= 7; ++k) {
      uint16_t *oMh, *oMl;
      if (k == 4) { oMh = M16Ah; oMl = M16Al; }
      else if (k == 7) { oMh = M128Ah; oMl = M128Al; }
      else { oMh = CMh[k & 1]; oMl = CMl[k & 1]; }
      uint16_t* oTh = (k < 7) ? CTh[k & 1] : nullptr;
      uint16_t* oTl = (k < 7) ? CTl[k & 1] : nullptr;
      k_mfma<128, 128><<<dim3(8, 8, NLAYERS), 256, 0, stream>>>(
          1024,
          inMh, inMl, 4096, 1024, MB1,
          inTh, inTl, 1024, MB1,
          nullptr, 0, 0,
          nullptr, 0, 0,
          oMh, oMl, 4096, 1024, 0, MB1,
          oTh, oTl, 1024, 0, MB1);
      inMh = oMh; inMl = oMl; inTh = oTh; inTl = oTl;
    }
  }

  int cur = 0;
  for (int l = 0; l < NLAYERS; ++l) {
    // [a|u] = H @ W[:,0:1024]^T ; f32 -> P, split(u) -> PU
    k_mfma<128, 128><<<dim3(16, 32, 1), 256, 0, stream>>>(
        1024,
        Hh[cur], Hl[cur], 4096, 1024, 0,
        W1h + (size_t)l * 2048 * 1024, W1l + (size_t)l * 2048 * 1024, 1024, 0,
        nullptr, 0, 0,
        P, 8192, 2048,
        PUh, PUl, 4096, 1024, 1024, 0,
        nullptr, nullptr, 0, 1, 0);

    // persistent: phase1 + phase2 + phase3
    k_layer<<<NBLK, 256, 0, stream>>>(
        SYNC + (size_t)l * 8192,
        P, PUh, PUl, Sh, Sl,
        M1h + (size_t)l * MB1, M1l + (size_t)l * MB1,
        M16Ah + (size_t)l * MB1, M16Al + (size_t)l * MB1,
        M128Ah + (size_t)l * MB1, M128Al + (size_t)l * MB1,
        G3h0, G3l0, G3h1, G3l1,
        BEh, BEl, LAMf, LAMh, LAMl,
        GSh0, GSl0, GSh1, GSl1,
        starter + (size_t)l * DIMX);

    // H_next = a + S @ W_hs^T (split out)
    k_mfma<128, 128><<<dim3(8, 32, 1), 256, 0, stream>>>(
        1024,
        Sh, Sl, 4096, 1024, 0,
        WSh + (size_t)l * MB1, WSl + (size_t)l * MB1, 1024, 0,
        P, 8192, 2048,
        nullptr, 0, 0,
        Hh[cur ^ 1], Hl[cur ^ 1], 4096, 1024, 0, 0,
        nullptr, nullptr, 0, 1, 0);
    cur ^= 1;
  }

  k_reorder_hi<<<(int)(TB * DIMX / 4 / 256), 256, 0, stream>>>(Hh[cur], YSB);
  k_logits<<<dim3(VOCAB / 128, TB / 128), 256, 0, stream>>>(YSB, OWB, out);
}

// Round 9
// 4205.848 us; speedup vs baseline: 2.9778x; 1.0056x over previous
//
#include <hip/hip_runtime.h>
#include <hip/hip_bf16.h>
#include <stdint.h>

#define BATCH 4
#define SEQ 1024
#define DIMX 1024
#define VOCAB 32000
#define NLAYERS 4
#define NBLK 256   // blocks in persistent kernel (1/CU)

// SYNC word layout per layer (stride-16 words = 64B slots):
//   [ (xcd*32+q)*16 ] : arrive slots (flat mode: idx=bid)
//   [ 4096+xcd*16 ]   : per-XCD global arrive
//   [ 4608 ]          : global release
//   [ 4864+xcd*16 ]   : per-XCD local release
//   [ 5120 ]          : mapping-mismatch flag
#define W_GARR 4096
#define W_GREL 4608
#define W_LREL 4864
#define W_FLAG 5120

using bf16x8 = __attribute__((ext_vector_type(8))) short;
using f32x4v = __attribute__((ext_vector_type(4))) float;

__device__ __forceinline__ uint16_t f2b(float f) {
  __hip_bfloat16 h = __float2bfloat16(f);
  return *reinterpret_cast<uint16_t*>(&h);
}
__device__ __forceinline__ float b2f(uint16_t u) {
  __hip_bfloat16 h = *reinterpret_cast<__hip_bfloat16*>(&u);
  return __bfloat162float(h);
}
__device__ __forceinline__ void fsplit(float v, uint16_t& h, uint16_t& l) {
  h = f2b(v);
  l = f2b(v - b2f(h));
}

__device__ __forceinline__ uint32_t get_xcc() {
  uint32_t x;
  asm volatile("s_getreg_b32 %0, hwreg(HW_REG_XCC_ID)" : "=s"(x));
  return x & 7u;
}

// ---------------- embedding gather -> split bf16: row (t*4+b)
__global__ __launch_bounds__(256) void k_embed_split(const int* __restrict__ ids,
                                                     const float* __restrict__ emb,
                                                     uint16_t* __restrict__ Hhi,
                                                     uint16_t* __restrict__ Hlo) {
  int idx = blockIdx.x * 256 + threadIdx.x;
  int d4 = idx & (DIMX / 4 - 1);
  int tb = idx >> 8;
  int t = tb >> 2, b = tb & 3;
  int id = ids[b * SEQ + t];
  float4 v = reinterpret_cast<const float4*>(emb + (size_t)id * DIMX)[d4];
  ushort4 h, l;
  fsplit(v.x, h.x, l.x); fsplit(v.y, h.y, l.y); fsplit(v.z, h.z, l.z); fsplit(v.w, h.w, l.w);
  reinterpret_cast<ushort4*>(Hhi)[idx] = h;
  reinterpret_cast<ushort4*>(Hlo)[idx] = l;
}

// ---------------- split all layers' weights: W1 (2048 rows), WS (1024), M1=Wss (1024)
__global__ __launch_bounds__(256) void k_split_w(const float* __restrict__ W,
                                                 uint16_t* __restrict__ W1h, uint16_t* __restrict__ W1l,
                                                 uint16_t* __restrict__ WSh, uint16_t* __restrict__ WSl,
                                                 uint16_t* __restrict__ M1h, uint16_t* __restrict__ M1l) {
  int idx = blockIdx.x * 256 + threadIdx.x;
  int c4 = idx & 255;
  int row = idx >> 8;
  int l = row >> 12, r = row & 4095;
  const float* Wl = W + (size_t)l * 4 * 1024 * 1024;
  const float* src;
  uint16_t *dh, *dl;
  size_t doff;
  if (r < 2048) { src = Wl + (size_t)r * 2048; dh = W1h; dl = W1l; doff = ((size_t)l * 2048 + r) * 1024; }
  else if (r < 3072) { int rr = r - 2048; src = Wl + (size_t)rr * 2048 + 1024; dh = WSh; dl = WSl; doff = ((size_t)l * 1024 + rr) * 1024; }
  else { int rr = r - 3072; src = Wl + (size_t)(1024 + rr) * 2048 + 1024; dh = M1h; dl = M1l; doff = ((size_t)l * 1024 + rr) * 1024; }
  float4 v = reinterpret_cast<const float4*>(src)[c4];
  ushort4 h, lo4;
  fsplit(v.x, h.x, lo4.x); fsplit(v.y, h.y, lo4.y); fsplit(v.z, h.z, lo4.z); fsplit(v.w, h.w, lo4.w);
  reinterpret_cast<ushort4*>(dh + doff)[c4] = h;
  reinterpret_cast<ushort4*>(dl + doff)[c4] = lo4;
}

// ---------------- T1 = Wss^T per layer (LDS-tiled transpose + split)
__global__ __launch_bounds__(256) void k_trans_w(const float* __restrict__ W,
                                                 uint16_t* __restrict__ T1h, uint16_t* __restrict__ T1l) {
  __shared__ float t[64][65];
  int l = blockIdx.z;
  const float* Wl = W + (size_t)l * 4 * 1024 * 1024;
  int i0 = blockIdx.y * 64, j0 = blockIdx.x * 64;
  int c4 = (threadIdx.x & 15) * 4, rr = threadIdx.x >> 4;
#pragma unroll
  for (int p = 0; p < 4; ++p) {
    int r = rr + p * 16;
    float4 v = *reinterpret_cast<const float4*>(Wl + (size_t)(1024 + i0 + r) * 2048 + 1024 + j0 + c4);
    t[r][c4] = v.x; t[r][c4 + 1] = v.y; t[r][c4 + 2] = v.z; t[r][c4 + 3] = v.w;
  }
  __syncthreads();
#pragma unroll
  for (int p = 0; p < 4; ++p) {
    int j = rr + p * 16;
    ushort4 h, l4;
    fsplit(t[c4 + 0][j], h.x, l4.x);
    fsplit(t[c4 + 1][j], h.y, l4.y);
    fsplit(t[c4 + 2][j], h.z, l4.z);
    fsplit(t[c4 + 3][j], h.w, l4.w);
    size_t o = (size_t)l * 1024 * 1024 + (size_t)(j0 + j) * 1024 + i0 + c4;
    *reinterpret_cast<ushort4*>(T1h + o) = h;
    *reinterpret_cast<ushort4*>(T1l + o) = l4;
  }
}

// ---------------- split-bf16 MFMA GEMM (NT), 128x128 tile, optional z-batch.
template <int BM, int BN>
__global__ __launch_bounds__(256) void k_mfma(
    int K,
    const uint16_t* __restrict__ Ahi, const uint16_t* __restrict__ Alo, int a_cs, int a_bs, size_t a_z,
    const uint16_t* __restrict__ Bhi, const uint16_t* __restrict__ Blo, int ldb, size_t b_z,
    const float* __restrict__ ADD, int add_cs, int add_bs,
    float* __restrict__ O1f, int o1_cs, int o1_bs,
    uint16_t* __restrict__ O1hi, uint16_t* __restrict__ O1lo, int o1s_cs, int o1s_bs, int split_n0, size_t o1_z,
    uint16_t* __restrict__ O2hi, uint16_t* __restrict__ O2lo, int o2_cs, int o2_bs, size_t o2_z) {
  constexpr int FM = BM / 32;
  constexpr int FN = BN / 32;
  __shared__ uint16_t sAh[BM * 32], sAl[BM * 32], sBh[BN * 32], sBl[BN * 32];
  size_t zb = blockIdx.z;
  Ahi += zb * a_z; Alo += zb * a_z;
  Bhi += zb * b_z; Blo += zb * b_z;
  if (O1hi) { O1hi += zb * o1_z; O1lo += zb * o1_z; }
  if (O2hi) { O2hi += zb * o2_z; O2lo += zb * o2_z; }
  int tid = threadIdx.x;
  int lane = tid & 63;
  int wave = tid >> 6;
  int wm = wave >> 1, wn = wave & 1;
  int m0 = blockIdx.y * BM, n0 = blockIdx.x * BN;
  f32x4v acc[FM][FN] = {};
  for (int kt = 0; kt < K; kt += 32) {
    __syncthreads();
#pragma unroll
    for (int q = 0; q < BM / 64; ++q) {
      int off = q * 4096 + tid * 16;
      int r = off >> 6;
      int cu = (off & 63) >> 1;
      size_t goff = (size_t)(m0 / 4 + (r >> 2)) * a_cs + (size_t)(r & 3) * a_bs + kt + cu;
      __builtin_amdgcn_global_load_lds(
          (const __attribute__((address_space(1))) uint32_t*)(Ahi + goff),
          (__attribute__((address_space(3))) uint32_t*)((char*)sAh + off), 16, 0, 0);
      __builtin_amdgcn_global_load_lds(
          (const __attribute__((address_space(1))) uint32_t*)(Alo + goff),
          (__attribute__((address_space(3))) uint32_t*)((char*)sAl + off), 16, 0, 0);
    }
#pragma unroll
    for (int q = 0; q < BN / 64; ++q) {
      int off = q * 4096 + tid * 16;
      int r = off >> 6, cu = (off & 63) >> 1;
      size_t goff = (size_t)(n0 + r) * ldb + kt + cu;
      __builtin_amdgcn_global_load_lds(
          (const __attribute__((address_space(1))) uint32_t*)(Bhi + goff),
          (__attribute__((address_space(3))) uint32_t*)((char*)sBh + off), 16, 0, 0);
      __builtin_amdgcn_global_load_lds(
          (const __attribute__((address_space(1))) uint32_t*)(Blo + goff),
          (__attribute__((address_space(3))) uint32_t*)((char*)sBl + off), 16, 0, 0);
    }
    __syncthreads();
    int rsel = lane & 15, ko = (lane >> 4) * 8;
    bf16x8 ah[FM], al[FM], bh[FN], bl[FN];
#pragma unroll
    for (int mf = 0; mf < FM; ++mf) {
      int row = wm * (FM * 16) + mf * 16 + rsel;
      ah[mf] = *reinterpret_cast<const bf16x8*>(sAh + row * 32 + ko);
      al[mf] = *reinterpret_cast<const bf16x8*>(sAl + row * 32 + ko);
    }
#pragma unroll
    for (int nf = 0; nf < FN; ++nf) {
      int row = wn * (FN * 16) + nf * 16 + rsel;
      bh[nf] = *reinterpret_cast<const bf16x8*>(sBh + row * 32 + ko);
      bl[nf] = *reinterpret_cast<const bf16x8*>(sBl + row * 32 + ko);
    }
#pragma unroll
    for (int mf = 0; mf < FM; ++mf)
#pragma unroll
      for (int nf = 0; nf < FN; ++nf) {
        acc[mf][nf] = __builtin_amdgcn_mfma_f32_16x16x32_bf16(ah[mf], bh[nf], acc[mf][nf], 0, 0, 0);
        acc[mf][nf] = __builtin_amdgcn_mfma_f32_16x16x32_bf16(ah[mf], bl[nf], acc[mf][nf], 0, 0, 0);
        acc[mf][nf] = __builtin_amdgcn_mfma_f32_16x16x32_bf16(al[mf], bh[nf], acc[mf][nf], 0, 0, 0);
      }
  }
  int rowg = (lane >> 4) * 4, colg = lane & 15;
#pragma unroll
  for (int mf = 0; mf < FM; ++mf)
#pragma unroll
    for (int nf = 0; nf < FN; ++nf)
#pragma unroll
      for (int r = 0; r < 4; ++r) {
        int m = m0 + wm * (FM * 16) + mf * 16 + rowg + r;
        int n = n0 + wn * (FN * 16) + nf * 16 + colg;
        size_t ro = (size_t)(m >> 2);
        float dot = acc[mf][nf][r];
        float v = dot;
        if (ADD) v += ADD[ro * add_cs + (size_t)(m & 3) * add_bs + n];
        if (O1f) O1f[ro * o1_cs + (size_t)(m & 3) * o1_bs + n] = v;
        if (O1hi && n >= split_n0) {
          uint16_t h, l;
          fsplit(v, h, l);
          size_t o = ro * o1s_cs + (size_t)(m & 3) * o1s_bs + (n - split_n0);
          O1hi[o] = h; O1lo[o] = l;
        }
        if (O2hi) {
          uint16_t h, l;
          fsplit(dot, h, l);
          size_t o = (o2_bs == 0) ? ((size_t)n * o2_cs + m)
                                  : (ro * o2_cs + (size_t)(m & 3) * o2_bs + n);
          O2hi[o] = h; O2lo[o] = l;
        }
      }
}

// ---------------- barriers.
// mode: flat (all-global, round-6) / hier global (round-8: 1 wbl2 + 1 inv per XCD) /
// LOCAL (new): within-XCD only — blocks on one XCD share a coherent L2, so sync needs
// only vmcnt-drained stores (done by __syncthreads) + relaxed L3 sync words + L1 inv.
// NO wbl2, NO L2 inv -> read-only panels stay L2-resident across steps.
__device__ __forceinline__ void bar_any(uint32_t* S, int flat, int global, uint32_t& gen) {
  gen++;
  __syncthreads();
  int bid = blockIdx.x, tid = threadIdx.x;
  if (flat) {
    if (tid == 0)
      __hip_atomic_store(S + (size_t)bid * 16, gen, __ATOMIC_RELEASE, __HIP_MEMORY_SCOPE_AGENT);
    if (bid == 0) {
      while (__hip_atomic_load(S + (size_t)tid * 16, __ATOMIC_RELAXED, __HIP_MEMORY_SCOPE_AGENT) < gen)
        __builtin_amdgcn_s_sleep(2);
      __syncthreads();
      if (tid == 0) {
        __builtin_amdgcn_fence(__ATOMIC_ACQUIRE, "agent");
        __hip_atomic_store(S + W_GREL, gen, __ATOMIC_RELEASE, __HIP_MEMORY_SCOPE_AGENT);
      }
      __syncthreads();
    } else {
      if (tid == 0) {
        while (__hip_atomic_load(S + W_GREL, __ATOMIC_RELAXED, __HIP_MEMORY_SCOPE_AGENT) < gen)
          __builtin_amdgcn_s_sleep(2);
        __builtin_amdgcn_fence(__ATOMIC_ACQUIRE, "agent");
      }
      __syncthreads();
    }
    return;
  }
  int xcd = bid & 7, q = bid >> 3;
  if (global) {
    if (q != 0) {
      if (tid == 0) {
        __hip_atomic_store(S + (size_t)(xcd * 32 + q) * 16, gen, __ATOMIC_RELAXED, __HIP_MEMORY_SCOPE_AGENT);
        while (__hip_atomic_load(S + W_LREL + xcd * 16, __ATOMIC_RELAXED, __HIP_MEMORY_SCOPE_AGENT) < gen)
          __builtin_amdgcn_s_sleep(1);
        asm volatile("buffer_inv sc0" ::: "memory");
      }
      __builtin_amdgcn_sched_barrier(0);
      __syncthreads();
    } else {
      if (tid < 31) {
        uint32_t* s = S + (size_t)(xcd * 32 + 1 + tid) * 16;
        while (__hip_atomic_load(s, __ATOMIC_RELAXED, __HIP_MEMORY_SCOPE_AGENT) < gen)
          __builtin_amdgcn_s_sleep(1);
      }
      __syncthreads();
      if (tid == 0)
        __hip_atomic_store(S + W_GARR + xcd * 16, gen, __ATOMIC_RELEASE, __HIP_MEMORY_SCOPE_AGENT);  // wbl2
      if (xcd == 0) {
        if (tid < 8) {
          while (__hip_atomic_load(S + W_GARR + tid * 16, __ATOMIC_RELAXED, __HIP_MEMORY_SCOPE_AGENT) < gen)
            __builtin_amdgcn_s_sleep(1);
        }
        __syncthreads();
        if (tid == 0)
          __hip_atomic_store(S + W_GREL, gen, __ATOMIC_RELEASE, __HIP_MEMORY_SCOPE_AGENT);
      }
      if (tid == 0) {
        while (__hip_atomic_load(S + W_GREL, __ATOMIC_RELAXED, __HIP_MEMORY_SCOPE_AGENT) < gen)
          __builtin_amdgcn_s_sleep(1);
        __builtin_amdgcn_fence(__ATOMIC_ACQUIRE, "agent");   // 1 L2 inv per XCD
        __hip_atomic_store(S + W_LREL + xcd * 16, gen, __ATOMIC_RELEASE, __HIP_MEMORY_SCOPE_AGENT);
      }
      __builtin_amdgcn_sched_barrier(0);
      __syncthreads();
    }
  } else {
    // XCD-local barrier: no cache walks at all (L1 inv only)
    if (q != 0) {
      if (tid == 0) {
        __hip_atomic_store(S + (size_t)(xcd * 32 + q) * 16, gen, __ATOMIC_RELAXED, __HIP_MEMORY_SCOPE_AGENT);
        while (__hip_atomic_load(S + W_LREL + xcd * 16, __ATOMIC_RELAXED, __HIP_MEMORY_SCOPE_AGENT) < gen)
          __builtin_amdgcn_s_sleep(1);
        asm volatile("buffer_inv sc0" ::: "memory");
      }
      __builtin_amdgcn_sched_barrier(0);
      __syncthreads();
    } else {
      if (tid < 31) {
        uint32_t* s = S + (size_t)(xcd * 32 + 1 + tid) * 16;
        while (__hip_atomic_load(s, __ATOMIC_RELAXED, __HIP_MEMORY_SCOPE_AGENT) < gen)
          __builtin_amdgcn_s_sleep(1);
      }
      __syncthreads();
      if (tid == 0) {
        asm volatile("buffer_inv sc0" ::: "memory");
        __hip_atomic_store(S + W_LREL + xcd * 16, gen, __ATOMIC_RELAXED, __HIP_MEMORY_SCOPE_AGENT);
      }
      __builtin_amdgcn_sched_barrier(0);
      __syncthreads();
    }
  }
}

// per-wave 16x16 NT tile, K=1024, B from GLOBAL (phase-2)
__device__ __forceinline__ f32x4v wtile16(
    const uint16_t* __restrict__ Ah, const uint16_t* __restrict__ Al,
    int a_cs, int a_bs, int m0,
    const uint16_t* __restrict__ Bh, const uint16_t* __restrict__ Bl,
    int n0, int lane) {
  int rsel = lane & 15, ko = (lane >> 4) * 8;
  int am = m0 + rsel;
  const uint16_t* pah = Ah + (size_t)(am >> 2) * a_cs + (size_t)(am & 3) * a_bs + ko;
  const uint16_t* pal = Al + (size_t)(am >> 2) * a_cs + (size_t)(am & 3) * a_bs + ko;
  const uint16_t* pbh = Bh + (size_t)(n0 + rsel) * 1024 + ko;
  const uint16_t* pbl = Bl + (size_t)(n0 + rsel) * 1024 + ko;
  f32x4v acc = {0.f, 0.f, 0.f, 0.f};
#pragma unroll 4
  for (int kt = 0; kt < 1024; kt += 32) {
    bf16x8 ah = *reinterpret_cast<const bf16x8*>(pah + kt);
    bf16x8 al = *reinterpret_cast<const bf16x8*>(pal + kt);
    bf16x8 bh = *reinterpret_cast<const bf16x8*>(pbh + kt);
    bf16x8 bl = *reinterpret_cast<const bf16x8*>(pbl + kt);
    acc = __builtin_amdgcn_mfma_f32_16x16x32_bf16(ah, bh, acc, 0, 0, 0);
    acc = __builtin_amdgcn_mfma_f32_16x16x32_bf16(ah, bl, acc, 0, 0, 0);
    acc = __builtin_amdgcn_mfma_f32_16x16x32_bf16(al, bh, acc, 0, 0, 0);
  }
  return acc;
}

// per-wave 16x16 NT tile, K=1024, B from LDS (XOR-swizzled), dual accumulator.
__device__ __forceinline__ f32x4v wtile16_lds(
    const uint16_t* __restrict__ Ah, const uint16_t* __restrict__ Al,
    int a_cs, int a_bs, int m0,
    const uint16_t* sBh, const uint16_t* sBl,
    int lane) {
  int rsel = lane & 15, ko = (lane >> 4) * 8;
  int am = m0 + rsel;
  const uint16_t* pah = Ah + (size_t)(am >> 2) * a_cs + (size_t)(am & 3) * a_bs + ko;
  const uint16_t* pal = Al + (size_t)(am >> 2) * a_cs + (size_t)(am & 3) * a_bs + ko;
  int rb = rsel * 1024;
  int s7 = rsel & 7;
  f32x4v acc0 = {0.f, 0.f, 0.f, 0.f}, acc1 = {0.f, 0.f, 0.f, 0.f};
#pragma unroll 4
  for (int kt = 0; kt < 1024; kt += 64) {
    int e0 = kt + ko, e1 = kt + 32 + ko;
    int o0 = rb + ((((e0) >> 3) ^ s7) << 3);
    int o1 = rb + ((((e1) >> 3) ^ s7) << 3);
    bf16x8 ah0 = *reinterpret_cast<const bf16x8*>(pah + kt);
    bf16x8 al0 = *reinterpret_cast<const bf16x8*>(pal + kt);
    bf16x8 ah1 = *reinterpret_cast<const bf16x8*>(pah + kt + 32);
    bf16x8 al1 = *reinterpret_cast<const bf16x8*>(pal + kt + 32);
    bf16x8 bh0 = *reinterpret_cast<const bf16x8*>(sBh + o0);
    bf16x8 bl0 = *reinterpret_cast<const bf16x8*>(sBl + o0);
    bf16x8 bh1 = *reinterpret_cast<const bf16x8*>(sBh + o1);
    bf16x8 bl1 = *reinterpret_cast<const bf16x8*>(sBl + o1);
    acc0 = __builtin_amdgcn_mfma_f32_16x16x32_bf16(ah0, bh0, acc0, 0, 0, 0);
    acc1 = __builtin_amdgcn_mfma_f32_16x16x32_bf16(ah1, bh1, acc1, 0, 0, 0);
    acc0 = __builtin_amdgcn_mfma_f32_16x16x32_bf16(ah0, bl0, acc0, 0, 0, 0);
    acc1 = __builtin_amdgcn_mfma_f32_16x16x32_bf16(ah1, bl1, acc1, 0, 0, 0);
    acc0 = __builtin_amdgcn_mfma_f32_16x16x32_bf16(al0, bh0, acc0, 0, 0, 0);
    acc1 = __builtin_amdgcn_mfma_f32_16x16x32_bf16(al1, bh1, acc1, 0, 0, 0);
  }
  return acc0 + acc1;
}

// ---------------- persistent per-layer kernel: 3-phase chunked scan, XCD-row-partitioned.
// Scan rows (chunk,batch) are independent -> XCD x owns rows [32x,32x+32) and computes ALL
// columns for them. Phases 1/3 and 2a/2c need only XCD-LOCAL barriers; global barriers only
// after 2a (publish lambda_7 to XCD0) and after 2b (publish beta to all). LAM/GS padded to
// 16 rows/group so each group is a clean MFMA A-tile (rows 4-15 garbage; MFMA output row r
// reads only A row r -> discarded safely).
__global__ __launch_bounds__(256) void k_layer(
    uint32_t* S,
    float* __restrict__ P,
    uint16_t* __restrict__ PUh, uint16_t* __restrict__ PUl,
    uint16_t* __restrict__ Sh, uint16_t* __restrict__ Sl,
    const uint16_t* __restrict__ M1h, const uint16_t* __restrict__ M1l,
    const uint16_t* __restrict__ M16h, const uint16_t* __restrict__ M16l,
    const uint16_t* __restrict__ M128h, const uint16_t* __restrict__ M128l,
    uint16_t* G3h0, uint16_t* G3l0, uint16_t* G3h1, uint16_t* G3l1,
    uint16_t* BEh, uint16_t* BEl,
    float* LAMf, uint16_t* LAMh, uint16_t* LAMl,
    uint16_t* GSh0, uint16_t* GSl0, uint16_t* GSh1, uint16_t* GSl1,
    const float* __restrict__ starterL) {
  __shared__ uint16_t sB[2][32 * 1024];   // 128 KB: M1 rows [32q,32q+32), staged once
  int tid = threadIdx.x, bid = blockIdx.x;
  int lane = tid & 63;
  int wv = tid >> 6;
  int xcd = bid & 7;
  int q = bid >> 3;
  uint32_t gen = 0;
  int rowg = (lane >> 4) * 4, colg = lane & 15;

  // phase-1/3 mapping: XCD owns rows [xcd*32, xcd*32+32); block q covers n-tiles {2q,2q+1}
  int m0_13 = xcd * 32 + (wv & 1) * 16;
  int n0_13 = (2 * q + (wv >> 1)) * 16;
  int lrb13 = (wv >> 1) * 16 * 1024;
  // phase-2 mapping (blocks q<16): group g = xcd; wave covers n-tile q*4+wv
  int n0_2 = (q * 4 + wv) * 16;

  // init: sigma_0 = starter broadcast (group 0 rows; G3/S c=0 rows)
  {
    int idx = bid * 256 + tid;
    if (idx < BATCH * DIMX) {
      int b = idx >> 10, d = idx & 1023;
      float v = starterL[d];
      uint16_t h, l;
      fsplit(v, h, l);
      size_t o = (size_t)b * 1024 + d;
      BEh[o] = h; BEl[o] = l;
      G3h0[o] = h; G3l0[o] = l;
      GSh0[o] = h; GSl0[o] = l;
      Sh[o] = h; Sl[o] = l;
    }
  }

  // ---- verify bid&7 == physical XCD; mismatch -> flat barriers for whole kernel
  if (tid == 0 && get_xcc() != (uint32_t)xcd)
    __hip_atomic_store(S + W_FLAG, 1u, __ATOMIC_RELAXED, __HIP_MEMORY_SCOPE_AGENT);
  bar_any(S, 1, 1, gen);   // flat verification barrier (publishes init + flag)
  int flat = (int)__hip_atomic_load(S + W_FLAG, __ATOMIC_RELAXED, __HIP_MEMORY_SCOPE_AGENT);

  // stage M1 rows [32q, 32q+32) into LDS (swizzled) — serves phases 1 AND 3
  {
    const uint16_t* gh = M1h + (size_t)(32 * q) * 1024;
    const uint16_t* gl = M1l + (size_t)(32 * q) * 1024;
    for (int i = tid; i < 32 * 128; i += 256) {
      int r = i >> 7, c8 = i & 127;
      int dst = r * 1024 + ((c8 ^ (r & 7)) << 3);
      *reinterpret_cast<bf16x8*>(&sB[0][dst]) = *reinterpret_cast<const bf16x8*>(gh + (size_t)r * 1024 + c8 * 8);
      *reinterpret_cast<bf16x8*>(&sB[1][dst]) = *reinterpret_cast<const bf16x8*>(gl + (size_t)r * 1024 + c8 * 8);
    }
  }
  __syncthreads();

  // ---- phase 1: l_j = A l_{j-1} + u_j, j=1..15 (XCD-local barriers only)
  for (int j = 1; j < 16; ++j) {
    {
      f32x4v acc = wtile16_lds(PUh + (size_t)(j - 1) * 4096, PUl + (size_t)(j - 1) * 4096,
                               65536, 1024, m0_13, &sB[0][lrb13], &sB[1][lrb13], lane);
      int n = n0_13 + colg;
#pragma unroll
      for (int rr = 0; rr < 4; ++rr) {
        int m = m0_13 + rowg + rr;
        int c = m >> 2, b = m & 3;
        size_t t = (size_t)(c * 16 + j);
        float* pu = P + (t * 4 + b) * 2048 + 1024 + n;
        float v = acc[rr] + *pu;
        *pu = v;
        uint16_t h, l;
        fsplit(v, h, l);
        size_t o = (t * 4 + b) * 1024 + n;
        PUh[o] = h; PUl[o] = l;
      }
    }
    bar_any(S, flat, 0, gen);
  }

  // ---- phase 2a init: lambda_0(g=xcd) = e_{8g} (local rows)
  if (q == 0) {
    for (int i = tid; i < 4096; i += 256) {
      int b = i >> 10, d = i & 1023;
      float v = P[((size_t)(xcd * 128 + 15) * 4 + b) * 2048 + 1024 + d];
      size_t o = (size_t)xcd * 16384 + (size_t)b * 1024 + d;
      LAMf[o] = v;
      uint16_t h, l;
      fsplit(v, h, l);
      LAMh[o] = h; LAMl[o] = l;
    }
  }
  bar_any(S, flat, 0, gen);

  // ---- phase 2a: lambda_j(g) = A16 lambda_{j-1}(g) + e_{8g+j}, j=1..7 (XCD g local)
  for (int j = 1; j < 8; ++j) {
    if (q < 16) {
      size_t abase = (size_t)(j - 1) * 131072 + (size_t)xcd * 16384;
      f32x4v acc = wtile16(LAMh + abase, LAMl + abase, 4096, 1024, 0, M16h, M16l, n0_2, lane);
      if (rowg == 0) {
        int n = n0_2 + colg;
#pragma unroll
        for (int rr = 0; rr < 4; ++rr) {
          int b = rr;
          int c = 8 * xcd + j;
          float e = P[((size_t)(c * 16 + 15) * 4 + b) * 2048 + 1024 + n];
          float v = acc[rr] + e;
          size_t o = (size_t)j * 131072 + (size_t)xcd * 16384 + (size_t)b * 1024 + n;
          LAMf[o] = v;
          uint16_t h, l;
          fsplit(v, h, l);
          LAMh[o] = h; LAMl[o] = l;
        }
      }
    }
    bar_any(S, flat, (j == 7) ? 1 : 0, gen);   // publish lambda_7 to XCD0
  }

  // ---- phase 2b: beta_{g+1} = A128 beta_g + lambda_7(g), g=0..6 (XCD0 only)
  for (int g = 0; g < 7; ++g) {
    if (xcd == 0 && q < 16) {
      f32x4v acc = wtile16(BEh + (size_t)g * 16384, BEl + (size_t)g * 16384,
                           4096, 1024, 0, M128h, M128l, n0_2, lane);
      if (rowg == 0) {
        int n = n0_2 + colg;
#pragma unroll
        for (int rr = 0; rr < 4; ++rr) {
          int b = rr;
          float v = acc[rr] + LAMf[(size_t)7 * 131072 + (size_t)g * 16384 + (size_t)b * 1024 + n];
          uint16_t h, l;
          fsplit(v, h, l);
          size_t ob = (size_t)(g + 1) * 16384 + (size_t)b * 1024 + n;
          BEh[ob] = h; BEl[ob] = l;
          int c = 8 * (g + 1);
          size_t o1 = (size_t)(c * 4 + b) * 1024 + n;
          G3h0[o1] = h; G3l0[o1] = l;
          size_t o2 = ((size_t)(c * 16) * 4 + b) * 1024 + n;
          Sh[o2] = h; Sl[o2] = l;
          GSh0[ob] = h; GSl0[ob] = l;
        }
      }
    }
    bar_any(S, flat, (g == 6) ? 1 : 0, gen);   // publish beta/GS/G3/S to all XCDs
  }

  // ---- phase 2c: Gs_j(g) = A16 Gs_{j-1}(g); sigma_{8g+j} = Gs_j + lambda_{j-1}, j=1..7
  int gsc = 0;
  for (int j = 1; j < 8; ++j) {
    uint16_t* gih = gsc ? GSh1 : GSh0;
    uint16_t* gil = gsc ? GSl1 : GSl0;
    uint16_t* goh = gsc ? GSh0 : GSh1;
    uint16_t* gol = gsc ? GSl0 : GSl1;
    if (q < 16) {
      size_t gbase = (size_t)xcd * 16384;
      f32x4v acc = wtile16(gih + gbase, gil + gbase, 4096, 1024, 0, M16h, M16l, n0_2, lane);
      if (rowg == 0) {
        int n = n0_2 + colg;
#pragma unroll
        for (int rr = 0; rr < 4; ++rr) {
          int b = rr;
          int c = 8 * xcd + j;
          float lam = LAMf[(size_t)(j - 1) * 131072 + (size_t)xcd * 16384 + (size_t)b * 1024 + n];
          float v = acc[rr] + lam;
          uint16_t h, l;
          fsplit(v, h, l);
          size_t o1 = (size_t)(c * 4 + b) * 1024 + n;
          G3h0[o1] = h; G3l0[o1] = l;
          size_t o2 = ((size_t)(c * 16) * 4 + b) * 1024 + n;
          Sh[o2] = h; Sl[o2] = l;
          uint16_t h2, l2;
          fsplit(acc[rr], h2, l2);
          goh[gbase + (size_t)b * 1024 + n] = h2;
          gol[gbase + (size_t)b * 1024 + n] = l2;
        }
      }
    }
    bar_any(S, flat, 0, gen);
    gsc ^= 1;
  }

  // ---- phase 3: G_j = A G_{j-1}; S[c*16+j] = G_j + l_{c*16+j-1}, j=1..15 (local)
  int g3 = 0;
  for (int j = 1; j < 16; ++j) {
    uint16_t* gih = g3 ? G3h1 : G3h0;
    uint16_t* gil = g3 ? G3l1 : G3l0;
    uint16_t* goh = g3 ? G3h0 : G3h1;
    uint16_t* gol = g3 ? G3l0 : G3l1;
    {
      f32x4v acc = wtile16_lds(gih, gil, 4096, 1024, m0_13, &sB[0][lrb13], &sB[1][lrb13], lane);
      int n = n0_13 + colg;
#pragma unroll
      for (int rr = 0; rr < 4; ++rr) {
        int m = m0_13 + rowg + rr;
        int c = m >> 2, b = m & 3;
        float u = P[((size_t)(c * 16 + j - 1) * 4 + b) * 2048 + 1024 + n];
        float v = acc[rr] + u;
        uint16_t h, l;
        fsplit(v, h, l);
        size_t o = ((size_t)(c * 16 + j) * 4 + b) * 1024 + n;
        Sh[o] = h; Sl[o] = l;
        uint16_t h2, l2;
        fsplit(acc[rr], h2, l2);
        goh[(size_t)m * 1024 + n] = h2;
        gol[(size_t)m * 1024 + n] = l2;
      }
    }
    if (j < 15) bar_any(S, flat, 0, gen);
    g3 ^= 1;
  }
}

// ---------------- reorder H_hi [t][b][d] -> Y [b][t][d]
__global__ __launch_bounds__(256) void k_reorder_hi(const uint16_t* __restrict__ Hhi, uint16_t* __restrict__ Y) {
  int idx = blockIdx.x * 256 + threadIdx.x;
  int d4 = idx & (DIMX / 4 - 1);
  int tb = idx >> 8;
  int t = tb >> 2, b = tb & 3;
  ushort4 v = reinterpret_cast<const ushort4*>(Hhi)[idx];
  reinterpret_cast<ushort4*>(Y + (size_t)(b * SEQ + t) * DIMX)[d4] = v;
}

__global__ __launch_bounds__(256) void k_cast_w(const float* __restrict__ src, uint16_t* __restrict__ dst, int n4) {
  int idx = blockIdx.x * 256 + threadIdx.x;
  if (idx >= n4) return;
  float4 v = reinterpret_cast<const float4*>(src)[idx];
  ushort4 o;
  o.x = f2b(v.x); o.y = f2b(v.y); o.z = f2b(v.z); o.w = f2b(v.w);
  reinterpret_cast<ushort4*>(dst)[idx] = o;
}

// ---------------- logits GEMM: bf16 MFMA 128x128
__global__ __launch_bounds__(256) void k_logits(const uint16_t* __restrict__ A,
                                                const uint16_t* __restrict__ Bt,
                                                float* __restrict__ C) {
  __shared__ uint16_t As[128 * 32];
  __shared__ uint16_t Bs[128 * 32];
  int tid = threadIdx.x;
  int bx = blockIdx.x, by = blockIdx.y;
  int lane = tid & 63, wave = tid >> 6;
  int wm = wave >> 1, wn = wave & 1;
  f32x4v acc[4][4] = {};
  const uint16_t* Ag = A + (size_t)by * 128 * 1024;
  const uint16_t* Bg = Bt + (size_t)bx * 128 * 1024;
  for (int kt = 0; kt < 1024; kt += 32) {
    __syncthreads();
#pragma unroll
    for (int q = 0; q < 2; ++q) {
      int off = q * 4096 + tid * 16;
      int r = off >> 6, cu = (off & 63) >> 1;
      __builtin_amdgcn_global_load_lds(
          (const __attribute__((address_space(1))) uint32_t*)(Ag + (size_t)r * 1024 + kt + cu),
          (__attribute__((address_space(3))) uint32_t*)((char*)As + off), 16, 0, 0);
      __builtin_amdgcn_global_load_lds(
          (const __attribute__((address_space(1))) uint32_t*)(Bg + (size_t)r * 1024 + kt + cu),
          (__attribute__((address_space(3))) uint32_t*)((char*)Bs + off), 16, 0, 0);
    }
    __syncthreads();
    int rsel = lane & 15, ko = (lane >> 4) * 8;
    bf16x8 af[4], bfr[4];
#pragma unroll
    for (int mf = 0; mf < 4; ++mf)
      af[mf] = *reinterpret_cast<const bf16x8*>(As + (wm * 64 + mf * 16 + rsel) * 32 + ko);
#pragma unroll
    for (int nf = 0; nf < 4; ++nf)
      bfr[nf] = *reinterpret_cast<const bf16x8*>(Bs + (wn * 64 + nf * 16 + rsel) * 32 + ko);
#pragma unroll
    for (int mf = 0; mf < 4; ++mf)
#pragma unroll
      for (int nf = 0; nf < 4; ++nf)
        acc[mf][nf] = __builtin_amdgcn_mfma_f32_16x16x32_bf16(af[mf], bfr[nf], acc[mf][nf], 0, 0, 0);
  }
  int rowg = (lane >> 4) * 4;
  int colg = lane & 15;
#pragma unroll
  for (int mf = 0; mf < 4; ++mf)
#pragma unroll
    for (int nf = 0; nf < 4; ++nf)
#pragma unroll
      for (int r = 0; r < 4; ++r) {
        int m = by * 128 + wm * 64 + mf * 16 + rowg + r;
        int n = bx * 128 + wn * 64 + nf * 16 + colg;
        C[(size_t)m * VOCAB + n] = acc[mf][nf][r];
      }
}

// =========================================================================
extern "C" void kernel_launch(void* const* d_in, const int* in_sizes, int n_in,
                              void* d_out, int out_size, void* d_ws, size_t ws_size,
                              hipStream_t stream) {
  const int* ids = (const int*)d_in[0];
  const float* emb = (const float*)d_in[1];
  const float* W = (const float*)d_in[2];
  const float* outw = (const float*)d_in[3];
  const float* starter = (const float*)d_in[4];
  float* out = (float*)d_out;

  char* wsb = (char*)d_ws;
  size_t off = 0;
  auto alloc = [&](size_t bytes) {
    void* p = wsb + off;
    off = (off + bytes + 255) & ~(size_t)255;
    return p;
  };
  const size_t TB = SEQ * BATCH;
  const size_t MB1 = (size_t)1024 * 1024;

  uint32_t* SYNC = (uint32_t*)alloc((size_t)NLAYERS * 8192 * 4);
  uint16_t* Hh[2] = {(uint16_t*)alloc(TB * DIMX * 2), (uint16_t*)alloc(TB * DIMX * 2)};
  uint16_t* Hl[2] = {(uint16_t*)alloc(TB * DIMX * 2), (uint16_t*)alloc(TB * DIMX * 2)};
  float* P = (float*)alloc(TB * 2 * DIMX * 4);
  uint16_t* PUh = (uint16_t*)alloc(TB * DIMX * 2);
  uint16_t* PUl = (uint16_t*)alloc(TB * DIMX * 2);
  uint16_t* Sh = (uint16_t*)alloc(TB * DIMX * 2);
  uint16_t* Sl = (uint16_t*)alloc(TB * DIMX * 2);
  uint16_t* W1h = (uint16_t*)alloc((size_t)NLAYERS * 2048 * 1024 * 2);
  uint16_t* W1l = (uint16_t*)alloc((size_t)NLAYERS * 2048 * 1024 * 2);
  uint16_t* WSh = (uint16_t*)alloc((size_t)NLAYERS * MB1 * 2);
  uint16_t* WSl = (uint16_t*)alloc((size_t)NLAYERS * MB1 * 2);
  uint16_t* M1h = (uint16_t*)alloc((size_t)NLAYERS * MB1 * 2);
  uint16_t* M1l = (uint16_t*)alloc((size_t)NLAYERS * MB1 * 2);
  uint16_t* T1h = (uint16_t*)alloc((size_t)NLAYERS * MB1 * 2);
  uint16_t* T1l = (uint16_t*)alloc((size_t)NLAYERS * MB1 * 2);
  uint16_t* M16Ah = (uint16_t*)alloc((size_t)NLAYERS * MB1 * 2);
  uint16_t* M16Al = (uint16_t*)alloc((size_t)NLAYERS * MB1 * 2);
  uint16_t* M128Ah = (uint16_t*)alloc((size_t)NLAYERS * MB1 * 2);
  uint16_t* M128Al = (uint16_t*)alloc((size_t)NLAYERS * MB1 * 2);
  uint16_t* G3h0 = (uint16_t*)alloc((size_t)256 * 1024 * 2);
  uint16_t* G3l0 = (uint16_t*)alloc((size_t)256 * 1024 * 2);
  uint16_t* G3h1 = (uint16_t*)alloc((size_t)256 * 1024 * 2);
  uint16_t* G3l1 = (uint16_t*)alloc((size_t)256 * 1024 * 2);
  uint16_t* BEh = (uint16_t*)alloc((size_t)8 * 16 * 1024 * 2);
  uint16_t* BEl = (uint16_t*)alloc((size_t)8 * 16 * 1024 * 2);
  float* LAMf = (float*)alloc((size_t)8 * 128 * 1024 * 4);   // padded [8][8][16][1024]
  uint16_t* LAMh = (uint16_t*)alloc((size_t)8 * 128 * 1024 * 2);
  uint16_t* LAMl = (uint16_t*)alloc((size_t)8 * 128 * 1024 * 2);
  uint16_t* GSh0 = (uint16_t*)alloc((size_t)128 * 1024 * 2);  // padded [8][16][1024]
  uint16_t* GSl0 = (uint16_t*)alloc((size_t)128 * 1024 * 2);
  uint16_t* GSh1 = (uint16_t*)alloc((size_t)128 * 1024 * 2);
  uint16_t* GSl1 = (uint16_t*)alloc((size_t)128 * 1024 * 2);
  uint16_t* YSB = (uint16_t*)alloc(TB * DIMX * 2);
  uint16_t* OWB = (uint16_t*)alloc((size_t)VOCAB * DIMX * 2);

  // power-chain ping-pong buffers overlaid on P / S / H[1]
  uint16_t* CMh[2] = {(uint16_t*)P, Sh};
  uint16_t* CMl[2] = {(uint16_t*)P + 4 * MB1, Sl};
  uint16_t* CTh[2] = {(uint16_t*)P + 8 * MB1, Hh[1]};
  uint16_t* CTl[2] = {(uint16_t*)P + 12 * MB1, Hl[1]};

  hipMemsetAsync(SYNC, 0, (size_t)NLAYERS * 8192 * 4, stream);
  k_split_w<<<NLAYERS * 4096, 256, 0, stream>>>(W, W1h, W1l, WSh, WSl, M1h, M1l);
  k_trans_w<<<dim3(16, 16, NLAYERS), 256, 0, stream>>>(W, T1h, T1l);
  k_cast_w<<<(int)((size_t)VOCAB * DIMX / 4 / 256), 256, 0, stream>>>(outw, OWB, VOCAB * DIMX / 4);
  k_embed_split<<<(int)(TB * DIMX / 4 / 256), 256, 0, stream>>>(ids, emb, Hh[0], Hl[0]);

  // power chain: level k -> A^(2^k)
  {
    const uint16_t *inMh = M1h, *inMl = M1l, *inTh = T1h, *inTl = T1l;
    for (int k = 1; k <= 7; ++k) {
      uint16_t *oMh, *oMl;
      if (k == 4) { oMh = M16Ah; oMl = M16Al; }
      else if (k == 7) { oMh = M128Ah; oMl = M128Al; }
      else { oMh = CMh[k & 1]; oMl = CMl[k & 1]; }
      uint16_t* oTh = (k < 7) ? CTh[k & 1] : nullptr;
      uint16_t* oTl = (k < 7) ? CTl[k & 1] : nullptr;
      k_mfma<128, 128><<<dim3(8, 8, NLAYERS), 256, 0, stream>>>(
          1024,
          inMh, inMl, 4096, 1024, MB1,
          inTh, inTl, 1024, MB1,
          nullptr, 0, 0,
          nullptr, 0, 0,
          oMh, oMl, 4096, 1024, 0, MB1,
          oTh, oTl, 1024, 0, MB1);
      inMh = oMh; inMl = oMl; inTh = oTh; inTl = oTl;
    }
  }

  int cur = 0;
  for (int l = 0; l < NLAYERS; ++l) {
    // [a|u] = H @ W[:,0:1024]^T ; f32 -> P, split(u) -> PU
    k_mfma<128, 128><<<dim3(16, 32, 1), 256, 0, stream>>>(
        1024,
        Hh[cur], Hl[cur], 4096, 1024, 0,
        W1h + (size_t)l * 2048 * 1024, W1l + (size_t)l * 2048 * 1024, 1024, 0,
        nullptr, 0, 0,
        P, 8192, 2048,
        PUh, PUl, 4096, 1024, 1024, 0,
        nullptr, nullptr, 0, 1, 0);

    // persistent: phase1 + phase2 + phase3
    k_layer<<<NBLK, 256, 0, stream>>>(
        SYNC + (size_t)l * 8192,
        P, PUh, PUl, Sh, Sl,
        M1h + (size_t)l * MB1, M1l + (size_t)l * MB1,
        M16Ah + (size_t)l * MB1, M16Al + (size_t)l * MB1,
        M128Ah + (size_t)l * MB1, M128Al + (size_t)l * MB1,
        G3h0, G3l0, G3h1, G3l1,
        BEh, BEl, LAMf, LAMh, LAMl,
        GSh0, GSl0, GSh1, GSl1,
        starter + (size_t)l * DIMX);

    // H_next = a + S @ W_hs^T (split out)
    k_mfma<128, 128><<<dim3(8, 32, 1), 256, 0, stream>>>(
        1024,
        Sh, Sl, 4096, 1024, 0,
        WSh + (size_t)l * MB1, WSl + (size_t)l * MB1, 1024, 0,
        P, 8192, 2048,
        nullptr, 0, 0,
        Hh[cur ^ 1], Hl[cur ^ 1], 4096, 1024, 0, 0,
        nullptr, nullptr, 0, 1, 0);
    cur ^= 1;
  }

  k_reorder_hi<<<(int)(TB * DIMX / 4 / 256), 256, 0, stream>>>(Hh[cur], YSB);
  k_logits<<<dim3(VOCAB / 128, TB / 128), 256, 0, stream>>>(YSB, OWB, out);
}